// Round 9
// baseline (877.486 us; speedup 1.0000x reference)
//
#include <hip/hip_runtime.h>
#include <math.h>

#define B_  4
#define S_  2048
#define D_  576
#define H_  9
#define HD_ 64
#define FF_ 1536
#define E_  8
#define TOK (B_*S_)   // 8192
// compact routed rows: 2*TOK + 8*127 pad rounded -> 17408; +TOK shared -> 25600
#define T1ROWS 17408
#define T1ALL  25600

typedef unsigned int   u32x4  __attribute__((ext_vector_type(4)));
typedef unsigned short u16x8  __attribute__((ext_vector_type(8)));
typedef __bf16         bf16x8 __attribute__((ext_vector_type(8)));
typedef _Float16       f16x8  __attribute__((ext_vector_type(8)));
typedef float          f32x4  __attribute__((ext_vector_type(4)));

__device__ __forceinline__ float b2f(unsigned short u) {
    union { unsigned int i; float f; } v; v.i = ((unsigned int)u) << 16; return v.f;
}
__device__ __forceinline__ unsigned short f2b(float f) {
    unsigned int u = __builtin_bit_cast(unsigned int, f);
    unsigned int r = 0x7fffu + ((u >> 16) & 1u);
    return (unsigned short)((u + r) >> 16);
}

// XCD-aware (x,y) block swizzle: consecutive logical tiles (which share A
// rows across the fast x dimension) land on the SAME XCD's L2 instead of
// round-robining across all 8. Pure permutation; identity if nwg % 8 != 0.
__device__ __forceinline__ void swz2d(int& bx, int& by) {
    int nx = gridDim.x, ny = gridDim.y;
    int nwg = nx * ny;
    if ((nwg & 7) == 0) {
        int orig = by * nx + bx;
        int logical = (orig & 7) * (nwg >> 3) + (orig >> 3);
        bx = logical % nx;
        by = logical / nx;
    }
}

// ---------------------------------------------------------------------------
// RMSNorm fp32 -> bf16 (for the expert phase)
// ---------------------------------------------------------------------------
__global__ __launch_bounds__(256)
void rmsnorm_k(const float* __restrict__ x, unsigned short* __restrict__ xn) {
    int tok = blockIdx.x, tid = threadIdx.x;
    const float* xr = x + (size_t)tok * D_;
    float v0 = xr[tid];
    float v1 = xr[tid + 256];
    float v2 = (tid < D_ - 512) ? xr[tid + 512] : 0.f;
    float ss = v0*v0 + v1*v1 + v2*v2;
    #pragma unroll
    for (int d = 1; d < 64; d <<= 1) ss += __shfl_xor(ss, d, 64);
    __shared__ float red[4];
    if ((tid & 63) == 0) red[tid >> 6] = ss;
    __syncthreads();
    float tot = red[0] + red[1] + red[2] + red[3];
    float rms = rsqrtf(tot / (float)D_ + 1e-6f);
    unsigned short* orow = xn + (size_t)tok * D_;
    orow[tid]       = f2b(v0 * rms);
    orow[tid + 256] = f2b(v1 * rms);
    if (tid < D_ - 512) orow[tid + 512] = f2b(v2 * rms);
}

// RMSNorm fp32 -> fp32, chunk-local output (fallback path)
__global__ __launch_bounds__(256)
void rms32_k(const float* __restrict__ x, float* __restrict__ xn) {
    int tok = blockIdx.x, tid = threadIdx.x;
    const float* xr = x + (size_t)tok * D_;
    float v0 = xr[tid];
    float v1 = xr[tid + 256];
    float v2 = (tid < D_ - 512) ? xr[tid + 512] : 0.f;
    float ss = v0*v0 + v1*v1 + v2*v2;
    #pragma unroll
    for (int d = 1; d < 64; d <<= 1) ss += __shfl_xor(ss, d, 64);
    __shared__ float red[4];
    if ((tid & 63) == 0) red[tid >> 6] = ss;
    __syncthreads();
    float tot = red[0] + red[1] + red[2] + red[3];
    float rms = rsqrtf(tot / (float)D_ + 1e-6f);
    float* orow = xn + (size_t)tok * D_;
    orow[tid]       = v0 * rms;
    orow[tid + 256] = v1 * rms;
    if (tid < D_ - 512) orow[tid + 512] = v2 * rms;
}

// RMSNorm fp32 -> pre-split f16 pair (Ah, Al*2048), chunk-local. Rounding is
// bit-identical to the old in-loop split of the fp32 xn32c value.
__global__ __launch_bounds__(256)
void rmssplit_k(const float* __restrict__ x,
                _Float16* __restrict__ xh, _Float16* __restrict__ xl) {
    int tok = blockIdx.x, tid = threadIdx.x;
    const float* xr = x + (size_t)tok * D_;
    float v0 = xr[tid];
    float v1 = xr[tid + 256];
    float v2 = (tid < D_ - 512) ? xr[tid + 512] : 0.f;
    float ss = v0*v0 + v1*v1 + v2*v2;
    #pragma unroll
    for (int d = 1; d < 64; d <<= 1) ss += __shfl_xor(ss, d, 64);
    __shared__ float red[4];
    if ((tid & 63) == 0) red[tid >> 6] = ss;
    __syncthreads();
    float tot = red[0] + red[1] + red[2] + red[3];
    float rms = rsqrtf(tot / (float)D_ + 1e-6f);
    _Float16* hr = xh + (size_t)tok * D_;
    _Float16* lr = xl + (size_t)tok * D_;
    {
        float v = v0 * rms; _Float16 h = (_Float16)v;
        hr[tid] = h; lr[tid] = (_Float16)((v - (float)h) * 2048.0f);
    }
    {
        float v = v1 * rms; _Float16 h = (_Float16)v;
        hr[tid + 256] = h; lr[tid + 256] = (_Float16)((v - (float)h) * 2048.0f);
    }
    if (tid < D_ - 512) {
        float v = v2 * rms; _Float16 h = (_Float16)v;
        hr[tid + 512] = h; lr[tid + 512] = (_Float16)((v - (float)h) * 2048.0f);
    }
}

// ---------------------------------------------------------------------------
// Merged weight convert+transpose, w1/w3 family: fp32 [D][FF] -> bf16 [FF][D].
// z: 0..7 = w1 experts, 8 = sw1, 9..16 = w3 experts, 17 = sw3.
// ---------------------------------------------------------------------------
__global__ __launch_bounds__(256)
void convw13_k(const float* __restrict__ w1, const float* __restrict__ w3,
               const float* __restrict__ sw1, const float* __restrict__ sw3,
               unsigned short* __restrict__ wt1, unsigned short* __restrict__ wt3)
{
    const size_t WE = (size_t)D_ * FF_;
    int z = blockIdx.z;
    const float* s; unsigned short* d;
    if (z < 8)       { s = w1 + (size_t)z * WE;       d = wt1 + (size_t)z * WE; }
    else if (z == 8) { s = sw1;                        d = wt1 + 8 * WE; }
    else if (z < 17) { s = w3 + (size_t)(z - 9) * WE;  d = wt3 + (size_t)(z - 9) * WE; }
    else             { s = sw3;                        d = wt3 + 8 * WE; }
    const int K = D_, N = FF_;
    __shared__ unsigned short t[64][72];
    int n0 = blockIdx.x * 64, k0 = blockIdx.y * 64;
    int tx = threadIdx.x & 63, ty = threadIdx.x >> 6;
    #pragma unroll
    for (int i = 0; i < 16; ++i) {
        int k = i * 4 + ty;
        t[k][tx] = f2b(s[(size_t)(k0 + k) * N + n0 + tx]);
    }
    __syncthreads();
    int r = threadIdx.x >> 3, c8 = (threadIdx.x & 7) * 8;
    #pragma unroll
    for (int it = 0; it < 2; ++it, r += 32) {
        u16x8 v;
        #pragma unroll
        for (int j = 0; j < 8; ++j) v[j] = t[c8 + j][r];
        *(u16x8*)&d[(size_t)(n0 + r) * K + k0 + c8] = v;
    }
}

// w2 family: fp32 [FF][D] -> bf16 [D][FF]. z: 0..7 = w2 experts, 8 = sw2.
__global__ __launch_bounds__(256)
void convw2_k(const float* __restrict__ w2, const float* __restrict__ sw2,
              unsigned short* __restrict__ wt2)
{
    const size_t WE = (size_t)D_ * FF_;
    int z = blockIdx.z;
    const float* s = (z < 8) ? w2 + (size_t)z * WE : sw2;
    unsigned short* d = wt2 + (size_t)z * WE;
    const int K = FF_, N = D_;
    __shared__ unsigned short t[64][72];
    int n0 = blockIdx.x * 64, k0 = blockIdx.y * 64;
    int tx = threadIdx.x & 63, ty = threadIdx.x >> 6;
    #pragma unroll
    for (int i = 0; i < 16; ++i) {
        int k = i * 4 + ty;
        t[k][tx] = f2b(s[(size_t)(k0 + k) * N + n0 + tx]);
    }
    __syncthreads();
    int r = threadIdx.x >> 3, c8 = (threadIdx.x & 7) * 8;
    #pragma unroll
    for (int it = 0; it < 2; ++it, r += 32) {
        u16x8 v;
        #pragma unroll
        for (int j = 0; j < 8; ++j) v[j] = t[c8 + j][r];
        *(u16x8*)&d[(size_t)(n0 + r) * K + k0 + c8] = v;
    }
}

// ---------------------------------------------------------------------------
// Split-weight convert+transpose for the high-precision path:
// fp32 [K][N] -> f16 Wh[N][K] and Wl[N][K] (= (v-h)*2048).
// ---------------------------------------------------------------------------
__global__ __launch_bounds__(256)
void convS_k(const float* __restrict__ src,
             _Float16* __restrict__ dh, _Float16* __restrict__ dl,
             int K, int N)
{
    __shared__ _Float16 th[64][72], tl[64][72];
    int n0 = blockIdx.x * 64, k0 = blockIdx.y * 64;
    int tx = threadIdx.x & 63, ty = threadIdx.x >> 6;
    #pragma unroll
    for (int i = 0; i < 16; ++i) {
        int k = i * 4 + ty;
        float v = src[(size_t)(k0 + k) * N + n0 + tx];
        _Float16 h = (_Float16)v;
        th[k][tx] = h;
        tl[k][tx] = (_Float16)((v - (float)h) * 2048.0f);
    }
    __syncthreads();
    int r = threadIdx.x >> 3, c8 = (threadIdx.x & 7) * 8;
    #pragma unroll
    for (int it = 0; it < 2; ++it, r += 32) {
        f16x8 vh, vl;
        #pragma unroll
        for (int j = 0; j < 8; ++j) { vh[j] = th[c8 + j][r]; vl[j] = tl[c8 + j][r]; }
        *(f16x8*)&dh[(size_t)(n0 + r) * K + k0 + c8] = vh;
        *(f16x8*)&dl[(size_t)(n0 + r) * K + k0 + c8] = vl;
    }
}

// ---------------------------------------------------------------------------
// High-precision GEMM via scaled fp16 split. XOR-swizzled unpadded LDS,
// XCD-swizzled grid. AB=1: A pre-split f16 (Ahp/Alp) -> vector staging.
// ---------------------------------------------------------------------------
template<int BN, int EPI, int WB, int AB>
__global__ __launch_bounds__(256)
void gemmS_k(const float* __restrict__ A,
             const _Float16* __restrict__ Ahp, const _Float16* __restrict__ Alp,
             const float* __restrict__ Bm,
             const _Float16* __restrict__ Bhp, const _Float16* __restrict__ Blp,
             float* __restrict__ Cout, const float* __restrict__ resid,
             int M, int N, int K, int ldb)
{
    constexpr int BM = 128, BK = 64;
    constexpr int WM = BM / 2, WN = BN / 2, MI = WM / 16, NJ = WN / 16;
    __shared__ alignas(16) _Float16 Ah[BM][BK], Al[BM][BK];
    __shared__ alignas(16) _Float16 Bh[BN][BK], Bl[BN][BK];
    const int tid  = threadIdx.x;
    int bxi = blockIdx.x, byi = blockIdx.y;
    swz2d(bxi, byi);
    const int bn0  = bxi * BN, bm0 = byi * BM;
    const int lane = tid & 63, wave = tid >> 6;
    const int l    = lane & 15, quad = lane >> 4;
    const int wm   = wave >> 1, wn = wave & 1;
    const int rsz  = (l & 7) << 3;          // read swizzle (16B slots)

    f32x4 accH[MI][NJ], accL[MI][NJ];
    #pragma unroll
    for (int mi = 0; mi < MI; ++mi)
        #pragma unroll
        for (int nj = 0; nj < NJ; ++nj) {
            accH[mi][nj] = (f32x4){0.f, 0.f, 0.f, 0.f};
            accL[mi][nj] = (f32x4){0.f, 0.f, 0.f, 0.f};
        }

    const int nK = K / BK;
    for (int kc = 0; kc < nK; ++kc) {
        __syncthreads();
        if constexpr (AB == 1) {
            #pragma unroll
            for (int i = 0; i < (BM * BK) / 2048; ++i) {
                int u = i * 256 + tid;
                int r = u >> 3, c8 = (u & 7) * 8;
                int cs = c8 ^ ((r & 7) << 3);
                *(f16x8*)&Ah[r][cs] =
                    *(const f16x8*)(Ahp + (size_t)(bm0 + r) * K + kc * BK + c8);
                *(f16x8*)&Al[r][cs] =
                    *(const f16x8*)(Alp + (size_t)(bm0 + r) * K + kc * BK + c8);
            }
        } else {
            #pragma unroll
            for (int i = 0; i < (BM * BK) / 2048; ++i) {
                int u = i * 256 + tid;
                int r = u >> 3, c8 = (u & 7) * 8;
                int cs = c8 ^ ((r & 7) << 3);
                const float* ga = A + (size_t)(bm0 + r) * K + kc * BK + c8;
                f16x8 hh, ll;
                #pragma unroll
                for (int j = 0; j < 8; ++j) {
                    float v = ga[j];
                    _Float16 h = (_Float16)v;
                    hh[j] = h;
                    ll[j] = (_Float16)((v - (float)h) * 2048.0f);
                }
                *(f16x8*)&Ah[r][cs] = hh;
                *(f16x8*)&Al[r][cs] = ll;
            }
        }
        if constexpr (WB == 1) {
            #pragma unroll
            for (int i = 0; i < (BN * BK) / 2048; ++i) {
                int u = i * 256 + tid;
                int n = u >> 3, c8 = (u & 7) * 8;
                int cs = c8 ^ ((n & 7) << 3);
                *(f16x8*)&Bh[n][cs] =
                    *(const f16x8*)(Bhp + (size_t)(bn0 + n) * K + kc * BK + c8);
                *(f16x8*)&Bl[n][cs] =
                    *(const f16x8*)(Blp + (size_t)(bn0 + n) * K + kc * BK + c8);
            }
        } else {
            #pragma unroll
            for (int i = 0; i < (BN * BK) / 2048; ++i) {
                int u = i * 256 + tid;
                int n = u % BN, k8 = (u / BN) * 8;
                int cs = k8 ^ ((n & 7) << 3);
                const float* gB = Bm + (size_t)(kc * BK + k8) * ldb + bn0 + n;
                f16x8 hh, ll;
                #pragma unroll
                for (int j = 0; j < 8; ++j) {
                    float v = gB[(size_t)j * ldb];
                    _Float16 h = (_Float16)v;
                    hh[j] = h;
                    ll[j] = (_Float16)((v - (float)h) * 2048.0f);
                }
                *(f16x8*)&Bh[n][cs] = hh;
                *(f16x8*)&Bl[n][cs] = ll;
            }
        }
        __syncthreads();
        #pragma unroll
        for (int ks = 0; ks < BK; ks += 32) {
            f16x8 ah[MI], al[MI], bh[NJ], bl[NJ];
            int col = (ks + quad * 8) ^ rsz;
            #pragma unroll
            for (int mi = 0; mi < MI; ++mi) {
                ah[mi] = *(const f16x8*)&Ah[wm * WM + mi * 16 + l][col];
                al[mi] = *(const f16x8*)&Al[wm * WM + mi * 16 + l][col];
            }
            #pragma unroll
            for (int nj = 0; nj < NJ; ++nj) {
                bh[nj] = *(const f16x8*)&Bh[wn * WN + nj * 16 + l][col];
                bl[nj] = *(const f16x8*)&Bl[wn * WN + nj * 16 + l][col];
            }
            #pragma unroll
            for (int mi = 0; mi < MI; ++mi)
                #pragma unroll
                for (int nj = 0; nj < NJ; ++nj) {
                    accH[mi][nj] = __builtin_amdgcn_mfma_f32_16x16x32_f16(
                        ah[mi], bh[nj], accH[mi][nj], 0, 0, 0);
                    accL[mi][nj] = __builtin_amdgcn_mfma_f32_16x16x32_f16(
                        ah[mi], bl[nj], accL[mi][nj], 0, 0, 0);
                    accL[mi][nj] = __builtin_amdgcn_mfma_f32_16x16x32_f16(
                        al[mi], bh[nj], accL[mi][nj], 0, 0, 0);
                }
        }
    }
    #pragma unroll
    for (int mi = 0; mi < MI; ++mi)
        #pragma unroll
        for (int nj = 0; nj < NJ; ++nj)
            #pragma unroll
            for (int r = 0; r < 4; ++r) {
                int row = bm0 + wm * WM + mi * 16 + quad * 4 + r;
                int col = bn0 + wn * WN + nj * 16 + l;
                float v = accH[mi][nj][r] + accL[mi][nj][r] * (1.0f / 2048.0f);
                size_t idx = (size_t)row * N + col;
                if constexpr (EPI == 0) Cout[idx] = v;
                else                    Cout[idx] = v + resid[idx];
            }
}

// ---------------------------------------------------------------------------
// Fused w1+w3 expert GEMM, ALL 9 experts (z = 0..8; 8 = shared via identity
// token list). XOR-swizzled unpadded LDS (conflict-free), XCD-swizzled grid
// so the 12 x-blocks sharing one A-row-panel stay on one XCD's L2.
// __launch_bounds__(256, 2): needs ~256 regs/thread; (256,3) spills (round 6).
// ---------------------------------------------------------------------------
__global__ __launch_bounds__(256, 2)
void gemm13_k(const unsigned short* __restrict__ A,
              const unsigned short* __restrict__ B1,
              const unsigned short* __restrict__ B3,
              unsigned short* __restrict__ T1o,
              const int* __restrict__ eidx,
              const int* __restrict__ counts,
              const int* __restrict__ offs,
              int N, long long bstr)
{
    constexpr int BM = 128, BK = 64;
    constexpr int MI = 4, NJ = 4;
    __shared__ alignas(16) unsigned short As[BM][BK];
    __shared__ alignas(16) unsigned short Bs1[BM][BK];
    __shared__ alignas(16) unsigned short Bs3[BM][BK];
    __shared__ int rowbuf[BM];
    const int tid  = threadIdx.x;
    int bxi = blockIdx.x, byi = blockIdx.y;
    swz2d(bxi, byi);
    const int bn0  = bxi * 128, bm0 = byi * 128;
    const int lane = tid & 63, wave = tid >> 6;
    const int l    = lane & 15, quad = lane >> 4;
    const int wm   = wave >> 1, wn = wave & 1;
    const int rs   = tid >> 3, c8 = (tid & 7) * 8;
    const int wsz  = (rs & 7) << 3;   // write swizzle
    const int rsz  = (l & 7) << 3;    // read swizzle

    int e = blockIdx.z;
    int cnt = counts[e];
    if (bm0 >= cnt) return;
    int crow0 = offs[e];
    B1 += (long long)e * bstr;
    B3 += (long long)e * bstr;
    if (tid < BM) {
        int rr = bm0 + tid;
        rowbuf[tid] = (rr < cnt) ? eidx[e * TOK + rr] : 0;
    }
    __syncthreads();

    f32x4 acc1[MI][NJ], acc3[MI][NJ];
    #pragma unroll
    for (int mi = 0; mi < MI; ++mi)
        #pragma unroll
        for (int nj = 0; nj < NJ; ++nj) {
            acc1[mi][nj] = (f32x4){0.f, 0.f, 0.f, 0.f};
            acc3[mi][nj] = (f32x4){0.f, 0.f, 0.f, 0.f};
        }

    const int nK = D_ / BK;   // 9
    u32x4 ra[4], rb1[4], rb3[4];
    #pragma unroll
    for (int i = 0; i < 4; ++i) {
        int r = i * 32 + rs;
        int arow = rowbuf[r];
        ra[i]  = *(const u32x4*)(A  + (size_t)arow * D_ + c8);
        rb1[i] = *(const u32x4*)(B1 + (size_t)(bn0 + r) * D_ + c8);
        rb3[i] = *(const u32x4*)(B3 + (size_t)(bn0 + r) * D_ + c8);
    }
    for (int kc = 0; kc < nK; ++kc) {
        __syncthreads();
        #pragma unroll
        for (int i = 0; i < 4; ++i) {
            int r = i * 32 + rs;
            *(u32x4*)&As[r][c8 ^ wsz]  = ra[i];
            *(u32x4*)&Bs1[r][c8 ^ wsz] = rb1[i];
            *(u32x4*)&Bs3[r][c8 ^ wsz] = rb3[i];
        }
        __syncthreads();
        if (kc + 1 < nK) {
            int ko = (kc + 1) * BK;
            #pragma unroll
            for (int i = 0; i < 4; ++i) {
                int r = i * 32 + rs;
                int arow = rowbuf[r];
                ra[i]  = *(const u32x4*)(A  + (size_t)arow * D_ + ko + c8);
                rb1[i] = *(const u32x4*)(B1 + (size_t)(bn0 + r) * D_ + ko + c8);
                rb3[i] = *(const u32x4*)(B3 + (size_t)(bn0 + r) * D_ + ko + c8);
            }
        }
        #pragma unroll
        for (int ks = 0; ks < BK; ks += 32) {
            bf16x8 af[MI], b1f[NJ], b3f[NJ];
            int col = (ks + quad * 8) ^ rsz;
            #pragma unroll
            for (int mi = 0; mi < MI; ++mi)
                af[mi] = __builtin_bit_cast(bf16x8,
                    *(const u32x4*)&As[wm * 64 + mi * 16 + l][col]);
            #pragma unroll
            for (int nj = 0; nj < NJ; ++nj) {
                b1f[nj] = __builtin_bit_cast(bf16x8,
                    *(const u32x4*)&Bs1[wn * 64 + nj * 16 + l][col]);
                b3f[nj] = __builtin_bit_cast(bf16x8,
                    *(const u32x4*)&Bs3[wn * 64 + nj * 16 + l][col]);
            }
            #pragma unroll
            for (int mi = 0; mi < MI; ++mi)
                #pragma unroll
                for (int nj = 0; nj < NJ; ++nj) {
                    acc1[mi][nj] = __builtin_amdgcn_mfma_f32_16x16x32_bf16(
                        af[mi], b1f[nj], acc1[mi][nj], 0, 0, 0);
                    acc3[mi][nj] = __builtin_amdgcn_mfma_f32_16x16x32_bf16(
                        af[mi], b3f[nj], acc3[mi][nj], 0, 0, 0);
                }
        }
    }
    #pragma unroll
    for (int mi = 0; mi < MI; ++mi)
        #pragma unroll
        for (int nj = 0; nj < NJ; ++nj)
            #pragma unroll
            for (int r = 0; r < 4; ++r) {
                int lrow = bm0 + wm * 64 + mi * 16 + quad * 4 + r;
                int col  = bn0 + wn * 64 + nj * 16 + l;
                float hv = b2f(f2b(acc1[mi][nj][r]));
                float g  = 0.5f * hv * (1.0f + erff(hv * 0.70710678118654752f));
                T1o[(size_t)(crow0 + lrow) * N + col] = f2b(g * acc3[mi][nj][r]);
            }
}

// ---------------------------------------------------------------------------
// w2 scatter GEMM, all 9 experts. BM=64, swizzled unpadded LDS (32.3 KB),
// XCD-swizzled grid. A rows compact, C scatter via rowbuf with atomicAdd.
// ---------------------------------------------------------------------------
__global__ __launch_bounds__(256)
void gemm2_k(const unsigned short* __restrict__ A,
             const unsigned short* __restrict__ Bm,
             float* __restrict__ Cout,
             const float* __restrict__ wgt,
             const int* __restrict__ eidx,
             const int* __restrict__ counts,
             const int* __restrict__ offs,
             int N, int K, int ldb, long long bstr)
{
    constexpr int BM = 64, BN = 192, BK = 64;
    constexpr int MI = 2, NJ = 6;                 // waves 2x2: WM=32, WN=96
    constexpr int AIT = (BM * BK) / 2048;         // 2
    constexpr int BIT = (BN * BK) / 2048;         // 6
    __shared__ alignas(16) unsigned short As[BM][BK];
    __shared__ alignas(16) unsigned short Bs[BN][BK];
    __shared__ int rowbuf[BM];
    const int tid  = threadIdx.x;
    int bxi = blockIdx.x, byi = blockIdx.y;
    swz2d(bxi, byi);
    const int bn0  = bxi * BN, bm0 = byi * BM;
    const int lane = tid & 63, wave = tid >> 6;
    const int l    = lane & 15, quad = lane >> 4;
    const int wm   = wave >> 1, wn = wave & 1;
    const int rs   = tid >> 3, c8 = (tid & 7) * 8;
    const int wsz  = (rs & 7) << 3;
    const int rsz  = (l & 7) << 3;

    int e = blockIdx.z;
    int cnt = counts[e];
    if (bm0 >= cnt) return;
    int crow0 = offs[e];
    int ebase = e * TOK;
    const unsigned short* Bt = Bm + (long long)e * bstr;
    if (tid < BM) {
        int rr = bm0 + tid;
        rowbuf[tid] = (rr < cnt) ? eidx[ebase + rr] : 0;
    }

    f32x4 acc[MI][NJ];
    #pragma unroll
    for (int mi = 0; mi < MI; ++mi)
        #pragma unroll
        for (int nj = 0; nj < NJ; ++nj) acc[mi][nj] = (f32x4){0.f, 0.f, 0.f, 0.f};

    const int nK = K / BK;
    u32x4 pa[AIT], pb[BIT];
    #pragma unroll
    for (int i = 0; i < AIT; ++i) {
        int r = i * 32 + rs;
        pa[i] = *(const u32x4*)(A + (size_t)(crow0 + bm0 + r) * K + c8);
    }
    #pragma unroll
    for (int i = 0; i < BIT; ++i) {
        int n = i * 32 + rs;
        pb[i] = *(const u32x4*)(Bt + (size_t)(bn0 + n) * ldb + c8);
    }
    for (int kc = 0; kc < nK; ++kc) {
        __syncthreads();
        #pragma unroll
        for (int i = 0; i < AIT; ++i) {
            int r = i * 32 + rs;
            *(u32x4*)&As[r][c8 ^ wsz] = pa[i];
        }
        #pragma unroll
        for (int i = 0; i < BIT; ++i) {
            int n = i * 32 + rs;
            *(u32x4*)&Bs[n][c8 ^ wsz] = pb[i];
        }
        __syncthreads();
        if (kc + 1 < nK) {
            int ko = (kc + 1) * BK;
            #pragma unroll
            for (int i = 0; i < AIT; ++i) {
                int r = i * 32 + rs;
                pa[i] = *(const u32x4*)(A + (size_t)(crow0 + bm0 + r) * K + ko + c8);
            }
            #pragma unroll
            for (int i = 0; i < BIT; ++i) {
                int n = i * 32 + rs;
                pb[i] = *(const u32x4*)(Bt + (size_t)(bn0 + n) * ldb + ko + c8);
            }
        }
        #pragma unroll
        for (int ks = 0; ks < BK; ks += 32) {
            bf16x8 af[MI], bfr[NJ];
            int col = (ks + quad * 8) ^ rsz;
            #pragma unroll
            for (int mi = 0; mi < MI; ++mi)
                af[mi] = __builtin_bit_cast(bf16x8,
                    *(const u32x4*)&As[wm * 32 + mi * 16 + l][col]);
            #pragma unroll
            for (int nj = 0; nj < NJ; ++nj)
                bfr[nj] = __builtin_bit_cast(bf16x8,
                    *(const u32x4*)&Bs[wn * 96 + nj * 16 + l][col]);
            #pragma unroll
            for (int mi = 0; mi < MI; ++mi)
                #pragma unroll
                for (int nj = 0; nj < NJ; ++nj)
                    acc[mi][nj] = __builtin_amdgcn_mfma_f32_16x16x32_bf16(
                        af[mi], bfr[nj], acc[mi][nj], 0, 0, 0);
        }
    }
    #pragma unroll
    for (int mi = 0; mi < MI; ++mi)
        #pragma unroll
        for (int nj = 0; nj < NJ; ++nj)
            #pragma unroll
            for (int r = 0; r < 4; ++r) {
                int lrow = bm0 + wm * 32 + mi * 16 + quad * 4 + r;
                if (lrow < cnt) {
                    int   tok = rowbuf[lrow - bm0];
                    float sc  = wgt[ebase + lrow];
                    int   col = bn0 + wn * 96 + nj * 16 + l;
                    atomicAdd(&Cout[(size_t)tok * N + col], sc * acc[mi][nj][r]);
                }
            }
}

// ---------------------------------------------------------------------------
// Expert-phase MFMA GEMM (fallback path only).
// ---------------------------------------------------------------------------
template<int BN, int EPI, int ROUTED, int WB>
__global__ __launch_bounds__(256)
void gemm_k(const unsigned short* __restrict__ A,
            const void* __restrict__ Bm,
            void* __restrict__ Cout,
            const void* __restrict__ resid,
            const float* __restrict__ wgt,
            const int* __restrict__ eidx,
            const int* __restrict__ counts,
            const int* __restrict__ offs,
            int M, int N, int K, int ldb, long long bstr)
{
    constexpr int BM = 128, BK = 64, LDT = BK + 8;
    constexpr int WM = BM / 2, WN = BN / 2, MI = WM / 16, NJ = WN / 16;
    constexpr int AIT = (BM * BK) / 2048, BIT = (BN * BK) / 2048;
    __shared__ alignas(16) unsigned short As[BM][LDT];
    __shared__ alignas(16) unsigned short Bs[BN][LDT];
    __shared__ int rowbuf[BM];
    const int tid  = threadIdx.x;
    const int bn0  = blockIdx.x * BN, bm0 = blockIdx.y * BM;
    const int lane = tid & 63, wave = tid >> 6;
    const int l    = lane & 15, quad = lane >> 4;
    const int wm   = wave >> 1, wn = wave & 1;

    int cnt = M, crow0 = 0, ebase = 0;
    long long boff = 0;
    if constexpr (ROUTED) {
        int e = blockIdx.z;
        cnt = counts[e];
        if (bm0 >= cnt) return;
        crow0 = offs[e];
        ebase = e * TOK;
        boff  = (long long)e * bstr;
        if (tid < BM) {
            int rr = bm0 + tid;
            rowbuf[tid] = (rr < cnt) ? eidx[ebase + rr] : 0;
        }
        __syncthreads();
    }

    f32x4 acc[MI][NJ];
    #pragma unroll
    for (int mi = 0; mi < MI; ++mi)
        #pragma unroll
        for (int nj = 0; nj < NJ; ++nj) acc[mi][nj] = (f32x4){0.f, 0.f, 0.f, 0.f};

    const int nK = K / BK;
    for (int kc = 0; kc < nK; ++kc) {
        __syncthreads();
        #pragma unroll
        for (int i = 0; i < AIT; ++i) {
            int u = i * 256 + tid;
            int r = u >> 3, c8 = (u & 7) * 8;
            int arow;
            if constexpr (ROUTED && EPI != 5) arow = rowbuf[r];
            else if constexpr (ROUTED)        arow = crow0 + bm0 + r;
            else                              arow = bm0 + r;
            *(u32x4*)&As[r][c8] =
                *(const u32x4*)(A + (size_t)arow * K + kc * BK + c8);
        }
        const float* Bf = (const float*)Bm + boff;
        #pragma unroll
        for (int i = 0; i < BIT; ++i) {
            int u = i * 256 + tid;
            int n = u % BN, k8 = (u / BN) * 8;
            const float* gB = Bf + (size_t)(kc * BK + k8) * ldb + bn0 + n;
            u16x8 tmp;
            #pragma unroll
            for (int j = 0; j < 8; ++j) tmp[j] = f2b(gB[(size_t)j * ldb]);
            *(u16x8*)&Bs[n][k8] = tmp;
        }
        __syncthreads();
        #pragma unroll
        for (int ks = 0; ks < BK; ks += 32) {
            bf16x8 af[MI], bfr[NJ];
            #pragma unroll
            for (int mi = 0; mi < MI; ++mi)
                af[mi] = __builtin_bit_cast(bf16x8,
                    *(const u32x4*)&As[wm * WM + mi * 16 + l][ks + quad * 8]);
            #pragma unroll
            for (int nj = 0; nj < NJ; ++nj)
                bfr[nj] = __builtin_bit_cast(bf16x8,
                    *(const u32x4*)&Bs[wn * WN + nj * 16 + l][ks + quad * 8]);
            #pragma unroll
            for (int mi = 0; mi < MI; ++mi)
                #pragma unroll
                for (int nj = 0; nj < NJ; ++nj)
                    acc[mi][nj] = __builtin_amdgcn_mfma_f32_16x16x32_bf16(
                        af[mi], bfr[nj], acc[mi][nj], 0, 0, 0);
        }
    }
    #pragma unroll
    for (int mi = 0; mi < MI; ++mi)
        #pragma unroll
        for (int nj = 0; nj < NJ; ++nj)
            #pragma unroll
            for (int r = 0; r < 4; ++r) {
                int lrow = bm0 + wm * WM + mi * 16 + quad * 4 + r;
                int col  = bn0 + wn * WN + nj * 16 + l;
                float v = acc[mi][nj][r];
                if constexpr (EPI == 0) {
                    ((unsigned short*)Cout)[(size_t)(crow0 + lrow) * N + col] = f2b(v);
                } else if constexpr (EPI == 3) {
                    size_t ix = (size_t)(crow0 + lrow) * N + col;
                    float hv = b2f(((const unsigned short*)resid)[ix]);
                    float g = 0.5f * hv * (1.0f + erff(hv * 0.70710678118654752f));
                    ((unsigned short*)Cout)[ix] = f2b(g * v);
                } else if constexpr (EPI == 4) {
                    ((float*)Cout)[(size_t)lrow * N + col] += v;
                } else {
                    if (lrow < cnt) {
                        int   tok = rowbuf[lrow - bm0];
                        float sc  = wgt[ebase + lrow];
                        atomicAdd(&((float*)Cout)[(size_t)tok * N + col], sc * v);
                    }
                }
            }
}

// ---------------------------------------------------------------------------
// Per-position cross-head attention, full fp32 (unchanged).
// ---------------------------------------------------------------------------
__global__ __launch_bounds__(256)
void attn32_k(const float* __restrict__ q,   // [ct][H][64]
              const float* __restrict__ kv,  // [ct][H][128]
              float* __restrict__ ao,        // [(b*H+h)*S+s][64]
              int pos0)
{
    int pl   = blockIdx.x * 4 + (threadIdx.x >> 6);
    int lane = threadIdx.x & 63;
    int pos  = pos0 + pl;
    int b = pos >> 11, s = pos & 2047;

    const float* qp  = q  + (size_t)pl * 576;
    const float* kvp = kv + (size_t)pl * 1152;

    int i = lane >> 1;
    float theta = powf(10000.f, -(float)i * (1.0f / 32.0f));
    float sn, cs;
    sincosf((float)s * theta, &sn, &cs);

    float qr[H_], kr[H_], vr[H_];
    #pragma unroll
    for (int h = 0; h < H_; ++h) {
        float qv = qp[h * 64 + lane];
        float qo = __shfl_xor(qv, 1, 64);
        qr[h] = (lane & 1) ? (qo * sn + qv * cs) : (qv * cs - qo * sn);
        kr[h] = kvp[h * 128 + lane];
        vr[h] = kvp[h * 128 + 64 + lane];
    }

    #pragma unroll
    for (int h = 0; h < H_; ++h) {
        float sc[H_];
        #pragma unroll
        for (int t = 0; t < H_; ++t) {
            float p = qr[h] * kr[t];
            #pragma unroll
            for (int d = 1; d < 64; d <<= 1) p += __shfl_xor(p, d, 64);
            sc[t] = p * 0.125f;
        }
        float mx = sc[0];
        #pragma unroll
        for (int t = 1; t < H_; ++t) mx = fmaxf(mx, sc[t]);
        float ssum = 0.f;
        #pragma unroll
        for (int t = 0; t < H_; ++t) { sc[t] = __expf(sc[t] - mx); ssum += sc[t]; }
        float inv = 1.0f / ssum;
        float ov = 0.f;
        #pragma unroll
        for (int t = 0; t < H_; ++t) ov += sc[t] * vr[t];
        ao[((size_t)(b * H_ + h) * S_ + s) * 64 + lane] = ov * inv;
    }
}

// ---------------------------------------------------------------------------
// Gating pass 1: per-token top-2 (no atomics). 4 tokens/block, 1 wave each.
// ---------------------------------------------------------------------------
__global__ __launch_bounds__(256)
void gate1_k(const float* __restrict__ x2,
             const float* __restrict__ gw,
             float* __restrict__ tw,    // [TOK][2]
             int*   __restrict__ tsel)  // [TOK]
{
    int tok  = blockIdx.x * 4 + (threadIdx.x >> 6);
    int lane = threadIdx.x & 63;
    float acc[8];
    #pragma unroll
    for (int e = 0; e < 8; ++e) acc[e] = 0.f;
    float ss = 0.f;
    for (int d = lane; d < D_; d += 64) {
        float xv = x2[(size_t)tok * D_ + d];
        ss += xv * xv;
        const float* wr = gw + (size_t)d * 8;
        #pragma unroll
        for (int e = 0; e < 8; ++e) acc[e] += xv * wr[e];
    }
    #pragma unroll
    for (int d = 1; d < 64; d <<= 1) ss += __shfl_xor(ss, d, 64);
    #pragma unroll
    for (int e = 0; e < 8; ++e)
        #pragma unroll
        for (int d = 1; d < 64; d <<= 1) acc[e] += __shfl_xor(acc[e], d, 64);
    if (lane == 0) {
        float rms = rsqrtf(ss / (float)D_ + 1e-6f);
        #pragma unroll
        for (int e = 0; e < 8; ++e) acc[e] *= rms;
        float mx = acc[0];
        #pragma unroll
        for (int e = 1; e < 8; ++e) mx = fmaxf(mx, acc[e]);
        float g[8], ssum = 0.f;
        #pragma unroll
        for (int e = 0; e < 8; ++e) { g[e] = __expf(acc[e] - mx); ssum += g[e]; }
        #pragma unroll
        for (int e = 0; e < 8; ++e) g[e] /= ssum;
        int i1 = 0;
        #pragma unroll
        for (int e = 1; e < 8; ++e) if (g[e] > g[i1]) i1 = e;
        int i2 = -1;
        #pragma unroll
        for (int e = 0; e < 8; ++e)
            if (e != i1 && (i2 < 0 || g[e] > g[i2])) i2 = e;
        float s2 = g[i1] + g[i2];
        tw[(size_t)tok * 2 + 0] = g[i1] / s2;
        tw[(size_t)tok * 2 + 1] = g[i2] / s2;
        tsel[tok] = i1 | (i2 << 8);
    }
}

// ---------------------------------------------------------------------------
// Gating pass 2: deterministic atomic-free compaction. One block per expert.
// Expert 8 (shared) gets the identity list with weight 1.0.
// ---------------------------------------------------------------------------
__global__ __launch_bounds__(256)
void gate2_k(const int*   __restrict__ tsel,
             const float* __restrict__ tw,
             float* __restrict__ wgt,     // [9][TOK]
             int*   __restrict__ eidx,    // [9][TOK]
             int*   __restrict__ counts)  // [9]
{
    int e    = blockIdx.x;   // 0..8
    int tid  = threadIdx.x;
    int lane = tid & 63, wv = tid >> 6;
    __shared__ int wtot[4];
    int base = 0;
    for (int t0 = 0; t0 < TOK; t0 += 256) {
        int tok = t0 + tid;
        int hit = 0; float w = 0.f;
        if (e == E_) { hit = 1; w = 1.0f; }
        else {
            int s = tsel[tok];
            if ((s & 255) == e)      { hit = 1; w = tw[(size_t)tok * 2 + 0]; }
            else if ((s >> 8) == e)  { hit = 1; w = tw[(size_t)tok * 2 + 1]; }
        }
        unsigned long long m = __ballot(hit);
        int pre = __popcll(m & ((1ull << lane) - 1ull));
        if (lane == 0) wtot[wv] = __popcll(m);
        __syncthreads();
        int off = base;
        for (int q = 0; q < wv; ++q) off += wtot[q];
        if (hit) {
            int p = off + pre;
            eidx[e * TOK + p] = tok;
            wgt [e * TOK + p] = w;
        }
        base += wtot[0] + wtot[1] + wtot[2] + wtot[3];
        __syncthreads();   // protect wtot before next chunk overwrites it
    }
    if (tid == 0) counts[e] = base;
}

// 128-padded exclusive prefix of counts -> per-expert compact row offsets
__global__ void offs_k(const int* __restrict__ counts, int* __restrict__ offs) {
    if (threadIdx.x == 0) {
        int run = 0;
        for (int e = 0; e < 9; ++e) {
            offs[e] = run;
            run += ((counts[e] + 127) >> 7) << 7;
        }
    }
}

// ---------------------------------------------------------------------------
extern "C" void kernel_launch(void* const* d_in, const int* in_sizes, int n_in,
                              void* d_out, int out_size, void* d_ws, size_t ws_size,
                              hipStream_t stream)
{
    const float* x      = (const float*)d_in[0];
    const float* q_w    = (const float*)d_in[1];
    const float* kv_w   = (const float*)d_in[2];
    const float* o_w    = (const float*)d_in[3];
    const float* gate_w = (const float*)d_in[4];
    const float* w1     = (const float*)d_in[5];
    const float* w2     = (const float*)d_in[6];
    const float* w3     = (const float*)d_in[7];
    const float* sw1    = (const float*)d_in[8];
    const float* sw2    = (const float*)d_in[9];
    const float* sw3    = (const float*)d_in[10];
    float* out = (float*)d_out;   // fp32: holds x2, then accumulates experts

    const size_t XN = (size_t)TOK * D_ * 2;   //  9,437,184 (bf16 TOK x D)
    char* ws = (char*)d_ws;
    unsigned short* xn16 = (unsigned short*)ws;          // [0, XN)      persists
    float*          ao32 = (float*)(ws + XN);            // [XN, 3XN)    phase A

    // split attention-path weights: qh/ql [D][D], kvh/kvl [1152][D], oh/ol [D][D]
    const size_t QE = (size_t)D_ * D_, KVE = (size_t)1152 * D_;
    const size_t SW = (2 * QE + KVE) * 2 * 2;   // 5,308,416 bytes
    _Float16* qwh  = (_Float16*)(ws + 3 * XN);
    _Float16* qwl  = qwh  + QE;
    _Float16* kvwh = qwl  + QE;
    _Float16* kvwl = kvwh + KVE;
    _Float16* owh  = kvwl + KVE;
    _Float16* owl  = owh  + QE;

    // phase-A chunking: footprint = 3XN + (convA?SW:0) + 8XN/TC
    bool convA = true;
    int TC = -1;
    for (int pass = 0; pass < 2; ++pass) {
        size_t base = 3 * XN + (convA ? SW : 0);
        if      (base + 8*XN    <= ws_size) { TC = 1; break; }
        else if (base + 8*XN/2  <= ws_size) { TC = 2; break; }
        else if (base + 8*XN/4  <= ws_size) { TC = 4; break; }
        else if (base + 8*XN/8  <= ws_size) { TC = 8; break; }
        else if (base + 8*XN/16 <= ws_size) { TC = 16; break; }
        else if (base + 8*XN/32 <= ws_size) { TC = 32; break; }
        else if (base + 8*XN/64 <= ws_size) { TC = 64; break; }
        convA = false;  // retry without split weights
    }
    if (TC < 0) { convA = false; TC = 64; }
    const int CT = TOK / TC;
    // chunk area: (convA) xnh/xnl f16 pair (= 2XN/TC total, same as fp32 xn32c)
    //             (else)  xn32c fp32
    char* chunk0 = ws + 3*XN + (convA ? SW : 0);
    _Float16* xnh  = (_Float16*)chunk0;
    _Float16* xnl  = xnh + (size_t)CT * D_;
    float*    xn32c = (float*)chunk0;
    float*    qc   = (float*)(chunk0 + (size_t)CT * D_ * 4);
    float*    kvc  = qc + (size_t)CT * D_;

    // expert-phase layout (reuses the ao32/chunk space, dead after step 2):
    int*   counts = (int*)(ws + XN);
    int*   offs   = counts + 16;
    float* wgt    = (float*)(ws + XN + 256);
    int*   eidx   = (int*)  (ws + XN + 256 + (size_t)9 * TOK * 4);
    float* tw     = (float*)(ws + XN + 256 + (size_t)9 * TOK * 8);
    int*   tsel   = (int*)  (ws + XN + 256 + (size_t)9 * TOK * 8 + (size_t)TOK * 8);
    const size_t fixedG = XN + 256 + (size_t)9 * TOK * 8 + (size_t)TOK * 12;

    const size_t WELEM = (size_t)D_ * FF_;          // 884736 elems per matrix
    const size_t WSZ   = 27 * WELEM * 2;            // 9 slots x (w1,w3,w2) bf16

    bool conv; int FC;
    if      (fixedG + WSZ + (size_t)T1ALL * FF_     * 2 <= ws_size) { conv = true;  FC = 1; }
    else if (fixedG + WSZ + (size_t)T1ALL * (FF_/2) * 2 <= ws_size) { conv = true;  FC = 2; }
    else if (fixedG + WSZ + (size_t)T1ALL * (FF_/4) * 2 <= ws_size) { conv = true;  FC = 4; }
    else if (fixedG + (size_t)T1ROWS * FF_     * 2 <= ws_size)      { conv = false; FC = 1; }
    else if (fixedG + (size_t)T1ROWS * (FF_/2) * 2 <= ws_size)      { conv = false; FC = 2; }
    else                                                            { conv = false; FC = 4; }
    const int FFc = FF_ / FC;

    unsigned short* wt1 = (unsigned short*)(ws + fixedG);   // 9 slots
    unsigned short* wt3 = wt1 + 9 * WELEM;                  // 9 slots
    unsigned short* wt2 = wt3 + 9 * WELEM;                  // 9 slots
    unsigned short* t1  = (unsigned short*)(ws + fixedG + (conv ? WSZ : 0));

    // 0) split attention-path weights once (bit-identical values)
    if (convA) {
        convS_k<<<dim3(D_/64,  D_/64), 256, 0, stream>>>(q_w,  qwh,  qwl,  D_, D_);
        convS_k<<<dim3(1152/64, D_/64), 256, 0, stream>>>(kv_w, kvwh, kvwl, D_, 1152);
        convS_k<<<dim3(D_/64,  D_/64), 256, 0, stream>>>(o_w,  owh,  owl,  D_, D_);
    }
    // 1) phase A per chunk: xn split (f16 pair), q, kv (split GEMM), attention
    for (int t = 0; t < TC; ++t) {
        const float* xc = x + (size_t)t * CT * D_;
        if (convA) {
            rmssplit_k<<<CT, 256, 0, stream>>>(xc, xnh, xnl);
            gemmS_k<64, 0, 1, 1><<<dim3(D_ / 64, CT / 128), 256, 0, stream>>>(
                nullptr, xnh, xnl, nullptr, qwh, qwl, qc, nullptr, CT, D_, D_, D_);
            gemmS_k<64, 0, 1, 1><<<dim3(1152 / 64, CT / 128), 256, 0, stream>>>(
                nullptr, xnh, xnl, nullptr, kvwh, kvwl, kvc, nullptr, CT, 1152, D_, D_);
        } else {
            rms32_k<<<CT, 256, 0, stream>>>(xc, xn32c);
            gemmS_k<64, 0, 0, 0><<<dim3(D_ / 64, CT / 128), 256, 0, stream>>>(
                xn32c, nullptr, nullptr, q_w, nullptr, nullptr, qc, nullptr, CT, D_, D_, D_);
            gemmS_k<64, 0, 0, 0><<<dim3(1152 / 64, CT / 128), 256, 0, stream>>>(
                xn32c, nullptr, nullptr, kv_w, nullptr, nullptr, kvc, nullptr, CT, 1152, D_, 1152);
        }
        attn32_k<<<CT / 4, 256, 0, stream>>>(qc, kvc, ao32, t * CT);
    }
    // 2) x2 = ao @ o_w + x  -> d_out (fp32, split GEMM; A stays fp32)
    if (convA)
        gemmS_k<64, 1, 1, 0><<<dim3(D_ / 64, TOK / 128), 256, 0, stream>>>(
            ao32, nullptr, nullptr, nullptr, owh, owl, out, x, TOK, D_, D_, D_);
    else
        gemmS_k<64, 1, 0, 0><<<dim3(D_ / 64, TOK / 128), 256, 0, stream>>>(
            ao32, nullptr, nullptr, o_w, nullptr, nullptr, out, x, TOK, D_, D_, D_);
    // 3) xn16 = rmsnorm(x2) (bf16, expert input)
    rmsnorm_k<<<TOK, 256, 0, stream>>>(out, xn16);
    // 4) gating (expert 8 = shared identity list)
    gate1_k<<<TOK / 4, 256, 0, stream>>>(out, gate_w, tw, tsel);
    gate2_k<<<E_ + 1, 256, 0, stream>>>(tsel, tw, wgt, eidx, counts);
    offs_k<<<1, 64, 0, stream>>>(counts, offs);
    // 4b) weight convert+transpose fp32 -> bf16 [N][K], 9 slots each
    if (conv) {
        convw13_k<<<dim3(FF_/64, D_/64, 18), 256, 0, stream>>>(
            w1, w3, sw1, sw3, wt1, wt3);
        convw2_k<<<dim3(D_/64, FF_/64, 9), 256, 0, stream>>>(w2, sw2, wt2);
    }
    // 5) all 9 experts in 2 launches per FF chunk (shared = expert 8)
    for (int c = 0; c < FC; ++c) {
        if (conv) {
            gemm13_k<<<dim3(FFc / 128, TOK / 128, 9), 256, 0, stream>>>(
                xn16, wt1 + (size_t)c * FFc * D_, wt3 + (size_t)c * FFc * D_,
                t1, eidx, counts, offs, FFc, (long long)WELEM);
            gemm2_k<<<dim3(D_ / 192, TOK / 64, 9), 256, 0, stream>>>(
                t1, wt2 + (size_t)c * FFc, out, wgt, eidx, counts, offs,
                D_, FFc, FF_, (long long)WELEM);
        } else {
            const float* w1c = w1 + (size_t)c * FFc;
            const float* w3c = w3 + (size_t)c * FFc;
            const float* w2c = w2 + (size_t)c * FFc * D_;
            gemm_k<128, 0, 1, 0><<<dim3(FFc / 128, TOK / 128, E_), 256, 0, stream>>>(
                xn16, w1c, t1, nullptr, wgt, eidx, counts, offs,
                TOK, FFc, D_, FF_, (long long)D_ * FF_);
            gemm_k<128, 3, 1, 0><<<dim3(FFc / 128, TOK / 128, E_), 256, 0, stream>>>(
                xn16, w3c, t1, t1, wgt, eidx, counts, offs,
                TOK, FFc, D_, FF_, (long long)D_ * FF_);
            gemm_k<64, 5, 1, 0><<<dim3(D_ / 64, TOK / 128, E_), 256, 0, stream>>>(
                t1, w2c, out, nullptr, wgt, eidx, counts, offs,
                TOK, D_, FFc, D_, (long long)FF_ * D_);
            gemm_k<128, 0, 0, 0><<<dim3(FFc / 128, TOK / 128), 256, 0, stream>>>(
                xn16, sw1 + (size_t)c * FFc, t1, nullptr, nullptr, nullptr, nullptr, nullptr,
                TOK, FFc, D_, FF_, 0);
            gemm_k<128, 3, 0, 0><<<dim3(FFc / 128, TOK / 128), 256, 0, stream>>>(
                xn16, sw3 + (size_t)c * FFc, t1, t1, nullptr, nullptr, nullptr, nullptr,
                TOK, FFc, D_, FF_, 0);
            gemm_k<64, 4, 0, 0><<<dim3(D_ / 64, TOK / 128), 256, 0, stream>>>(
                t1, sw2 + (size_t)c * FFc * D_, out, nullptr, nullptr, nullptr, nullptr, nullptr,
                TOK, D_, FFc, D_, 0);
        }
    }
}

// Round 10
// 621.138 us; speedup vs baseline: 1.4127x; 1.4127x over previous
//
#include <hip/hip_runtime.h>
#include <math.h>

#define B_  4
#define S_  2048
#define D_  576
#define H_  9
#define HD_ 64
#define FF_ 1536
#define E_  8
#define TOK (B_*S_)   // 8192
// compact routed rows: 2*TOK + 8*127 pad rounded -> 17408; +TOK shared -> 25600
#define T1ROWS 17408
#define T1ALL  25600

typedef unsigned int   u32x4  __attribute__((ext_vector_type(4)));
typedef unsigned short u16x8  __attribute__((ext_vector_type(8)));
typedef __bf16         bf16x8 __attribute__((ext_vector_type(8)));
typedef _Float16       f16x8  __attribute__((ext_vector_type(8)));
typedef float          f32x4  __attribute__((ext_vector_type(4)));

__device__ __forceinline__ float b2f(unsigned short u) {
    union { unsigned int i; float f; } v; v.i = ((unsigned int)u) << 16; return v.f;
}
__device__ __forceinline__ unsigned short f2b(float f) {
    unsigned int u = __builtin_bit_cast(unsigned int, f);
    unsigned int r = 0x7fffu + ((u >> 16) & 1u);
    return (unsigned short)((u + r) >> 16);
}

// NOTE (round 9 post-mortem): an XCD-aware (x,y) block swizzle here REGRESSED
// 2.5x. With per-expert early-exit (bm0 >= cnt), liveness correlates with the
// logical index, and the swizzle made liveness correlate with orig%8 — i.e.
// ALL live blocks landed on 2 of 8 XCDs (Occupancy 19% -> 6.8%). Do not
// reintroduce a dispatch-order permutation on grids with early-exit.

// ---------------------------------------------------------------------------
// RMSNorm fp32 -> bf16 (for the expert phase)
// ---------------------------------------------------------------------------
__global__ __launch_bounds__(256)
void rmsnorm_k(const float* __restrict__ x, unsigned short* __restrict__ xn) {
    int tok = blockIdx.x, tid = threadIdx.x;
    const float* xr = x + (size_t)tok * D_;
    float v0 = xr[tid];
    float v1 = xr[tid + 256];
    float v2 = (tid < D_ - 512) ? xr[tid + 512] : 0.f;
    float ss = v0*v0 + v1*v1 + v2*v2;
    #pragma unroll
    for (int d = 1; d < 64; d <<= 1) ss += __shfl_xor(ss, d, 64);
    __shared__ float red[4];
    if ((tid & 63) == 0) red[tid >> 6] = ss;
    __syncthreads();
    float tot = red[0] + red[1] + red[2] + red[3];
    float rms = rsqrtf(tot / (float)D_ + 1e-6f);
    unsigned short* orow = xn + (size_t)tok * D_;
    orow[tid]       = f2b(v0 * rms);
    orow[tid + 256] = f2b(v1 * rms);
    if (tid < D_ - 512) orow[tid + 512] = f2b(v2 * rms);
}

// RMSNorm fp32 -> fp32, chunk-local output (fallback path)
__global__ __launch_bounds__(256)
void rms32_k(const float* __restrict__ x, float* __restrict__ xn) {
    int tok = blockIdx.x, tid = threadIdx.x;
    const float* xr = x + (size_t)tok * D_;
    float v0 = xr[tid];
    float v1 = xr[tid + 256];
    float v2 = (tid < D_ - 512) ? xr[tid + 512] : 0.f;
    float ss = v0*v0 + v1*v1 + v2*v2;
    #pragma unroll
    for (int d = 1; d < 64; d <<= 1) ss += __shfl_xor(ss, d, 64);
    __shared__ float red[4];
    if ((tid & 63) == 0) red[tid >> 6] = ss;
    __syncthreads();
    float tot = red[0] + red[1] + red[2] + red[3];
    float rms = rsqrtf(tot / (float)D_ + 1e-6f);
    float* orow = xn + (size_t)tok * D_;
    orow[tid]       = v0 * rms;
    orow[tid + 256] = v1 * rms;
    if (tid < D_ - 512) orow[tid + 512] = v2 * rms;
}

// RMSNorm fp32 -> pre-split f16 pair (Ah, Al*2048), chunk-local. Rounding is
// bit-identical to the old in-loop split of the fp32 xn32c value.
__global__ __launch_bounds__(256)
void rmssplit_k(const float* __restrict__ x,
                _Float16* __restrict__ xh, _Float16* __restrict__ xl) {
    int tok = blockIdx.x, tid = threadIdx.x;
    const float* xr = x + (size_t)tok * D_;
    float v0 = xr[tid];
    float v1 = xr[tid + 256];
    float v2 = (tid < D_ - 512) ? xr[tid + 512] : 0.f;
    float ss = v0*v0 + v1*v1 + v2*v2;
    #pragma unroll
    for (int d = 1; d < 64; d <<= 1) ss += __shfl_xor(ss, d, 64);
    __shared__ float red[4];
    if ((tid & 63) == 0) red[tid >> 6] = ss;
    __syncthreads();
    float tot = red[0] + red[1] + red[2] + red[3];
    float rms = rsqrtf(tot / (float)D_ + 1e-6f);
    _Float16* hr = xh + (size_t)tok * D_;
    _Float16* lr = xl + (size_t)tok * D_;
    {
        float v = v0 * rms; _Float16 h = (_Float16)v;
        hr[tid] = h; lr[tid] = (_Float16)((v - (float)h) * 2048.0f);
    }
    {
        float v = v1 * rms; _Float16 h = (_Float16)v;
        hr[tid + 256] = h; lr[tid + 256] = (_Float16)((v - (float)h) * 2048.0f);
    }
    if (tid < D_ - 512) {
        float v = v2 * rms; _Float16 h = (_Float16)v;
        hr[tid + 512] = h; lr[tid + 512] = (_Float16)((v - (float)h) * 2048.0f);
    }
}

// ---------------------------------------------------------------------------
// Merged weight convert+transpose, w1/w3 family: fp32 [D][FF] -> bf16 [FF][D].
// z: 0..7 = w1 experts, 8 = sw1, 9..16 = w3 experts, 17 = sw3.
// ---------------------------------------------------------------------------
__global__ __launch_bounds__(256)
void convw13_k(const float* __restrict__ w1, const float* __restrict__ w3,
               const float* __restrict__ sw1, const float* __restrict__ sw3,
               unsigned short* __restrict__ wt1, unsigned short* __restrict__ wt3)
{
    const size_t WE = (size_t)D_ * FF_;
    int z = blockIdx.z;
    const float* s; unsigned short* d;
    if (z < 8)       { s = w1 + (size_t)z * WE;       d = wt1 + (size_t)z * WE; }
    else if (z == 8) { s = sw1;                        d = wt1 + 8 * WE; }
    else if (z < 17) { s = w3 + (size_t)(z - 9) * WE;  d = wt3 + (size_t)(z - 9) * WE; }
    else             { s = sw3;                        d = wt3 + 8 * WE; }
    const int K = D_, N = FF_;
    __shared__ unsigned short t[64][72];
    int n0 = blockIdx.x * 64, k0 = blockIdx.y * 64;
    int tx = threadIdx.x & 63, ty = threadIdx.x >> 6;
    #pragma unroll
    for (int i = 0; i < 16; ++i) {
        int k = i * 4 + ty;
        t[k][tx] = f2b(s[(size_t)(k0 + k) * N + n0 + tx]);
    }
    __syncthreads();
    int r = threadIdx.x >> 3, c8 = (threadIdx.x & 7) * 8;
    #pragma unroll
    for (int it = 0; it < 2; ++it, r += 32) {
        u16x8 v;
        #pragma unroll
        for (int j = 0; j < 8; ++j) v[j] = t[c8 + j][r];
        *(u16x8*)&d[(size_t)(n0 + r) * K + k0 + c8] = v;
    }
}

// w2 family: fp32 [FF][D] -> bf16 [D][FF]. z: 0..7 = w2 experts, 8 = sw2.
__global__ __launch_bounds__(256)
void convw2_k(const float* __restrict__ w2, const float* __restrict__ sw2,
              unsigned short* __restrict__ wt2)
{
    const size_t WE = (size_t)D_ * FF_;
    int z = blockIdx.z;
    const float* s = (z < 8) ? w2 + (size_t)z * WE : sw2;
    unsigned short* d = wt2 + (size_t)z * WE;
    const int K = FF_, N = D_;
    __shared__ unsigned short t[64][72];
    int n0 = blockIdx.x * 64, k0 = blockIdx.y * 64;
    int tx = threadIdx.x & 63, ty = threadIdx.x >> 6;
    #pragma unroll
    for (int i = 0; i < 16; ++i) {
        int k = i * 4 + ty;
        t[k][tx] = f2b(s[(size_t)(k0 + k) * N + n0 + tx]);
    }
    __syncthreads();
    int r = threadIdx.x >> 3, c8 = (threadIdx.x & 7) * 8;
    #pragma unroll
    for (int it = 0; it < 2; ++it, r += 32) {
        u16x8 v;
        #pragma unroll
        for (int j = 0; j < 8; ++j) v[j] = t[c8 + j][r];
        *(u16x8*)&d[(size_t)(n0 + r) * K + k0 + c8] = v;
    }
}

// ---------------------------------------------------------------------------
// Split-weight convert+transpose for the high-precision path:
// fp32 [K][N] -> f16 Wh[N][K] and Wl[N][K] (= (v-h)*2048).
// ---------------------------------------------------------------------------
__global__ __launch_bounds__(256)
void convS_k(const float* __restrict__ src,
             _Float16* __restrict__ dh, _Float16* __restrict__ dl,
             int K, int N)
{
    __shared__ _Float16 th[64][72], tl[64][72];
    int n0 = blockIdx.x * 64, k0 = blockIdx.y * 64;
    int tx = threadIdx.x & 63, ty = threadIdx.x >> 6;
    #pragma unroll
    for (int i = 0; i < 16; ++i) {
        int k = i * 4 + ty;
        float v = src[(size_t)(k0 + k) * N + n0 + tx];
        _Float16 h = (_Float16)v;
        th[k][tx] = h;
        tl[k][tx] = (_Float16)((v - (float)h) * 2048.0f);
    }
    __syncthreads();
    int r = threadIdx.x >> 3, c8 = (threadIdx.x & 7) * 8;
    #pragma unroll
    for (int it = 0; it < 2; ++it, r += 32) {
        f16x8 vh, vl;
        #pragma unroll
        for (int j = 0; j < 8; ++j) { vh[j] = th[c8 + j][r]; vl[j] = tl[c8 + j][r]; }
        *(f16x8*)&dh[(size_t)(n0 + r) * K + k0 + c8] = vh;
        *(f16x8*)&dl[(size_t)(n0 + r) * K + k0 + c8] = vl;
    }
}

// ---------------------------------------------------------------------------
// High-precision GEMM via scaled fp16 split. XOR-swizzled unpadded LDS.
// AB=1: A pre-split f16 (Ahp/Alp) -> vector staging.
// ---------------------------------------------------------------------------
template<int BN, int EPI, int WB, int AB>
__global__ __launch_bounds__(256)
void gemmS_k(const float* __restrict__ A,
             const _Float16* __restrict__ Ahp, const _Float16* __restrict__ Alp,
             const float* __restrict__ Bm,
             const _Float16* __restrict__ Bhp, const _Float16* __restrict__ Blp,
             float* __restrict__ Cout, const float* __restrict__ resid,
             int M, int N, int K, int ldb)
{
    constexpr int BM = 128, BK = 64;
    constexpr int WM = BM / 2, WN = BN / 2, MI = WM / 16, NJ = WN / 16;
    __shared__ alignas(16) _Float16 Ah[BM][BK], Al[BM][BK];
    __shared__ alignas(16) _Float16 Bh[BN][BK], Bl[BN][BK];
    const int tid  = threadIdx.x;
    const int bn0  = blockIdx.x * BN, bm0 = blockIdx.y * BM;
    const int lane = tid & 63, wave = tid >> 6;
    const int l    = lane & 15, quad = lane >> 4;
    const int wm   = wave >> 1, wn = wave & 1;
    const int rsz  = (l & 7) << 3;          // read swizzle (16B slots)

    f32x4 accH[MI][NJ], accL[MI][NJ];
    #pragma unroll
    for (int mi = 0; mi < MI; ++mi)
        #pragma unroll
        for (int nj = 0; nj < NJ; ++nj) {
            accH[mi][nj] = (f32x4){0.f, 0.f, 0.f, 0.f};
            accL[mi][nj] = (f32x4){0.f, 0.f, 0.f, 0.f};
        }

    const int nK = K / BK;
    for (int kc = 0; kc < nK; ++kc) {
        __syncthreads();
        if constexpr (AB == 1) {
            #pragma unroll
            for (int i = 0; i < (BM * BK) / 2048; ++i) {
                int u = i * 256 + tid;
                int r = u >> 3, c8 = (u & 7) * 8;
                int cs = c8 ^ ((r & 7) << 3);
                *(f16x8*)&Ah[r][cs] =
                    *(const f16x8*)(Ahp + (size_t)(bm0 + r) * K + kc * BK + c8);
                *(f16x8*)&Al[r][cs] =
                    *(const f16x8*)(Alp + (size_t)(bm0 + r) * K + kc * BK + c8);
            }
        } else {
            #pragma unroll
            for (int i = 0; i < (BM * BK) / 2048; ++i) {
                int u = i * 256 + tid;
                int r = u >> 3, c8 = (u & 7) * 8;
                int cs = c8 ^ ((r & 7) << 3);
                const float* ga = A + (size_t)(bm0 + r) * K + kc * BK + c8;
                f16x8 hh, ll;
                #pragma unroll
                for (int j = 0; j < 8; ++j) {
                    float v = ga[j];
                    _Float16 h = (_Float16)v;
                    hh[j] = h;
                    ll[j] = (_Float16)((v - (float)h) * 2048.0f);
                }
                *(f16x8*)&Ah[r][cs] = hh;
                *(f16x8*)&Al[r][cs] = ll;
            }
        }
        if constexpr (WB == 1) {
            #pragma unroll
            for (int i = 0; i < (BN * BK) / 2048; ++i) {
                int u = i * 256 + tid;
                int n = u >> 3, c8 = (u & 7) * 8;
                int cs = c8 ^ ((n & 7) << 3);
                *(f16x8*)&Bh[n][cs] =
                    *(const f16x8*)(Bhp + (size_t)(bn0 + n) * K + kc * BK + c8);
                *(f16x8*)&Bl[n][cs] =
                    *(const f16x8*)(Blp + (size_t)(bn0 + n) * K + kc * BK + c8);
            }
        } else {
            #pragma unroll
            for (int i = 0; i < (BN * BK) / 2048; ++i) {
                int u = i * 256 + tid;
                int n = u % BN, k8 = (u / BN) * 8;
                int cs = k8 ^ ((n & 7) << 3);
                const float* gB = Bm + (size_t)(kc * BK + k8) * ldb + bn0 + n;
                f16x8 hh, ll;
                #pragma unroll
                for (int j = 0; j < 8; ++j) {
                    float v = gB[(size_t)j * ldb];
                    _Float16 h = (_Float16)v;
                    hh[j] = h;
                    ll[j] = (_Float16)((v - (float)h) * 2048.0f);
                }
                *(f16x8*)&Bh[n][cs] = hh;
                *(f16x8*)&Bl[n][cs] = ll;
            }
        }
        __syncthreads();
        #pragma unroll
        for (int ks = 0; ks < BK; ks += 32) {
            f16x8 ah[MI], al[MI], bh[NJ], bl[NJ];
            int col = (ks + quad * 8) ^ rsz;
            #pragma unroll
            for (int mi = 0; mi < MI; ++mi) {
                ah[mi] = *(const f16x8*)&Ah[wm * WM + mi * 16 + l][col];
                al[mi] = *(const f16x8*)&Al[wm * WM + mi * 16 + l][col];
            }
            #pragma unroll
            for (int nj = 0; nj < NJ; ++nj) {
                bh[nj] = *(const f16x8*)&Bh[wn * WN + nj * 16 + l][col];
                bl[nj] = *(const f16x8*)&Bl[wn * WN + nj * 16 + l][col];
            }
            #pragma unroll
            for (int mi = 0; mi < MI; ++mi)
                #pragma unroll
                for (int nj = 0; nj < NJ; ++nj) {
                    accH[mi][nj] = __builtin_amdgcn_mfma_f32_16x16x32_f16(
                        ah[mi], bh[nj], accH[mi][nj], 0, 0, 0);
                    accL[mi][nj] = __builtin_amdgcn_mfma_f32_16x16x32_f16(
                        ah[mi], bl[nj], accL[mi][nj], 0, 0, 0);
                    accL[mi][nj] = __builtin_amdgcn_mfma_f32_16x16x32_f16(
                        al[mi], bh[nj], accL[mi][nj], 0, 0, 0);
                }
        }
    }
    #pragma unroll
    for (int mi = 0; mi < MI; ++mi)
        #pragma unroll
        for (int nj = 0; nj < NJ; ++nj)
            #pragma unroll
            for (int r = 0; r < 4; ++r) {
                int row = bm0 + wm * WM + mi * 16 + quad * 4 + r;
                int col = bn0 + wn * WN + nj * 16 + l;
                float v = accH[mi][nj][r] + accL[mi][nj][r] * (1.0f / 2048.0f);
                size_t idx = (size_t)row * N + col;
                if constexpr (EPI == 0) Cout[idx] = v;
                else                    Cout[idx] = v + resid[idx];
            }
}

// ---------------------------------------------------------------------------
// Fused w1+w3 expert GEMM, ALL 9 experts (z = 0..8; 8 = shared via identity
// token list). XOR-swizzled unpadded LDS (conflict-free).
// __launch_bounds__(256, 2): needs ~256 regs/thread; (256,3) spills (round 6).
// ---------------------------------------------------------------------------
__global__ __launch_bounds__(256, 2)
void gemm13_k(const unsigned short* __restrict__ A,
              const unsigned short* __restrict__ B1,
              const unsigned short* __restrict__ B3,
              unsigned short* __restrict__ T1o,
              const int* __restrict__ eidx,
              const int* __restrict__ counts,
              const int* __restrict__ offs,
              int N, long long bstr)
{
    constexpr int BM = 128, BK = 64;
    constexpr int MI = 4, NJ = 4;
    __shared__ alignas(16) unsigned short As[BM][BK];
    __shared__ alignas(16) unsigned short Bs1[BM][BK];
    __shared__ alignas(16) unsigned short Bs3[BM][BK];
    __shared__ int rowbuf[BM];
    const int tid  = threadIdx.x;
    const int bn0  = blockIdx.x * 128, bm0 = blockIdx.y * 128;
    const int lane = tid & 63, wave = tid >> 6;
    const int l    = lane & 15, quad = lane >> 4;
    const int wm   = wave >> 1, wn = wave & 1;
    const int rs   = tid >> 3, c8 = (tid & 7) * 8;
    const int wsz  = (rs & 7) << 3;   // write swizzle
    const int rsz  = (l & 7) << 3;    // read swizzle

    int e = blockIdx.z;
    int cnt = counts[e];
    if (bm0 >= cnt) return;
    int crow0 = offs[e];
    B1 += (long long)e * bstr;
    B3 += (long long)e * bstr;
    if (tid < BM) {
        int rr = bm0 + tid;
        rowbuf[tid] = (rr < cnt) ? eidx[e * TOK + rr] : 0;
    }
    __syncthreads();

    f32x4 acc1[MI][NJ], acc3[MI][NJ];
    #pragma unroll
    for (int mi = 0; mi < MI; ++mi)
        #pragma unroll
        for (int nj = 0; nj < NJ; ++nj) {
            acc1[mi][nj] = (f32x4){0.f, 0.f, 0.f, 0.f};
            acc3[mi][nj] = (f32x4){0.f, 0.f, 0.f, 0.f};
        }

    const int nK = D_ / BK;   // 9
    u32x4 ra[4], rb1[4], rb3[4];
    #pragma unroll
    for (int i = 0; i < 4; ++i) {
        int r = i * 32 + rs;
        int arow = rowbuf[r];
        ra[i]  = *(const u32x4*)(A  + (size_t)arow * D_ + c8);
        rb1[i] = *(const u32x4*)(B1 + (size_t)(bn0 + r) * D_ + c8);
        rb3[i] = *(const u32x4*)(B3 + (size_t)(bn0 + r) * D_ + c8);
    }
    for (int kc = 0; kc < nK; ++kc) {
        __syncthreads();
        #pragma unroll
        for (int i = 0; i < 4; ++i) {
            int r = i * 32 + rs;
            *(u32x4*)&As[r][c8 ^ wsz]  = ra[i];
            *(u32x4*)&Bs1[r][c8 ^ wsz] = rb1[i];
            *(u32x4*)&Bs3[r][c8 ^ wsz] = rb3[i];
        }
        __syncthreads();
        if (kc + 1 < nK) {
            int ko = (kc + 1) * BK;
            #pragma unroll
            for (int i = 0; i < 4; ++i) {
                int r = i * 32 + rs;
                int arow = rowbuf[r];
                ra[i]  = *(const u32x4*)(A  + (size_t)arow * D_ + ko + c8);
                rb1[i] = *(const u32x4*)(B1 + (size_t)(bn0 + r) * D_ + ko + c8);
                rb3[i] = *(const u32x4*)(B3 + (size_t)(bn0 + r) * D_ + ko + c8);
            }
        }
        #pragma unroll
        for (int ks = 0; ks < BK; ks += 32) {
            bf16x8 af[MI], b1f[NJ], b3f[NJ];
            int col = (ks + quad * 8) ^ rsz;
            #pragma unroll
            for (int mi = 0; mi < MI; ++mi)
                af[mi] = __builtin_bit_cast(bf16x8,
                    *(const u32x4*)&As[wm * 64 + mi * 16 + l][col]);
            #pragma unroll
            for (int nj = 0; nj < NJ; ++nj) {
                b1f[nj] = __builtin_bit_cast(bf16x8,
                    *(const u32x4*)&Bs1[wn * 64 + nj * 16 + l][col]);
                b3f[nj] = __builtin_bit_cast(bf16x8,
                    *(const u32x4*)&Bs3[wn * 64 + nj * 16 + l][col]);
            }
            #pragma unroll
            for (int mi = 0; mi < MI; ++mi)
                #pragma unroll
                for (int nj = 0; nj < NJ; ++nj) {
                    acc1[mi][nj] = __builtin_amdgcn_mfma_f32_16x16x32_bf16(
                        af[mi], b1f[nj], acc1[mi][nj], 0, 0, 0);
                    acc3[mi][nj] = __builtin_amdgcn_mfma_f32_16x16x32_bf16(
                        af[mi], b3f[nj], acc3[mi][nj], 0, 0, 0);
                }
        }
    }
    #pragma unroll
    for (int mi = 0; mi < MI; ++mi)
        #pragma unroll
        for (int nj = 0; nj < NJ; ++nj)
            #pragma unroll
            for (int r = 0; r < 4; ++r) {
                int lrow = bm0 + wm * 64 + mi * 16 + quad * 4 + r;
                int col  = bn0 + wn * 64 + nj * 16 + l;
                float hv = b2f(f2b(acc1[mi][nj][r]));
                float g  = 0.5f * hv * (1.0f + erff(hv * 0.70710678118654752f));
                T1o[(size_t)(crow0 + lrow) * N + col] = f2b(g * acc3[mi][nj][r]);
            }
}

// ---------------------------------------------------------------------------
// w2 scatter GEMM, all 9 experts. BM=64, swizzled unpadded LDS (32.3 KB).
// A rows compact, C scatter via rowbuf with atomicAdd.
// ---------------------------------------------------------------------------
__global__ __launch_bounds__(256)
void gemm2_k(const unsigned short* __restrict__ A,
             const unsigned short* __restrict__ Bm,
             float* __restrict__ Cout,
             const float* __restrict__ wgt,
             const int* __restrict__ eidx,
             const int* __restrict__ counts,
             const int* __restrict__ offs,
             int N, int K, int ldb, long long bstr)
{
    constexpr int BM = 64, BN = 192, BK = 64;
    constexpr int MI = 2, NJ = 6;                 // waves 2x2: WM=32, WN=96
    constexpr int AIT = (BM * BK) / 2048;         // 2
    constexpr int BIT = (BN * BK) / 2048;         // 6
    __shared__ alignas(16) unsigned short As[BM][BK];
    __shared__ alignas(16) unsigned short Bs[BN][BK];
    __shared__ int rowbuf[BM];
    const int tid  = threadIdx.x;
    const int bn0  = blockIdx.x * BN, bm0 = blockIdx.y * BM;
    const int lane = tid & 63, wave = tid >> 6;
    const int l    = lane & 15, quad = lane >> 4;
    const int wm   = wave >> 1, wn = wave & 1;
    const int rs   = tid >> 3, c8 = (tid & 7) * 8;
    const int wsz  = (rs & 7) << 3;
    const int rsz  = (l & 7) << 3;

    int e = blockIdx.z;
    int cnt = counts[e];
    if (bm0 >= cnt) return;
    int crow0 = offs[e];
    int ebase = e * TOK;
    const unsigned short* Bt = Bm + (long long)e * bstr;
    if (tid < BM) {
        int rr = bm0 + tid;
        rowbuf[tid] = (rr < cnt) ? eidx[ebase + rr] : 0;
    }

    f32x4 acc[MI][NJ];
    #pragma unroll
    for (int mi = 0; mi < MI; ++mi)
        #pragma unroll
        for (int nj = 0; nj < NJ; ++nj) acc[mi][nj] = (f32x4){0.f, 0.f, 0.f, 0.f};

    const int nK = K / BK;
    u32x4 pa[AIT], pb[BIT];
    #pragma unroll
    for (int i = 0; i < AIT; ++i) {
        int r = i * 32 + rs;
        pa[i] = *(const u32x4*)(A + (size_t)(crow0 + bm0 + r) * K + c8);
    }
    #pragma unroll
    for (int i = 0; i < BIT; ++i) {
        int n = i * 32 + rs;
        pb[i] = *(const u32x4*)(Bt + (size_t)(bn0 + n) * ldb + c8);
    }
    for (int kc = 0; kc < nK; ++kc) {
        __syncthreads();
        #pragma unroll
        for (int i = 0; i < AIT; ++i) {
            int r = i * 32 + rs;
            *(u32x4*)&As[r][c8 ^ wsz] = pa[i];
        }
        #pragma unroll
        for (int i = 0; i < BIT; ++i) {
            int n = i * 32 + rs;
            *(u32x4*)&Bs[n][c8 ^ wsz] = pb[i];
        }
        __syncthreads();
        if (kc + 1 < nK) {
            int ko = (kc + 1) * BK;
            #pragma unroll
            for (int i = 0; i < AIT; ++i) {
                int r = i * 32 + rs;
                pa[i] = *(const u32x4*)(A + (size_t)(crow0 + bm0 + r) * K + ko + c8);
            }
            #pragma unroll
            for (int i = 0; i < BIT; ++i) {
                int n = i * 32 + rs;
                pb[i] = *(const u32x4*)(Bt + (size_t)(bn0 + n) * ldb + ko + c8);
            }
        }
        #pragma unroll
        for (int ks = 0; ks < BK; ks += 32) {
            bf16x8 af[MI], bfr[NJ];
            int col = (ks + quad * 8) ^ rsz;
            #pragma unroll
            for (int mi = 0; mi < MI; ++mi)
                af[mi] = __builtin_bit_cast(bf16x8,
                    *(const u32x4*)&As[wm * 32 + mi * 16 + l][col]);
            #pragma unroll
            for (int nj = 0; nj < NJ; ++nj)
                bfr[nj] = __builtin_bit_cast(bf16x8,
                    *(const u32x4*)&Bs[wn * 96 + nj * 16 + l][col]);
            #pragma unroll
            for (int mi = 0; mi < MI; ++mi)
                #pragma unroll
                for (int nj = 0; nj < NJ; ++nj)
                    acc[mi][nj] = __builtin_amdgcn_mfma_f32_16x16x32_bf16(
                        af[mi], bfr[nj], acc[mi][nj], 0, 0, 0);
        }
    }
    #pragma unroll
    for (int mi = 0; mi < MI; ++mi)
        #pragma unroll
        for (int nj = 0; nj < NJ; ++nj)
            #pragma unroll
            for (int r = 0; r < 4; ++r) {
                int lrow = bm0 + wm * 32 + mi * 16 + quad * 4 + r;
                if (lrow < cnt) {
                    int   tok = rowbuf[lrow - bm0];
                    float sc  = wgt[ebase + lrow];
                    int   col = bn0 + wn * 96 + nj * 16 + l;
                    atomicAdd(&Cout[(size_t)tok * N + col], sc * acc[mi][nj][r]);
                }
            }
}

// ---------------------------------------------------------------------------
// Expert-phase MFMA GEMM (fallback path only).
// ---------------------------------------------------------------------------
template<int BN, int EPI, int ROUTED, int WB>
__global__ __launch_bounds__(256)
void gemm_k(const unsigned short* __restrict__ A,
            const void* __restrict__ Bm,
            void* __restrict__ Cout,
            const void* __restrict__ resid,
            const float* __restrict__ wgt,
            const int* __restrict__ eidx,
            const int* __restrict__ counts,
            const int* __restrict__ offs,
            int M, int N, int K, int ldb, long long bstr)
{
    constexpr int BM = 128, BK = 64, LDT = BK + 8;
    constexpr int WM = BM / 2, WN = BN / 2, MI = WM / 16, NJ = WN / 16;
    constexpr int AIT = (BM * BK) / 2048, BIT = (BN * BK) / 2048;
    __shared__ alignas(16) unsigned short As[BM][LDT];
    __shared__ alignas(16) unsigned short Bs[BN][LDT];
    __shared__ int rowbuf[BM];
    const int tid  = threadIdx.x;
    const int bn0  = blockIdx.x * BN, bm0 = blockIdx.y * BM;
    const int lane = tid & 63, wave = tid >> 6;
    const int l    = lane & 15, quad = lane >> 4;
    const int wm   = wave >> 1, wn = wave & 1;

    int cnt = M, crow0 = 0, ebase = 0;
    long long boff = 0;
    if constexpr (ROUTED) {
        int e = blockIdx.z;
        cnt = counts[e];
        if (bm0 >= cnt) return;
        crow0 = offs[e];
        ebase = e * TOK;
        boff  = (long long)e * bstr;
        if (tid < BM) {
            int rr = bm0 + tid;
            rowbuf[tid] = (rr < cnt) ? eidx[ebase + rr] : 0;
        }
        __syncthreads();
    }

    f32x4 acc[MI][NJ];
    #pragma unroll
    for (int mi = 0; mi < MI; ++mi)
        #pragma unroll
        for (int nj = 0; nj < NJ; ++nj) acc[mi][nj] = (f32x4){0.f, 0.f, 0.f, 0.f};

    const int nK = K / BK;
    for (int kc = 0; kc < nK; ++kc) {
        __syncthreads();
        #pragma unroll
        for (int i = 0; i < AIT; ++i) {
            int u = i * 256 + tid;
            int r = u >> 3, c8 = (u & 7) * 8;
            int arow;
            if constexpr (ROUTED && EPI != 5) arow = rowbuf[r];
            else if constexpr (ROUTED)        arow = crow0 + bm0 + r;
            else                              arow = bm0 + r;
            *(u32x4*)&As[r][c8] =
                *(const u32x4*)(A + (size_t)arow * K + kc * BK + c8);
        }
        const float* Bf = (const float*)Bm + boff;
        #pragma unroll
        for (int i = 0; i < BIT; ++i) {
            int u = i * 256 + tid;
            int n = u % BN, k8 = (u / BN) * 8;
            const float* gB = Bf + (size_t)(kc * BK + k8) * ldb + bn0 + n;
            u16x8 tmp;
            #pragma unroll
            for (int j = 0; j < 8; ++j) tmp[j] = f2b(gB[(size_t)j * ldb]);
            *(u16x8*)&Bs[n][k8] = tmp;
        }
        __syncthreads();
        #pragma unroll
        for (int ks = 0; ks < BK; ks += 32) {
            bf16x8 af[MI], bfr[NJ];
            #pragma unroll
            for (int mi = 0; mi < MI; ++mi)
                af[mi] = __builtin_bit_cast(bf16x8,
                    *(const u32x4*)&As[wm * WM + mi * 16 + l][ks + quad * 8]);
            #pragma unroll
            for (int nj = 0; nj < NJ; ++nj)
                bfr[nj] = __builtin_bit_cast(bf16x8,
                    *(const u32x4*)&Bs[wn * WN + nj * 16 + l][ks + quad * 8]);
            #pragma unroll
            for (int mi = 0; mi < MI; ++mi)
                #pragma unroll
                for (int nj = 0; nj < NJ; ++nj)
                    acc[mi][nj] = __builtin_amdgcn_mfma_f32_16x16x32_bf16(
                        af[mi], bfr[nj], acc[mi][nj], 0, 0, 0);
        }
    }
    #pragma unroll
    for (int mi = 0; mi < MI; ++mi)
        #pragma unroll
        for (int nj = 0; nj < NJ; ++nj)
            #pragma unroll
            for (int r = 0; r < 4; ++r) {
                int lrow = bm0 + wm * WM + mi * 16 + quad * 4 + r;
                int col  = bn0 + wn * WN + nj * 16 + l;
                float v = acc[mi][nj][r];
                if constexpr (EPI == 0) {
                    ((unsigned short*)Cout)[(size_t)(crow0 + lrow) * N + col] = f2b(v);
                } else if constexpr (EPI == 3) {
                    size_t ix = (size_t)(crow0 + lrow) * N + col;
                    float hv = b2f(((const unsigned short*)resid)[ix]);
                    float g = 0.5f * hv * (1.0f + erff(hv * 0.70710678118654752f));
                    ((unsigned short*)Cout)[ix] = f2b(g * v);
                } else if constexpr (EPI == 4) {
                    ((float*)Cout)[(size_t)lrow * N + col] += v;
                } else {
                    if (lrow < cnt) {
                        int   tok = rowbuf[lrow - bm0];
                        float sc  = wgt[ebase + lrow];
                        atomicAdd(&((float*)Cout)[(size_t)tok * N + col], sc * v);
                    }
                }
            }
}

// ---------------------------------------------------------------------------
// Per-position cross-head attention, full fp32 (unchanged).
// ---------------------------------------------------------------------------
__global__ __launch_bounds__(256)
void attn32_k(const float* __restrict__ q,   // [ct][H][64]
              const float* __restrict__ kv,  // [ct][H][128]
              float* __restrict__ ao,        // [(b*H+h)*S+s][64]
              int pos0)
{
    int pl   = blockIdx.x * 4 + (threadIdx.x >> 6);
    int lane = threadIdx.x & 63;
    int pos  = pos0 + pl;
    int b = pos >> 11, s = pos & 2047;

    const float* qp  = q  + (size_t)pl * 576;
    const float* kvp = kv + (size_t)pl * 1152;

    int i = lane >> 1;
    float theta = powf(10000.f, -(float)i * (1.0f / 32.0f));
    float sn, cs;
    sincosf((float)s * theta, &sn, &cs);

    float qr[H_], kr[H_], vr[H_];
    #pragma unroll
    for (int h = 0; h < H_; ++h) {
        float qv = qp[h * 64 + lane];
        float qo = __shfl_xor(qv, 1, 64);
        qr[h] = (lane & 1) ? (qo * sn + qv * cs) : (qv * cs - qo * sn);
        kr[h] = kvp[h * 128 + lane];
        vr[h] = kvp[h * 128 + 64 + lane];
    }

    #pragma unroll
    for (int h = 0; h < H_; ++h) {
        float sc[H_];
        #pragma unroll
        for (int t = 0; t < H_; ++t) {
            float p = qr[h] * kr[t];
            #pragma unroll
            for (int d = 1; d < 64; d <<= 1) p += __shfl_xor(p, d, 64);
            sc[t] = p * 0.125f;
        }
        float mx = sc[0];
        #pragma unroll
        for (int t = 1; t < H_; ++t) mx = fmaxf(mx, sc[t]);
        float ssum = 0.f;
        #pragma unroll
        for (int t = 0; t < H_; ++t) { sc[t] = __expf(sc[t] - mx); ssum += sc[t]; }
        float inv = 1.0f / ssum;
        float ov = 0.f;
        #pragma unroll
        for (int t = 0; t < H_; ++t) ov += sc[t] * vr[t];
        ao[((size_t)(b * H_ + h) * S_ + s) * 64 + lane] = ov * inv;
    }
}

// ---------------------------------------------------------------------------
// Gating pass 1: per-token top-2 (no atomics). 4 tokens/block, 1 wave each.
// ---------------------------------------------------------------------------
__global__ __launch_bounds__(256)
void gate1_k(const float* __restrict__ x2,
             const float* __restrict__ gw,
             float* __restrict__ tw,    // [TOK][2]
             int*   __restrict__ tsel)  // [TOK]
{
    int tok  = blockIdx.x * 4 + (threadIdx.x >> 6);
    int lane = threadIdx.x & 63;
    float acc[8];
    #pragma unroll
    for (int e = 0; e < 8; ++e) acc[e] = 0.f;
    float ss = 0.f;
    for (int d = lane; d < D_; d += 64) {
        float xv = x2[(size_t)tok * D_ + d];
        ss += xv * xv;
        const float* wr = gw + (size_t)d * 8;
        #pragma unroll
        for (int e = 0; e < 8; ++e) acc[e] += xv * wr[e];
    }
    #pragma unroll
    for (int d = 1; d < 64; d <<= 1) ss += __shfl_xor(ss, d, 64);
    #pragma unroll
    for (int e = 0; e < 8; ++e)
        #pragma unroll
        for (int d = 1; d < 64; d <<= 1) acc[e] += __shfl_xor(acc[e], d, 64);
    if (lane == 0) {
        float rms = rsqrtf(ss / (float)D_ + 1e-6f);
        #pragma unroll
        for (int e = 0; e < 8; ++e) acc[e] *= rms;
        float mx = acc[0];
        #pragma unroll
        for (int e = 1; e < 8; ++e) mx = fmaxf(mx, acc[e]);
        float g[8], ssum = 0.f;
        #pragma unroll
        for (int e = 0; e < 8; ++e) { g[e] = __expf(acc[e] - mx); ssum += g[e]; }
        #pragma unroll
        for (int e = 0; e < 8; ++e) g[e] /= ssum;
        int i1 = 0;
        #pragma unroll
        for (int e = 1; e < 8; ++e) if (g[e] > g[i1]) i1 = e;
        int i2 = -1;
        #pragma unroll
        for (int e = 0; e < 8; ++e)
            if (e != i1 && (i2 < 0 || g[e] > g[i2])) i2 = e;
        float s2 = g[i1] + g[i2];
        tw[(size_t)tok * 2 + 0] = g[i1] / s2;
        tw[(size_t)tok * 2 + 1] = g[i2] / s2;
        tsel[tok] = i1 | (i2 << 8);
    }
}

// ---------------------------------------------------------------------------
// Gating pass 2: deterministic atomic-free compaction. One block per expert.
// Expert 8 (shared) gets the identity list with weight 1.0.
// ---------------------------------------------------------------------------
__global__ __launch_bounds__(256)
void gate2_k(const int*   __restrict__ tsel,
             const float* __restrict__ tw,
             float* __restrict__ wgt,     // [9][TOK]
             int*   __restrict__ eidx,    // [9][TOK]
             int*   __restrict__ counts)  // [9]
{
    int e    = blockIdx.x;   // 0..8
    int tid  = threadIdx.x;
    int lane = tid & 63, wv = tid >> 6;
    __shared__ int wtot[4];
    int base = 0;
    for (int t0 = 0; t0 < TOK; t0 += 256) {
        int tok = t0 + tid;
        int hit = 0; float w = 0.f;
        if (e == E_) { hit = 1; w = 1.0f; }
        else {
            int s = tsel[tok];
            if ((s & 255) == e)      { hit = 1; w = tw[(size_t)tok * 2 + 0]; }
            else if ((s >> 8) == e)  { hit = 1; w = tw[(size_t)tok * 2 + 1]; }
        }
        unsigned long long m = __ballot(hit);
        int pre = __popcll(m & ((1ull << lane) - 1ull));
        if (lane == 0) wtot[wv] = __popcll(m);
        __syncthreads();
        int off = base;
        for (int q = 0; q < wv; ++q) off += wtot[q];
        if (hit) {
            int p = off + pre;
            eidx[e * TOK + p] = tok;
            wgt [e * TOK + p] = w;
        }
        base += wtot[0] + wtot[1] + wtot[2] + wtot[3];
        __syncthreads();   // protect wtot before next chunk overwrites it
    }
    if (tid == 0) counts[e] = base;
}

// 128-padded exclusive prefix of counts -> per-expert compact row offsets
__global__ void offs_k(const int* __restrict__ counts, int* __restrict__ offs) {
    if (threadIdx.x == 0) {
        int run = 0;
        for (int e = 0; e < 9; ++e) {
            offs[e] = run;
            run += ((counts[e] + 127) >> 7) << 7;
        }
    }
}

// ---------------------------------------------------------------------------
extern "C" void kernel_launch(void* const* d_in, const int* in_sizes, int n_in,
                              void* d_out, int out_size, void* d_ws, size_t ws_size,
                              hipStream_t stream)
{
    const float* x      = (const float*)d_in[0];
    const float* q_w    = (const float*)d_in[1];
    const float* kv_w   = (const float*)d_in[2];
    const float* o_w    = (const float*)d_in[3];
    const float* gate_w = (const float*)d_in[4];
    const float* w1     = (const float*)d_in[5];
    const float* w2     = (const float*)d_in[6];
    const float* w3     = (const float*)d_in[7];
    const float* sw1    = (const float*)d_in[8];
    const float* sw2    = (const float*)d_in[9];
    const float* sw3    = (const float*)d_in[10];
    float* out = (float*)d_out;   // fp32: holds x2, then accumulates experts

    const size_t XN = (size_t)TOK * D_ * 2;   //  9,437,184 (bf16 TOK x D)
    char* ws = (char*)d_ws;
    unsigned short* xn16 = (unsigned short*)ws;          // [0, XN)      persists
    float*          ao32 = (float*)(ws + XN);            // [XN, 3XN)    phase A

    // split attention-path weights: qh/ql [D][D], kvh/kvl [1152][D], oh/ol [D][D]
    const size_t QE = (size_t)D_ * D_, KVE = (size_t)1152 * D_;
    const size_t SW = (2 * QE + KVE) * 2 * 2;   // 5,308,416 bytes
    _Float16* qwh  = (_Float16*)(ws + 3 * XN);
    _Float16* qwl  = qwh  + QE;
    _Float16* kvwh = qwl  + QE;
    _Float16* kvwl = kvwh + KVE;
    _Float16* owh  = kvwl + KVE;
    _Float16* owl  = owh  + QE;

    // phase-A chunking: footprint = 3XN + (convA?SW:0) + 8XN/TC
    bool convA = true;
    int TC = -1;
    for (int pass = 0; pass < 2; ++pass) {
        size_t base = 3 * XN + (convA ? SW : 0);
        if      (base + 8*XN    <= ws_size) { TC = 1; break; }
        else if (base + 8*XN/2  <= ws_size) { TC = 2; break; }
        else if (base + 8*XN/4  <= ws_size) { TC = 4; break; }
        else if (base + 8*XN/8  <= ws_size) { TC = 8; break; }
        else if (base + 8*XN/16 <= ws_size) { TC = 16; break; }
        else if (base + 8*XN/32 <= ws_size) { TC = 32; break; }
        else if (base + 8*XN/64 <= ws_size) { TC = 64; break; }
        convA = false;  // retry without split weights
    }
    if (TC < 0) { convA = false; TC = 64; }
    const int CT = TOK / TC;
    // chunk area: (convA) xnh/xnl f16 pair (= 2XN/TC total, same as fp32 xn32c)
    //             (else)  xn32c fp32
    char* chunk0 = ws + 3*XN + (convA ? SW : 0);
    _Float16* xnh  = (_Float16*)chunk0;
    _Float16* xnl  = xnh + (size_t)CT * D_;
    float*    xn32c = (float*)chunk0;
    float*    qc   = (float*)(chunk0 + (size_t)CT * D_ * 4);
    float*    kvc  = qc + (size_t)CT * D_;

    // expert-phase layout (reuses the ao32/chunk space, dead after step 2):
    int*   counts = (int*)(ws + XN);
    int*   offs   = counts + 16;
    float* wgt    = (float*)(ws + XN + 256);
    int*   eidx   = (int*)  (ws + XN + 256 + (size_t)9 * TOK * 4);
    float* tw     = (float*)(ws + XN + 256 + (size_t)9 * TOK * 8);
    int*   tsel   = (int*)  (ws + XN + 256 + (size_t)9 * TOK * 8 + (size_t)TOK * 8);
    const size_t fixedG = XN + 256 + (size_t)9 * TOK * 8 + (size_t)TOK * 12;

    const size_t WELEM = (size_t)D_ * FF_;          // 884736 elems per matrix
    const size_t WSZ   = 27 * WELEM * 2;            // 9 slots x (w1,w3,w2) bf16

    bool conv; int FC;
    if      (fixedG + WSZ + (size_t)T1ALL * FF_     * 2 <= ws_size) { conv = true;  FC = 1; }
    else if (fixedG + WSZ + (size_t)T1ALL * (FF_/2) * 2 <= ws_size) { conv = true;  FC = 2; }
    else if (fixedG + WSZ + (size_t)T1ALL * (FF_/4) * 2 <= ws_size) { conv = true;  FC = 4; }
    else if (fixedG + (size_t)T1ROWS * FF_     * 2 <= ws_size)      { conv = false; FC = 1; }
    else if (fixedG + (size_t)T1ROWS * (FF_/2) * 2 <= ws_size)      { conv = false; FC = 2; }
    else                                                            { conv = false; FC = 4; }
    const int FFc = FF_ / FC;

    unsigned short* wt1 = (unsigned short*)(ws + fixedG);   // 9 slots
    unsigned short* wt3 = wt1 + 9 * WELEM;                  // 9 slots
    unsigned short* wt2 = wt3 + 9 * WELEM;                  // 9 slots
    unsigned short* t1  = (unsigned short*)(ws + fixedG + (conv ? WSZ : 0));

    // 0) split attention-path weights once (bit-identical values)
    if (convA) {
        convS_k<<<dim3(D_/64,  D_/64), 256, 0, stream>>>(q_w,  qwh,  qwl,  D_, D_);
        convS_k<<<dim3(1152/64, D_/64), 256, 0, stream>>>(kv_w, kvwh, kvwl, D_, 1152);
        convS_k<<<dim3(D_/64,  D_/64), 256, 0, stream>>>(o_w,  owh,  owl,  D_, D_);
    }
    // 1) phase A per chunk: xn split (f16 pair), q, kv (split GEMM), attention
    for (int t = 0; t < TC; ++t) {
        const float* xc = x + (size_t)t * CT * D_;
        if (convA) {
            rmssplit_k<<<CT, 256, 0, stream>>>(xc, xnh, xnl);
            gemmS_k<64, 0, 1, 1><<<dim3(D_ / 64, CT / 128), 256, 0, stream>>>(
                nullptr, xnh, xnl, nullptr, qwh, qwl, qc, nullptr, CT, D_, D_, D_);
            gemmS_k<64, 0, 1, 1><<<dim3(1152 / 64, CT / 128), 256, 0, stream>>>(
                nullptr, xnh, xnl, nullptr, kvwh, kvwl, kvc, nullptr, CT, 1152, D_, D_);
        } else {
            rms32_k<<<CT, 256, 0, stream>>>(xc, xn32c);
            gemmS_k<64, 0, 0, 0><<<dim3(D_ / 64, CT / 128), 256, 0, stream>>>(
                xn32c, nullptr, nullptr, q_w, nullptr, nullptr, qc, nullptr, CT, D_, D_, D_);
            gemmS_k<64, 0, 0, 0><<<dim3(1152 / 64, CT / 128), 256, 0, stream>>>(
                xn32c, nullptr, nullptr, kv_w, nullptr, nullptr, kvc, nullptr, CT, 1152, D_, 1152);
        }
        attn32_k<<<CT / 4, 256, 0, stream>>>(qc, kvc, ao32, t * CT);
    }
    // 2) x2 = ao @ o_w + x  -> d_out (fp32, split GEMM; A stays fp32)
    if (convA)
        gemmS_k<64, 1, 1, 0><<<dim3(D_ / 64, TOK / 128), 256, 0, stream>>>(
            ao32, nullptr, nullptr, nullptr, owh, owl, out, x, TOK, D_, D_, D_);
    else
        gemmS_k<64, 1, 0, 0><<<dim3(D_ / 64, TOK / 128), 256, 0, stream>>>(
            ao32, nullptr, nullptr, o_w, nullptr, nullptr, out, x, TOK, D_, D_, D_);
    // 3) xn16 = rmsnorm(x2) (bf16, expert input)
    rmsnorm_k<<<TOK, 256, 0, stream>>>(out, xn16);
    // 4) gating (expert 8 = shared identity list)
    gate1_k<<<TOK / 4, 256, 0, stream>>>(out, gate_w, tw, tsel);
    gate2_k<<<E_ + 1, 256, 0, stream>>>(tsel, tw, wgt, eidx, counts);
    offs_k<<<1, 64, 0, stream>>>(counts, offs);
    // 4b) weight convert+transpose fp32 -> bf16 [N][K], 9 slots each
    if (conv) {
        convw13_k<<<dim3(FF_/64, D_/64, 18), 256, 0, stream>>>(
            w1, w3, sw1, sw3, wt1, wt3);
        convw2_k<<<dim3(D_/64, FF_/64, 9), 256, 0, stream>>>(w2, sw2, wt2);
    }
    // 5) all 9 experts in 2 launches per FF chunk (shared = expert 8)
    for (int c = 0; c < FC; ++c) {
        if (conv) {
            gemm13_k<<<dim3(FFc / 128, TOK / 128, 9), 256, 0, stream>>>(
                xn16, wt1 + (size_t)c * FFc * D_, wt3 + (size_t)c * FFc * D_,
                t1, eidx, counts, offs, FFc, (long long)WELEM);
            gemm2_k<<<dim3(D_ / 192, TOK / 64, 9), 256, 0, stream>>>(
                t1, wt2 + (size_t)c * FFc, out, wgt, eidx, counts, offs,
                D_, FFc, FF_, (long long)WELEM);
        } else {
            const float* w1c = w1 + (size_t)c * FFc;
            const float* w3c = w3 + (size_t)c * FFc;
            const float* w2c = w2 + (size_t)c * FFc * D_;
            gemm_k<128, 0, 1, 0><<<dim3(FFc / 128, TOK / 128, E_), 256, 0, stream>>>(
                xn16, w1c, t1, nullptr, wgt, eidx, counts, offs,
                TOK, FFc, D_, FF_, (long long)D_ * FF_);
            gemm_k<128, 3, 1, 0><<<dim3(FFc / 128, TOK / 128, E_), 256, 0, stream>>>(
                xn16, w3c, t1, t1, wgt, eidx, counts, offs,
                TOK, FFc, D_, FF_, (long long)D_ * FF_);
            gemm_k<64, 5, 1, 0><<<dim3(D_ / 64, TOK / 128, E_), 256, 0, stream>>>(
                t1, w2c, out, nullptr, wgt, eidx, counts, offs,
                TOK, D_, FFc, D_, (long long)FF_ * D_);
            gemm_k<128, 0, 0, 0><<<dim3(FFc / 128, TOK / 128), 256, 0, stream>>>(
                xn16, sw1 + (size_t)c * FFc, t1, nullptr, nullptr, nullptr, nullptr, nullptr,
                TOK, FFc, D_, FF_, 0);
            gemm_k<128, 3, 0, 0><<<dim3(FFc / 128, TOK / 128), 256, 0, stream>>>(
                xn16, sw3 + (size_t)c * FFc, t1, t1, nullptr, nullptr, nullptr, nullptr,
                TOK, FFc, D_, FF_, 0);
            gemm_k<64, 4, 0, 0><<<dim3(D_ / 64, TOK / 128), 256, 0, stream>>>(
                t1, sw2 + (size_t)c * FFc * D_, out, nullptr, nullptr, nullptr, nullptr, nullptr,
                TOK, D_, FFc, D_, 0);
        }
    }
}

// Round 11
// 614.453 us; speedup vs baseline: 1.4281x; 1.0109x over previous
//
#include <hip/hip_runtime.h>
#include <math.h>

#define B_  4
#define S_  2048
#define D_  576
#define H_  9
#define HD_ 64
#define FF_ 1536
#define E_  8
#define TOK (B_*S_)   // 8192
// compact routed rows: 2*TOK + 8*127 pad rounded -> 17408; +TOK shared -> 25600
#define T1ROWS 17408
#define T1ALL  25600

typedef unsigned int   u32x4  __attribute__((ext_vector_type(4)));
typedef unsigned short u16x8  __attribute__((ext_vector_type(8)));
typedef __bf16         bf16x8 __attribute__((ext_vector_type(8)));
typedef _Float16       f16x8  __attribute__((ext_vector_type(8)));
typedef float          f32x4  __attribute__((ext_vector_type(4)));

__device__ __forceinline__ float b2f(unsigned short u) {
    union { unsigned int i; float f; } v; v.i = ((unsigned int)u) << 16; return v.f;
}
__device__ __forceinline__ unsigned short f2b(float f) {
    unsigned int u = __builtin_bit_cast(unsigned int, f);
    unsigned int r = 0x7fffu + ((u >> 16) & 1u);
    return (unsigned short)((u + r) >> 16);
}

// Liveness-aware XCD chunking (round-9 lesson applied): bijectively remap
// ONLY the live block range [0, nlive) so each XCD residue class (flat%8)
// covers a CONTIGUOUS chunk of logical tiles — A-panels / B-slices stay in
// one XCD's L2. Unlike round-9's naive swizzle (which concentrated the live
// tiles of early-exit grids onto 2 XCDs), the domain here is exactly the
// live tiles, so per-XCD load balance is exact by construction.
// Requires (gridDim.x*gridDim.y) % 8 == 0 so flat%8 == orig%8 per z-slice.
__device__ __forceinline__ bool swzlive(int orig, int nlive, int nx,
                                        int& bx, int& by) {
    if (orig >= nlive) return false;
    int xcd = orig & 7, i = orig >> 3;
    int q = nlive >> 3, r = nlive & 7;
    int l = (xcd < r ? xcd * (q + 1) : r * (q + 1) + (xcd - r) * q) + i;
    bx = l % nx; by = l / nx;
    return true;
}

// ---------------------------------------------------------------------------
// RMSNorm fp32 -> bf16 (for the expert phase)
// ---------------------------------------------------------------------------
__global__ __launch_bounds__(256)
void rmsnorm_k(const float* __restrict__ x, unsigned short* __restrict__ xn) {
    int tok = blockIdx.x, tid = threadIdx.x;
    const float* xr = x + (size_t)tok * D_;
    float v0 = xr[tid];
    float v1 = xr[tid + 256];
    float v2 = (tid < D_ - 512) ? xr[tid + 512] : 0.f;
    float ss = v0*v0 + v1*v1 + v2*v2;
    #pragma unroll
    for (int d = 1; d < 64; d <<= 1) ss += __shfl_xor(ss, d, 64);
    __shared__ float red[4];
    if ((tid & 63) == 0) red[tid >> 6] = ss;
    __syncthreads();
    float tot = red[0] + red[1] + red[2] + red[3];
    float rms = rsqrtf(tot / (float)D_ + 1e-6f);
    unsigned short* orow = xn + (size_t)tok * D_;
    orow[tid]       = f2b(v0 * rms);
    orow[tid + 256] = f2b(v1 * rms);
    if (tid < D_ - 512) orow[tid + 512] = f2b(v2 * rms);
}

// RMSNorm fp32 -> fp32, chunk-local output (fallback path)
__global__ __launch_bounds__(256)
void rms32_k(const float* __restrict__ x, float* __restrict__ xn) {
    int tok = blockIdx.x, tid = threadIdx.x;
    const float* xr = x + (size_t)tok * D_;
    float v0 = xr[tid];
    float v1 = xr[tid + 256];
    float v2 = (tid < D_ - 512) ? xr[tid + 512] : 0.f;
    float ss = v0*v0 + v1*v1 + v2*v2;
    #pragma unroll
    for (int d = 1; d < 64; d <<= 1) ss += __shfl_xor(ss, d, 64);
    __shared__ float red[4];
    if ((tid & 63) == 0) red[tid >> 6] = ss;
    __syncthreads();
    float tot = red[0] + red[1] + red[2] + red[3];
    float rms = rsqrtf(tot / (float)D_ + 1e-6f);
    float* orow = xn + (size_t)tok * D_;
    orow[tid]       = v0 * rms;
    orow[tid + 256] = v1 * rms;
    if (tid < D_ - 512) orow[tid + 512] = v2 * rms;
}

// RMSNorm fp32 -> pre-split f16 pair (Ah, Al*2048), chunk-local. Rounding is
// bit-identical to the old in-loop split of the fp32 xn32c value.
__global__ __launch_bounds__(256)
void rmssplit_k(const float* __restrict__ x,
                _Float16* __restrict__ xh, _Float16* __restrict__ xl) {
    int tok = blockIdx.x, tid = threadIdx.x;
    const float* xr = x + (size_t)tok * D_;
    float v0 = xr[tid];
    float v1 = xr[tid + 256];
    float v2 = (tid < D_ - 512) ? xr[tid + 512] : 0.f;
    float ss = v0*v0 + v1*v1 + v2*v2;
    #pragma unroll
    for (int d = 1; d < 64; d <<= 1) ss += __shfl_xor(ss, d, 64);
    __shared__ float red[4];
    if ((tid & 63) == 0) red[tid >> 6] = ss;
    __syncthreads();
    float tot = red[0] + red[1] + red[2] + red[3];
    float rms = rsqrtf(tot / (float)D_ + 1e-6f);
    _Float16* hr = xh + (size_t)tok * D_;
    _Float16* lr = xl + (size_t)tok * D_;
    {
        float v = v0 * rms; _Float16 h = (_Float16)v;
        hr[tid] = h; lr[tid] = (_Float16)((v - (float)h) * 2048.0f);
    }
    {
        float v = v1 * rms; _Float16 h = (_Float16)v;
        hr[tid + 256] = h; lr[tid + 256] = (_Float16)((v - (float)h) * 2048.0f);
    }
    if (tid < D_ - 512) {
        float v = v2 * rms; _Float16 h = (_Float16)v;
        hr[tid + 512] = h; lr[tid + 512] = (_Float16)((v - (float)h) * 2048.0f);
    }
}

// ---------------------------------------------------------------------------
// Merged weight convert+transpose, w1/w3 family: fp32 [D][FF] -> bf16 [FF][D].
// z: 0..7 = w1 experts, 8 = sw1, 9..16 = w3 experts, 17 = sw3.
// ---------------------------------------------------------------------------
__global__ __launch_bounds__(256)
void convw13_k(const float* __restrict__ w1, const float* __restrict__ w3,
               const float* __restrict__ sw1, const float* __restrict__ sw3,
               unsigned short* __restrict__ wt1, unsigned short* __restrict__ wt3)
{
    const size_t WE = (size_t)D_ * FF_;
    int z = blockIdx.z;
    const float* s; unsigned short* d;
    if (z < 8)       { s = w1 + (size_t)z * WE;       d = wt1 + (size_t)z * WE; }
    else if (z == 8) { s = sw1;                        d = wt1 + 8 * WE; }
    else if (z < 17) { s = w3 + (size_t)(z - 9) * WE;  d = wt3 + (size_t)(z - 9) * WE; }
    else             { s = sw3;                        d = wt3 + 8 * WE; }
    const int K = D_, N = FF_;
    __shared__ unsigned short t[64][72];
    int n0 = blockIdx.x * 64, k0 = blockIdx.y * 64;
    int tx = threadIdx.x & 63, ty = threadIdx.x >> 6;
    #pragma unroll
    for (int i = 0; i < 16; ++i) {
        int k = i * 4 + ty;
        t[k][tx] = f2b(s[(size_t)(k0 + k) * N + n0 + tx]);
    }
    __syncthreads();
    int r = threadIdx.x >> 3, c8 = (threadIdx.x & 7) * 8;
    #pragma unroll
    for (int it = 0; it < 2; ++it, r += 32) {
        u16x8 v;
        #pragma unroll
        for (int j = 0; j < 8; ++j) v[j] = t[c8 + j][r];
        *(u16x8*)&d[(size_t)(n0 + r) * K + k0 + c8] = v;
    }
}

// w2 family: fp32 [FF][D] -> bf16 [D][FF]. z: 0..7 = w2 experts, 8 = sw2.
__global__ __launch_bounds__(256)
void convw2_k(const float* __restrict__ w2, const float* __restrict__ sw2,
              unsigned short* __restrict__ wt2)
{
    const size_t WE = (size_t)D_ * FF_;
    int z = blockIdx.z;
    const float* s = (z < 8) ? w2 + (size_t)z * WE : sw2;
    unsigned short* d = wt2 + (size_t)z * WE;
    const int K = FF_, N = D_;
    __shared__ unsigned short t[64][72];
    int n0 = blockIdx.x * 64, k0 = blockIdx.y * 64;
    int tx = threadIdx.x & 63, ty = threadIdx.x >> 6;
    #pragma unroll
    for (int i = 0; i < 16; ++i) {
        int k = i * 4 + ty;
        t[k][tx] = f2b(s[(size_t)(k0 + k) * N + n0 + tx]);
    }
    __syncthreads();
    int r = threadIdx.x >> 3, c8 = (threadIdx.x & 7) * 8;
    #pragma unroll
    for (int it = 0; it < 2; ++it, r += 32) {
        u16x8 v;
        #pragma unroll
        for (int j = 0; j < 8; ++j) v[j] = t[c8 + j][r];
        *(u16x8*)&d[(size_t)(n0 + r) * K + k0 + c8] = v;
    }
}

// ---------------------------------------------------------------------------
// Split-weight convert+transpose for the high-precision path:
// fp32 [K][N] -> f16 Wh[N][K] and Wl[N][K] (= (v-h)*2048).
// ---------------------------------------------------------------------------
__global__ __launch_bounds__(256)
void convS_k(const float* __restrict__ src,
             _Float16* __restrict__ dh, _Float16* __restrict__ dl,
             int K, int N)
{
    __shared__ _Float16 th[64][72], tl[64][72];
    int n0 = blockIdx.x * 64, k0 = blockIdx.y * 64;
    int tx = threadIdx.x & 63, ty = threadIdx.x >> 6;
    #pragma unroll
    for (int i = 0; i < 16; ++i) {
        int k = i * 4 + ty;
        float v = src[(size_t)(k0 + k) * N + n0 + tx];
        _Float16 h = (_Float16)v;
        th[k][tx] = h;
        tl[k][tx] = (_Float16)((v - (float)h) * 2048.0f);
    }
    __syncthreads();
    int r = threadIdx.x >> 3, c8 = (threadIdx.x & 7) * 8;
    #pragma unroll
    for (int it = 0; it < 2; ++it, r += 32) {
        f16x8 vh, vl;
        #pragma unroll
        for (int j = 0; j < 8; ++j) { vh[j] = th[c8 + j][r]; vl[j] = tl[c8 + j][r]; }
        *(f16x8*)&dh[(size_t)(n0 + r) * K + k0 + c8] = vh;
        *(f16x8*)&dl[(size_t)(n0 + r) * K + k0 + c8] = vl;
    }
}

// ---------------------------------------------------------------------------
// High-precision GEMM via scaled fp16 split. XOR-swizzled unpadded LDS.
// AB=1: A pre-split f16 (Ahp/Alp) -> vector staging.
// ---------------------------------------------------------------------------
template<int BN, int EPI, int WB, int AB>
__global__ __launch_bounds__(256)
void gemmS_k(const float* __restrict__ A,
             const _Float16* __restrict__ Ahp, const _Float16* __restrict__ Alp,
             const float* __restrict__ Bm,
             const _Float16* __restrict__ Bhp, const _Float16* __restrict__ Blp,
             float* __restrict__ Cout, const float* __restrict__ resid,
             int M, int N, int K, int ldb)
{
    constexpr int BM = 128, BK = 64;
    constexpr int WM = BM / 2, WN = BN / 2, MI = WM / 16, NJ = WN / 16;
    __shared__ alignas(16) _Float16 Ah[BM][BK], Al[BM][BK];
    __shared__ alignas(16) _Float16 Bh[BN][BK], Bl[BN][BK];
    const int tid  = threadIdx.x;
    const int bn0  = blockIdx.x * BN, bm0 = blockIdx.y * BM;
    const int lane = tid & 63, wave = tid >> 6;
    const int l    = lane & 15, quad = lane >> 4;
    const int wm   = wave >> 1, wn = wave & 1;
    const int rsz  = (l & 7) << 3;          // read swizzle (16B slots)

    f32x4 accH[MI][NJ], accL[MI][NJ];
    #pragma unroll
    for (int mi = 0; mi < MI; ++mi)
        #pragma unroll
        for (int nj = 0; nj < NJ; ++nj) {
            accH[mi][nj] = (f32x4){0.f, 0.f, 0.f, 0.f};
            accL[mi][nj] = (f32x4){0.f, 0.f, 0.f, 0.f};
        }

    const int nK = K / BK;
    for (int kc = 0; kc < nK; ++kc) {
        __syncthreads();
        if constexpr (AB == 1) {
            #pragma unroll
            for (int i = 0; i < (BM * BK) / 2048; ++i) {
                int u = i * 256 + tid;
                int r = u >> 3, c8 = (u & 7) * 8;
                int cs = c8 ^ ((r & 7) << 3);
                *(f16x8*)&Ah[r][cs] =
                    *(const f16x8*)(Ahp + (size_t)(bm0 + r) * K + kc * BK + c8);
                *(f16x8*)&Al[r][cs] =
                    *(const f16x8*)(Alp + (size_t)(bm0 + r) * K + kc * BK + c8);
            }
        } else {
            #pragma unroll
            for (int i = 0; i < (BM * BK) / 2048; ++i) {
                int u = i * 256 + tid;
                int r = u >> 3, c8 = (u & 7) * 8;
                int cs = c8 ^ ((r & 7) << 3);
                const float* ga = A + (size_t)(bm0 + r) * K + kc * BK + c8;
                f16x8 hh, ll;
                #pragma unroll
                for (int j = 0; j < 8; ++j) {
                    float v = ga[j];
                    _Float16 h = (_Float16)v;
                    hh[j] = h;
                    ll[j] = (_Float16)((v - (float)h) * 2048.0f);
                }
                *(f16x8*)&Ah[r][cs] = hh;
                *(f16x8*)&Al[r][cs] = ll;
            }
        }
        if constexpr (WB == 1) {
            #pragma unroll
            for (int i = 0; i < (BN * BK) / 2048; ++i) {
                int u = i * 256 + tid;
                int n = u >> 3, c8 = (u & 7) * 8;
                int cs = c8 ^ ((n & 7) << 3);
                *(f16x8*)&Bh[n][cs] =
                    *(const f16x8*)(Bhp + (size_t)(bn0 + n) * K + kc * BK + c8);
                *(f16x8*)&Bl[n][cs] =
                    *(const f16x8*)(Blp + (size_t)(bn0 + n) * K + kc * BK + c8);
            }
        } else {
            #pragma unroll
            for (int i = 0; i < (BN * BK) / 2048; ++i) {
                int u = i * 256 + tid;
                int n = u % BN, k8 = (u / BN) * 8;
                int cs = k8 ^ ((n & 7) << 3);
                const float* gB = Bm + (size_t)(kc * BK + k8) * ldb + bn0 + n;
                f16x8 hh, ll;
                #pragma unroll
                for (int j = 0; j < 8; ++j) {
                    float v = gB[(size_t)j * ldb];
                    _Float16 h = (_Float16)v;
                    hh[j] = h;
                    ll[j] = (_Float16)((v - (float)h) * 2048.0f);
                }
                *(f16x8*)&Bh[n][cs] = hh;
                *(f16x8*)&Bl[n][cs] = ll;
            }
        }
        __syncthreads();
        #pragma unroll
        for (int ks = 0; ks < BK; ks += 32) {
            f16x8 ah[MI], al[MI], bh[NJ], bl[NJ];
            int col = (ks + quad * 8) ^ rsz;
            #pragma unroll
            for (int mi = 0; mi < MI; ++mi) {
                ah[mi] = *(const f16x8*)&Ah[wm * WM + mi * 16 + l][col];
                al[mi] = *(const f16x8*)&Al[wm * WM + mi * 16 + l][col];
            }
            #pragma unroll
            for (int nj = 0; nj < NJ; ++nj) {
                bh[nj] = *(const f16x8*)&Bh[wn * WN + nj * 16 + l][col];
                bl[nj] = *(const f16x8*)&Bl[wn * WN + nj * 16 + l][col];
            }
            #pragma unroll
            for (int mi = 0; mi < MI; ++mi)
                #pragma unroll
                for (int nj = 0; nj < NJ; ++nj) {
                    accH[mi][nj] = __builtin_amdgcn_mfma_f32_16x16x32_f16(
                        ah[mi], bh[nj], accH[mi][nj], 0, 0, 0);
                    accL[mi][nj] = __builtin_amdgcn_mfma_f32_16x16x32_f16(
                        ah[mi], bl[nj], accL[mi][nj], 0, 0, 0);
                    accL[mi][nj] = __builtin_amdgcn_mfma_f32_16x16x32_f16(
                        al[mi], bh[nj], accL[mi][nj], 0, 0, 0);
                }
        }
    }
    #pragma unroll
    for (int mi = 0; mi < MI; ++mi)
        #pragma unroll
        for (int nj = 0; nj < NJ; ++nj)
            #pragma unroll
            for (int r = 0; r < 4; ++r) {
                int row = bm0 + wm * WM + mi * 16 + quad * 4 + r;
                int col = bn0 + wn * WN + nj * 16 + l;
                float v = accH[mi][nj][r] + accL[mi][nj][r] * (1.0f / 2048.0f);
                size_t idx = (size_t)row * N + col;
                if constexpr (EPI == 0) Cout[idx] = v;
                else                    Cout[idx] = v + resid[idx];
            }
}

// ---------------------------------------------------------------------------
// Fused w1+w3 expert GEMM, ALL 9 experts (z = 0..8; 8 = shared via identity
// token list). XOR-swizzled unpadded LDS (conflict-free). Liveness-aware
// XCD chunking via swzlive (grid x*y = 768 % 8 == 0).
// __launch_bounds__(256, 2): needs ~256 regs/thread; (256,3) spills (round 6).
// ---------------------------------------------------------------------------
__global__ __launch_bounds__(256, 2)
void gemm13_k(const unsigned short* __restrict__ A,
              const unsigned short* __restrict__ B1,
              const unsigned short* __restrict__ B3,
              unsigned short* __restrict__ T1o,
              const int* __restrict__ eidx,
              const int* __restrict__ counts,
              const int* __restrict__ offs,
              int N, long long bstr)
{
    constexpr int BM = 128, BK = 64;
    constexpr int MI = 4, NJ = 4;
    __shared__ alignas(16) unsigned short As[BM][BK];
    __shared__ alignas(16) unsigned short Bs1[BM][BK];
    __shared__ alignas(16) unsigned short Bs3[BM][BK];
    __shared__ int rowbuf[BM];
    const int tid  = threadIdx.x;
    const int lane = tid & 63, wave = tid >> 6;
    const int l    = lane & 15, quad = lane >> 4;
    const int wm   = wave >> 1, wn = wave & 1;
    const int rs   = tid >> 3, c8 = (tid & 7) * 8;
    const int wsz  = (rs & 7) << 3;   // write swizzle
    const int rsz  = (l & 7) << 3;    // read swizzle

    int e = blockIdx.z;
    int cnt = counts[e];
    int nx = gridDim.x;
    int nyl = (cnt + 127) >> 7;
    int bxi, byi;
    if (!swzlive(blockIdx.y * nx + blockIdx.x, nx * nyl, nx, bxi, byi)) return;
    const int bn0 = bxi * 128, bm0 = byi * 128;
    int crow0 = offs[e];
    B1 += (long long)e * bstr;
    B3 += (long long)e * bstr;
    if (tid < BM) {
        int rr = bm0 + tid;
        rowbuf[tid] = (rr < cnt) ? eidx[e * TOK + rr] : 0;
    }
    __syncthreads();

    f32x4 acc1[MI][NJ], acc3[MI][NJ];
    #pragma unroll
    for (int mi = 0; mi < MI; ++mi)
        #pragma unroll
        for (int nj = 0; nj < NJ; ++nj) {
            acc1[mi][nj] = (f32x4){0.f, 0.f, 0.f, 0.f};
            acc3[mi][nj] = (f32x4){0.f, 0.f, 0.f, 0.f};
        }

    const int nK = D_ / BK;   // 9
    u32x4 ra[4], rb1[4], rb3[4];
    #pragma unroll
    for (int i = 0; i < 4; ++i) {
        int r = i * 32 + rs;
        int arow = rowbuf[r];
        ra[i]  = *(const u32x4*)(A  + (size_t)arow * D_ + c8);
        rb1[i] = *(const u32x4*)(B1 + (size_t)(bn0 + r) * D_ + c8);
        rb3[i] = *(const u32x4*)(B3 + (size_t)(bn0 + r) * D_ + c8);
    }
    for (int kc = 0; kc < nK; ++kc) {
        __syncthreads();
        #pragma unroll
        for (int i = 0; i < 4; ++i) {
            int r = i * 32 + rs;
            *(u32x4*)&As[r][c8 ^ wsz]  = ra[i];
            *(u32x4*)&Bs1[r][c8 ^ wsz] = rb1[i];
            *(u32x4*)&Bs3[r][c8 ^ wsz] = rb3[i];
        }
        __syncthreads();
        if (kc + 1 < nK) {
            int ko = (kc + 1) * BK;
            #pragma unroll
            for (int i = 0; i < 4; ++i) {
                int r = i * 32 + rs;
                int arow = rowbuf[r];
                ra[i]  = *(const u32x4*)(A  + (size_t)arow * D_ + ko + c8);
                rb1[i] = *(const u32x4*)(B1 + (size_t)(bn0 + r) * D_ + ko + c8);
                rb3[i] = *(const u32x4*)(B3 + (size_t)(bn0 + r) * D_ + ko + c8);
            }
        }
        #pragma unroll
        for (int ks = 0; ks < BK; ks += 32) {
            bf16x8 af[MI], b1f[NJ], b3f[NJ];
            int col = (ks + quad * 8) ^ rsz;
            #pragma unroll
            for (int mi = 0; mi < MI; ++mi)
                af[mi] = __builtin_bit_cast(bf16x8,
                    *(const u32x4*)&As[wm * 64 + mi * 16 + l][col]);
            #pragma unroll
            for (int nj = 0; nj < NJ; ++nj) {
                b1f[nj] = __builtin_bit_cast(bf16x8,
                    *(const u32x4*)&Bs1[wn * 64 + nj * 16 + l][col]);
                b3f[nj] = __builtin_bit_cast(bf16x8,
                    *(const u32x4*)&Bs3[wn * 64 + nj * 16 + l][col]);
            }
            #pragma unroll
            for (int mi = 0; mi < MI; ++mi)
                #pragma unroll
                for (int nj = 0; nj < NJ; ++nj) {
                    acc1[mi][nj] = __builtin_amdgcn_mfma_f32_16x16x32_bf16(
                        af[mi], b1f[nj], acc1[mi][nj], 0, 0, 0);
                    acc3[mi][nj] = __builtin_amdgcn_mfma_f32_16x16x32_bf16(
                        af[mi], b3f[nj], acc3[mi][nj], 0, 0, 0);
                }
        }
    }
    #pragma unroll
    for (int mi = 0; mi < MI; ++mi)
        #pragma unroll
        for (int nj = 0; nj < NJ; ++nj)
            #pragma unroll
            for (int r = 0; r < 4; ++r) {
                int lrow = bm0 + wm * 64 + mi * 16 + quad * 4 + r;
                int col  = bn0 + wn * 64 + nj * 16 + l;
                float hv = b2f(f2b(acc1[mi][nj][r]));
                float g  = 0.5f * hv * (1.0f + erff(hv * 0.70710678118654752f));
                T1o[(size_t)(crow0 + lrow) * N + col] = f2b(g * acc3[mi][nj][r]);
            }
}

// ---------------------------------------------------------------------------
// w2 scatter GEMM, all 9 experts. BM=64, swizzled unpadded LDS (32.3 KB).
// Liveness-aware XCD chunking (grid x*y = 384 % 8 == 0). A rows compact,
// C scatter via rowbuf with atomicAdd.
// ---------------------------------------------------------------------------
__global__ __launch_bounds__(256)
void gemm2_k(const unsigned short* __restrict__ A,
             const unsigned short* __restrict__ Bm,
             float* __restrict__ Cout,
             const float* __restrict__ wgt,
             const int* __restrict__ eidx,
             const int* __restrict__ counts,
             const int* __restrict__ offs,
             int N, int K, int ldb, long long bstr)
{
    constexpr int BM = 64, BN = 192, BK = 64;
    constexpr int MI = 2, NJ = 6;                 // waves 2x2: WM=32, WN=96
    constexpr int AIT = (BM * BK) / 2048;         // 2
    constexpr int BIT = (BN * BK) / 2048;         // 6
    __shared__ alignas(16) unsigned short As[BM][BK];
    __shared__ alignas(16) unsigned short Bs[BN][BK];
    __shared__ int rowbuf[BM];
    const int tid  = threadIdx.x;
    const int lane = tid & 63, wave = tid >> 6;
    const int l    = lane & 15, quad = lane >> 4;
    const int wm   = wave >> 1, wn = wave & 1;
    const int rs   = tid >> 3, c8 = (tid & 7) * 8;
    const int wsz  = (rs & 7) << 3;
    const int rsz  = (l & 7) << 3;

    int e = blockIdx.z;
    int cnt = counts[e];
    int nx = gridDim.x;
    int nyl = (cnt + 63) >> 6;
    int bxi, byi;
    if (!swzlive(blockIdx.y * nx + blockIdx.x, nx * nyl, nx, bxi, byi)) return;
    const int bn0 = bxi * BN, bm0 = byi * BM;
    int crow0 = offs[e];
    int ebase = e * TOK;
    const unsigned short* Bt = Bm + (long long)e * bstr;
    if (tid < BM) {
        int rr = bm0 + tid;
        rowbuf[tid] = (rr < cnt) ? eidx[ebase + rr] : 0;
    }

    f32x4 acc[MI][NJ];
    #pragma unroll
    for (int mi = 0; mi < MI; ++mi)
        #pragma unroll
        for (int nj = 0; nj < NJ; ++nj) acc[mi][nj] = (f32x4){0.f, 0.f, 0.f, 0.f};

    const int nK = K / BK;
    u32x4 pa[AIT], pb[BIT];
    #pragma unroll
    for (int i = 0; i < AIT; ++i) {
        int r = i * 32 + rs;
        pa[i] = *(const u32x4*)(A + (size_t)(crow0 + bm0 + r) * K + c8);
    }
    #pragma unroll
    for (int i = 0; i < BIT; ++i) {
        int n = i * 32 + rs;
        pb[i] = *(const u32x4*)(Bt + (size_t)(bn0 + n) * ldb + c8);
    }
    for (int kc = 0; kc < nK; ++kc) {
        __syncthreads();
        #pragma unroll
        for (int i = 0; i < AIT; ++i) {
            int r = i * 32 + rs;
            *(u32x4*)&As[r][c8 ^ wsz] = pa[i];
        }
        #pragma unroll
        for (int i = 0; i < BIT; ++i) {
            int n = i * 32 + rs;
            *(u32x4*)&Bs[n][c8 ^ wsz] = pb[i];
        }
        __syncthreads();
        if (kc + 1 < nK) {
            int ko = (kc + 1) * BK;
            #pragma unroll
            for (int i = 0; i < AIT; ++i) {
                int r = i * 32 + rs;
                pa[i] = *(const u32x4*)(A + (size_t)(crow0 + bm0 + r) * K + ko + c8);
            }
            #pragma unroll
            for (int i = 0; i < BIT; ++i) {
                int n = i * 32 + rs;
                pb[i] = *(const u32x4*)(Bt + (size_t)(bn0 + n) * ldb + ko + c8);
            }
        }
        #pragma unroll
        for (int ks = 0; ks < BK; ks += 32) {
            bf16x8 af[MI], bfr[NJ];
            int col = (ks + quad * 8) ^ rsz;
            #pragma unroll
            for (int mi = 0; mi < MI; ++mi)
                af[mi] = __builtin_bit_cast(bf16x8,
                    *(const u32x4*)&As[wm * 32 + mi * 16 + l][col]);
            #pragma unroll
            for (int nj = 0; nj < NJ; ++nj)
                bfr[nj] = __builtin_bit_cast(bf16x8,
                    *(const u32x4*)&Bs[wn * 96 + nj * 16 + l][col]);
            #pragma unroll
            for (int mi = 0; mi < MI; ++mi)
                #pragma unroll
                for (int nj = 0; nj < NJ; ++nj)
                    acc[mi][nj] = __builtin_amdgcn_mfma_f32_16x16x32_bf16(
                        af[mi], bfr[nj], acc[mi][nj], 0, 0, 0);
        }
    }
    #pragma unroll
    for (int mi = 0; mi < MI; ++mi)
        #pragma unroll
        for (int nj = 0; nj < NJ; ++nj)
            #pragma unroll
            for (int r = 0; r < 4; ++r) {
                int lrow = bm0 + wm * 32 + mi * 16 + quad * 4 + r;
                if (lrow < cnt) {
                    int   tok = rowbuf[lrow - bm0];
                    float sc  = wgt[ebase + lrow];
                    int   col = bn0 + wn * 96 + nj * 16 + l;
                    atomicAdd(&Cout[(size_t)tok * N + col], sc * acc[mi][nj][r]);
                }
            }
}

// ---------------------------------------------------------------------------
// Expert-phase MFMA GEMM (fallback path only).
// ---------------------------------------------------------------------------
template<int BN, int EPI, int ROUTED, int WB>
__global__ __launch_bounds__(256)
void gemm_k(const unsigned short* __restrict__ A,
            const void* __restrict__ Bm,
            void* __restrict__ Cout,
            const void* __restrict__ resid,
            const float* __restrict__ wgt,
            const int* __restrict__ eidx,
            const int* __restrict__ counts,
            const int* __restrict__ offs,
            int M, int N, int K, int ldb, long long bstr)
{
    constexpr int BM = 128, BK = 64, LDT = BK + 8;
    constexpr int WM = BM / 2, WN = BN / 2, MI = WM / 16, NJ = WN / 16;
    constexpr int AIT = (BM * BK) / 2048, BIT = (BN * BK) / 2048;
    __shared__ alignas(16) unsigned short As[BM][LDT];
    __shared__ alignas(16) unsigned short Bs[BN][LDT];
    __shared__ int rowbuf[BM];
    const int tid  = threadIdx.x;
    const int bn0  = blockIdx.x * BN, bm0 = blockIdx.y * BM;
    const int lane = tid & 63, wave = tid >> 6;
    const int l    = lane & 15, quad = lane >> 4;
    const int wm   = wave >> 1, wn = wave & 1;

    int cnt = M, crow0 = 0, ebase = 0;
    long long boff = 0;
    if constexpr (ROUTED) {
        int e = blockIdx.z;
        cnt = counts[e];
        if (bm0 >= cnt) return;
        crow0 = offs[e];
        ebase = e * TOK;
        boff  = (long long)e * bstr;
        if (tid < BM) {
            int rr = bm0 + tid;
            rowbuf[tid] = (rr < cnt) ? eidx[ebase + rr] : 0;
        }
        __syncthreads();
    }

    f32x4 acc[MI][NJ];
    #pragma unroll
    for (int mi = 0; mi < MI; ++mi)
        #pragma unroll
        for (int nj = 0; nj < NJ; ++nj) acc[mi][nj] = (f32x4){0.f, 0.f, 0.f, 0.f};

    const int nK = K / BK;
    for (int kc = 0; kc < nK; ++kc) {
        __syncthreads();
        #pragma unroll
        for (int i = 0; i < AIT; ++i) {
            int u = i * 256 + tid;
            int r = u >> 3, c8 = (u & 7) * 8;
            int arow;
            if constexpr (ROUTED && EPI != 5) arow = rowbuf[r];
            else if constexpr (ROUTED)        arow = crow0 + bm0 + r;
            else                              arow = bm0 + r;
            *(u32x4*)&As[r][c8] =
                *(const u32x4*)(A + (size_t)arow * K + kc * BK + c8);
        }
        const float* Bf = (const float*)Bm + boff;
        #pragma unroll
        for (int i = 0; i < BIT; ++i) {
            int u = i * 256 + tid;
            int n = u % BN, k8 = (u / BN) * 8;
            const float* gB = Bf + (size_t)(kc * BK + k8) * ldb + bn0 + n;
            u16x8 tmp;
            #pragma unroll
            for (int j = 0; j < 8; ++j) tmp[j] = f2b(gB[(size_t)j * ldb]);
            *(u16x8*)&Bs[n][k8] = tmp;
        }
        __syncthreads();
        #pragma unroll
        for (int ks = 0; ks < BK; ks += 32) {
            bf16x8 af[MI], bfr[NJ];
            #pragma unroll
            for (int mi = 0; mi < MI; ++mi)
                af[mi] = __builtin_bit_cast(bf16x8,
                    *(const u32x4*)&As[wm * WM + mi * 16 + l][ks + quad * 8]);
            #pragma unroll
            for (int nj = 0; nj < NJ; ++nj)
                bfr[nj] = __builtin_bit_cast(bf16x8,
                    *(const u32x4*)&Bs[wn * WN + nj * 16 + l][ks + quad * 8]);
            #pragma unroll
            for (int mi = 0; mi < MI; ++mi)
                #pragma unroll
                for (int nj = 0; nj < NJ; ++nj)
                    acc[mi][nj] = __builtin_amdgcn_mfma_f32_16x16x32_bf16(
                        af[mi], bfr[nj], acc[mi][nj], 0, 0, 0);
        }
    }
    #pragma unroll
    for (int mi = 0; mi < MI; ++mi)
        #pragma unroll
        for (int nj = 0; nj < NJ; ++nj)
            #pragma unroll
            for (int r = 0; r < 4; ++r) {
                int lrow = bm0 + wm * WM + mi * 16 + quad * 4 + r;
                int col  = bn0 + wn * WN + nj * 16 + l;
                float v = acc[mi][nj][r];
                if constexpr (EPI == 0) {
                    ((unsigned short*)Cout)[(size_t)(crow0 + lrow) * N + col] = f2b(v);
                } else if constexpr (EPI == 3) {
                    size_t ix = (size_t)(crow0 + lrow) * N + col;
                    float hv = b2f(((const unsigned short*)resid)[ix]);
                    float g = 0.5f * hv * (1.0f + erff(hv * 0.70710678118654752f));
                    ((unsigned short*)Cout)[ix] = f2b(g * v);
                } else if constexpr (EPI == 4) {
                    ((float*)Cout)[(size_t)lrow * N + col] += v;
                } else {
                    if (lrow < cnt) {
                        int   tok = rowbuf[lrow - bm0];
                        float sc  = wgt[ebase + lrow];
                        atomicAdd(&((float*)Cout)[(size_t)tok * N + col], sc * v);
                    }
                }
            }
}

// ---------------------------------------------------------------------------
// Per-position cross-head attention, full fp32 (unchanged).
// ---------------------------------------------------------------------------
__global__ __launch_bounds__(256)
void attn32_k(const float* __restrict__ q,   // [ct][H][64]
              const float* __restrict__ kv,  // [ct][H][128]
              float* __restrict__ ao,        // [(b*H+h)*S+s][64]
              int pos0)
{
    int pl   = blockIdx.x * 4 + (threadIdx.x >> 6);
    int lane = threadIdx.x & 63;
    int pos  = pos0 + pl;
    int b = pos >> 11, s = pos & 2047;

    const float* qp  = q  + (size_t)pl * 576;
    const float* kvp = kv + (size_t)pl * 1152;

    int i = lane >> 1;
    float theta = powf(10000.f, -(float)i * (1.0f / 32.0f));
    float sn, cs;
    sincosf((float)s * theta, &sn, &cs);

    float qr[H_], kr[H_], vr[H_];
    #pragma unroll
    for (int h = 0; h < H_; ++h) {
        float qv = qp[h * 64 + lane];
        float qo = __shfl_xor(qv, 1, 64);
        qr[h] = (lane & 1) ? (qo * sn + qv * cs) : (qv * cs - qo * sn);
        kr[h] = kvp[h * 128 + lane];
        vr[h] = kvp[h * 128 + 64 + lane];
    }

    #pragma unroll
    for (int h = 0; h < H_; ++h) {
        float sc[H_];
        #pragma unroll
        for (int t = 0; t < H_; ++t) {
            float p = qr[h] * kr[t];
            #pragma unroll
            for (int d = 1; d < 64; d <<= 1) p += __shfl_xor(p, d, 64);
            sc[t] = p * 0.125f;
        }
        float mx = sc[0];
        #pragma unroll
        for (int t = 1; t < H_; ++t) mx = fmaxf(mx, sc[t]);
        float ssum = 0.f;
        #pragma unroll
        for (int t = 0; t < H_; ++t) { sc[t] = __expf(sc[t] - mx); ssum += sc[t]; }
        float inv = 1.0f / ssum;
        float ov = 0.f;
        #pragma unroll
        for (int t = 0; t < H_; ++t) ov += sc[t] * vr[t];
        ao[((size_t)(b * H_ + h) * S_ + s) * 64 + lane] = ov * inv;
    }
}

// ---------------------------------------------------------------------------
// Gating pass 1: per-token top-2 (no atomics). 4 tokens/block, 1 wave each.
// ---------------------------------------------------------------------------
__global__ __launch_bounds__(256)
void gate1_k(const float* __restrict__ x2,
             const float* __restrict__ gw,
             float* __restrict__ tw,    // [TOK][2]
             int*   __restrict__ tsel)  // [TOK]
{
    int tok  = blockIdx.x * 4 + (threadIdx.x >> 6);
    int lane = threadIdx.x & 63;
    float acc[8];
    #pragma unroll
    for (int e = 0; e < 8; ++e) acc[e] = 0.f;
    float ss = 0.f;
    for (int d = lane; d < D_; d += 64) {
        float xv = x2[(size_t)tok * D_ + d];
        ss += xv * xv;
        const float* wr = gw + (size_t)d * 8;
        #pragma unroll
        for (int e = 0; e < 8; ++e) acc[e] += xv * wr[e];
    }
    #pragma unroll
    for (int d = 1; d < 64; d <<= 1) ss += __shfl_xor(ss, d, 64);
    #pragma unroll
    for (int e = 0; e < 8; ++e)
        #pragma unroll
        for (int d = 1; d < 64; d <<= 1) acc[e] += __shfl_xor(acc[e], d, 64);
    if (lane == 0) {
        float rms = rsqrtf(ss / (float)D_ + 1e-6f);
        #pragma unroll
        for (int e = 0; e < 8; ++e) acc[e] *= rms;
        float mx = acc[0];
        #pragma unroll
        for (int e = 1; e < 8; ++e) mx = fmaxf(mx, acc[e]);
        float g[8], ssum = 0.f;
        #pragma unroll
        for (int e = 0; e < 8; ++e) { g[e] = __expf(acc[e] - mx); ssum += g[e]; }
        #pragma unroll
        for (int e = 0; e < 8; ++e) g[e] /= ssum;
        int i1 = 0;
        #pragma unroll
        for (int e = 1; e < 8; ++e) if (g[e] > g[i1]) i1 = e;
        int i2 = -1;
        #pragma unroll
        for (int e = 0; e < 8; ++e)
            if (e != i1 && (i2 < 0 || g[e] > g[i2])) i2 = e;
        float s2 = g[i1] + g[i2];
        tw[(size_t)tok * 2 + 0] = g[i1] / s2;
        tw[(size_t)tok * 2 + 1] = g[i2] / s2;
        tsel[tok] = i1 | (i2 << 8);
    }
}

// ---------------------------------------------------------------------------
// Gating pass 2: deterministic atomic-free compaction. One block per expert.
// Expert 8 (shared) gets the identity list with weight 1.0.
// ---------------------------------------------------------------------------
__global__ __launch_bounds__(256)
void gate2_k(const int*   __restrict__ tsel,
             const float* __restrict__ tw,
             float* __restrict__ wgt,     // [9][TOK]
             int*   __restrict__ eidx,    // [9][TOK]
             int*   __restrict__ counts)  // [9]
{
    int e    = blockIdx.x;   // 0..8
    int tid  = threadIdx.x;
    int lane = tid & 63, wv = tid >> 6;
    __shared__ int wtot[4];
    int base = 0;
    for (int t0 = 0; t0 < TOK; t0 += 256) {
        int tok = t0 + tid;
        int hit = 0; float w = 0.f;
        if (e == E_) { hit = 1; w = 1.0f; }
        else {
            int s = tsel[tok];
            if ((s & 255) == e)      { hit = 1; w = tw[(size_t)tok * 2 + 0]; }
            else if ((s >> 8) == e)  { hit = 1; w = tw[(size_t)tok * 2 + 1]; }
        }
        unsigned long long m = __ballot(hit);
        int pre = __popcll(m & ((1ull << lane) - 1ull));
        if (lane == 0) wtot[wv] = __popcll(m);
        __syncthreads();
        int off = base;
        for (int q = 0; q < wv; ++q) off += wtot[q];
        if (hit) {
            int p = off + pre;
            eidx[e * TOK + p] = tok;
            wgt [e * TOK + p] = w;
        }
        base += wtot[0] + wtot[1] + wtot[2] + wtot[3];
        __syncthreads();   // protect wtot before next chunk overwrites it
    }
    if (tid == 0) counts[e] = base;
}

// 128-padded exclusive prefix of counts -> per-expert compact row offsets
__global__ void offs_k(const int* __restrict__ counts, int* __restrict__ offs) {
    if (threadIdx.x == 0) {
        int run = 0;
        for (int e = 0; e < 9; ++e) {
            offs[e] = run;
            run += ((counts[e] + 127) >> 7) << 7;
        }
    }
}

// ---------------------------------------------------------------------------
extern "C" void kernel_launch(void* const* d_in, const int* in_sizes, int n_in,
                              void* d_out, int out_size, void* d_ws, size_t ws_size,
                              hipStream_t stream)
{
    const float* x      = (const float*)d_in[0];
    const float* q_w    = (const float*)d_in[1];
    const float* kv_w   = (const float*)d_in[2];
    const float* o_w    = (const float*)d_in[3];
    const float* gate_w = (const float*)d_in[4];
    const float* w1     = (const float*)d_in[5];
    const float* w2     = (const float*)d_in[6];
    const float* w3     = (const float*)d_in[7];
    const float* sw1    = (const float*)d_in[8];
    const float* sw2    = (const float*)d_in[9];
    const float* sw3    = (const float*)d_in[10];
    float* out = (float*)d_out;   // fp32: holds x2, then accumulates experts

    const size_t XN = (size_t)TOK * D_ * 2;   //  9,437,184 (bf16 TOK x D)
    char* ws = (char*)d_ws;
    unsigned short* xn16 = (unsigned short*)ws;          // [0, XN)      persists
    float*          ao32 = (float*)(ws + XN);            // [XN, 3XN)    phase A

    // split attention-path weights: qh/ql [D][D], kvh/kvl [1152][D], oh/ol [D][D]
    const size_t QE = (size_t)D_ * D_, KVE = (size_t)1152 * D_;
    const size_t SW = (2 * QE + KVE) * 2 * 2;   // 5,308,416 bytes
    _Float16* qwh  = (_Float16*)(ws + 3 * XN);
    _Float16* qwl  = qwh  + QE;
    _Float16* kvwh = qwl  + QE;
    _Float16* kvwl = kvwh + KVE;
    _Float16* owh  = kvwl + KVE;
    _Float16* owl  = owh  + QE;

    // phase-A chunking: footprint = 3XN + (convA?SW:0) + 8XN/TC
    bool convA = true;
    int TC = -1;
    for (int pass = 0; pass < 2; ++pass) {
        size_t base = 3 * XN + (convA ? SW : 0);
        if      (base + 8*XN    <= ws_size) { TC = 1; break; }
        else if (base + 8*XN/2  <= ws_size) { TC = 2; break; }
        else if (base + 8*XN/4  <= ws_size) { TC = 4; break; }
        else if (base + 8*XN/8  <= ws_size) { TC = 8; break; }
        else if (base + 8*XN/16 <= ws_size) { TC = 16; break; }
        else if (base + 8*XN/32 <= ws_size) { TC = 32; break; }
        else if (base + 8*XN/64 <= ws_size) { TC = 64; break; }
        convA = false;  // retry without split weights
    }
    if (TC < 0) { convA = false; TC = 64; }
    const int CT = TOK / TC;
    // chunk area: (convA) xnh/xnl f16 pair (= 2XN/TC total, same as fp32 xn32c)
    //             (else)  xn32c fp32
    char* chunk0 = ws + 3*XN + (convA ? SW : 0);
    _Float16* xnh  = (_Float16*)chunk0;
    _Float16* xnl  = xnh + (size_t)CT * D_;
    float*    xn32c = (float*)chunk0;
    float*    qc   = (float*)(chunk0 + (size_t)CT * D_ * 4);
    float*    kvc  = qc + (size_t)CT * D_;

    // expert-phase layout (reuses the ao32/chunk space, dead after step 2):
    int*   counts = (int*)(ws + XN);
    int*   offs   = counts + 16;
    float* wgt    = (float*)(ws + XN + 256);
    int*   eidx   = (int*)  (ws + XN + 256 + (size_t)9 * TOK * 4);
    float* tw     = (float*)(ws + XN + 256 + (size_t)9 * TOK * 8);
    int*   tsel   = (int*)  (ws + XN + 256 + (size_t)9 * TOK * 8 + (size_t)TOK * 8);
    const size_t fixedG = XN + 256 + (size_t)9 * TOK * 8 + (size_t)TOK * 12;

    const size_t WELEM = (size_t)D_ * FF_;          // 884736 elems per matrix
    const size_t WSZ   = 27 * WELEM * 2;            // 9 slots x (w1,w3,w2) bf16

    bool conv; int FC;
    if      (fixedG + WSZ + (size_t)T1ALL * FF_     * 2 <= ws_size) { conv = true;  FC = 1; }
    else if (fixedG + WSZ + (size_t)T1ALL * (FF_/2) * 2 <= ws_size) { conv = true;  FC = 2; }
    else if (fixedG + WSZ + (size_t)T1ALL * (FF_/4) * 2 <= ws_size) { conv = true;  FC = 4; }
    else if (fixedG + (size_t)T1ROWS * FF_     * 2 <= ws_size)      { conv = false; FC = 1; }
    else if (fixedG + (size_t)T1ROWS * (FF_/2) * 2 <= ws_size)      { conv = false; FC = 2; }
    else                                                            { conv = false; FC = 4; }
    const int FFc = FF_ / FC;

    unsigned short* wt1 = (unsigned short*)(ws + fixedG);   // 9 slots
    unsigned short* wt3 = wt1 + 9 * WELEM;                  // 9 slots
    unsigned short* wt2 = wt3 + 9 * WELEM;                  // 9 slots
    unsigned short* t1  = (unsigned short*)(ws + fixedG + (conv ? WSZ : 0));

    // 0) split attention-path weights once (bit-identical values)
    if (convA) {
        convS_k<<<dim3(D_/64,  D_/64), 256, 0, stream>>>(q_w,  qwh,  qwl,  D_, D_);
        convS_k<<<dim3(1152/64, D_/64), 256, 0, stream>>>(kv_w, kvwh, kvwl, D_, 1152);
        convS_k<<<dim3(D_/64,  D_/64), 256, 0, stream>>>(o_w,  owh,  owl,  D_, D_);
    }
    // 1) phase A per chunk: xn split (f16 pair), q, kv (split GEMM), attention
    for (int t = 0; t < TC; ++t) {
        const float* xc = x + (size_t)t * CT * D_;
        if (convA) {
            rmssplit_k<<<CT, 256, 0, stream>>>(xc, xnh, xnl);
            gemmS_k<64, 0, 1, 1><<<dim3(D_ / 64, CT / 128), 256, 0, stream>>>(
                nullptr, xnh, xnl, nullptr, qwh, qwl, qc, nullptr, CT, D_, D_, D_);
            gemmS_k<64, 0, 1, 1><<<dim3(1152 / 64, CT / 128), 256, 0, stream>>>(
                nullptr, xnh, xnl, nullptr, kvwh, kvwl, kvc, nullptr, CT, 1152, D_, D_);
        } else {
            rms32_k<<<CT, 256, 0, stream>>>(xc, xn32c);
            gemmS_k<64, 0, 0, 0><<<dim3(D_ / 64, CT / 128), 256, 0, stream>>>(
                xn32c, nullptr, nullptr, q_w, nullptr, nullptr, qc, nullptr, CT, D_, D_, D_);
            gemmS_k<64, 0, 0, 0><<<dim3(1152 / 64, CT / 128), 256, 0, stream>>>(
                xn32c, nullptr, nullptr, kv_w, nullptr, nullptr, kvc, nullptr, CT, 1152, D_, 1152);
        }
        attn32_k<<<CT / 4, 256, 0, stream>>>(qc, kvc, ao32, t * CT);
    }
    // 2) x2 = ao @ o_w + x  -> d_out (fp32, split GEMM; A stays fp32)
    if (convA)
        gemmS_k<64, 1, 1, 0><<<dim3(D_ / 64, TOK / 128), 256, 0, stream>>>(
            ao32, nullptr, nullptr, nullptr, owh, owl, out, x, TOK, D_, D_, D_);
    else
        gemmS_k<64, 1, 0, 0><<<dim3(D_ / 64, TOK / 128), 256, 0, stream>>>(
            ao32, nullptr, nullptr, o_w, nullptr, nullptr, out, x, TOK, D_, D_, D_);
    // 3) xn16 = rmsnorm(x2) (bf16, expert input)
    rmsnorm_k<<<TOK, 256, 0, stream>>>(out, xn16);
    // 4) gating (expert 8 = shared identity list)
    gate1_k<<<TOK / 4, 256, 0, stream>>>(out, gate_w, tw, tsel);
    gate2_k<<<E_ + 1, 256, 0, stream>>>(tsel, tw, wgt, eidx, counts);
    offs_k<<<1, 64, 0, stream>>>(counts, offs);
    // 4b) weight convert+transpose fp32 -> bf16 [N][K], 9 slots each
    if (conv) {
        convw13_k<<<dim3(FF_/64, D_/64, 18), 256, 0, stream>>>(
            w1, w3, sw1, sw3, wt1, wt3);
        convw2_k<<<dim3(D_/64, FF_/64, 9), 256, 0, stream>>>(w2, sw2, wt2);
    }
    // 5) all 9 experts in 2 launches per FF chunk (shared = expert 8)
    for (int c = 0; c < FC; ++c) {
        if (conv) {
            gemm13_k<<<dim3(FFc / 128, TOK / 128, 9), 256, 0, stream>>>(
                xn16, wt1 + (size_t)c * FFc * D_, wt3 + (size_t)c * FFc * D_,
                t1, eidx, counts, offs, FFc, (long long)WELEM);
            gemm2_k<<<dim3(D_ / 192, TOK / 64, 9), 256, 0, stream>>>(
                t1, wt2 + (size_t)c * FFc, out, wgt, eidx, counts, offs,
                D_, FFc, FF_, (long long)WELEM);
        } else {
            const float* w1c = w1 + (size_t)c * FFc;
            const float* w3c = w3 + (size_t)c * FFc;
            const float* w2c = w2 + (size_t)c * FFc * D_;
            gemm_k<128, 0, 1, 0><<<dim3(FFc / 128, TOK / 128, E_), 256, 0, stream>>>(
                xn16, w1c, t1, nullptr, wgt, eidx, counts, offs,
                TOK, FFc, D_, FF_, (long long)D_ * FF_);
            gemm_k<128, 3, 1, 0><<<dim3(FFc / 128, TOK / 128, E_), 256, 0, stream>>>(
                xn16, w3c, t1, t1, wgt, eidx, counts, offs,
                TOK, FFc, D_, FF_, (long long)D_ * FF_);
            gemm_k<64, 5, 1, 0><<<dim3(D_ / 64, TOK / 128, E_), 256, 0, stream>>>(
                t1, w2c, out, nullptr, wgt, eidx, counts, offs,
                TOK, D_, FFc, D_, (long long)FF_ * D_);
            gemm_k<128, 0, 0, 0><<<dim3(FFc / 128, TOK / 128), 256, 0, stream>>>(
                xn16, sw1 + (size_t)c * FFc, t1, nullptr, nullptr, nullptr, nullptr, nullptr,
                TOK, FFc, D_, FF_, 0);
            gemm_k<128, 3, 0, 0><<<dim3(FFc / 128, TOK / 128), 256, 0, stream>>>(
                xn16, sw3 + (size_t)c * FFc, t1, t1, nullptr, nullptr, nullptr, nullptr,
                TOK, FFc, D_, FF_, 0);
            gemm_k<64, 4, 0, 0><<<dim3(D_ / 64, TOK / 128), 256, 0, stream>>>(
                t1, sw2 + (size_t)c * FFc * D_, out, nullptr, nullptr, nullptr, nullptr, nullptr,
                TOK, D_, FFc, D_, 0);
        }
    }
}

// Round 12
// 603.419 us; speedup vs baseline: 1.4542x; 1.0183x over previous
//
#include <hip/hip_runtime.h>
#include <math.h>

#define B_  4
#define S_  2048
#define D_  576
#define H_  9
#define HD_ 64
#define FF_ 1536
#define E_  8
#define TOK (B_*S_)   // 8192
// compact routed rows: 2*TOK + 8*127 pad rounded -> 17408; +TOK shared -> 25600
#define T1ROWS 17408
#define T1ALL  25600

typedef unsigned int   u32x4  __attribute__((ext_vector_type(4)));
typedef unsigned short u16x8  __attribute__((ext_vector_type(8)));
typedef __bf16         bf16x8 __attribute__((ext_vector_type(8)));
typedef _Float16       f16x8  __attribute__((ext_vector_type(8)));
typedef float          f32x4  __attribute__((ext_vector_type(4)));

__device__ __forceinline__ float b2f(unsigned short u) {
    union { unsigned int i; float f; } v; v.i = ((unsigned int)u) << 16; return v.f;
}
__device__ __forceinline__ unsigned short f2b(float f) {
    unsigned int u = __builtin_bit_cast(unsigned int, f);
    unsigned int r = 0x7fffu + ((u >> 16) & 1u);
    return (unsigned short)((u + r) >> 16);
}

// NOTE (rounds 9/11 post-mortem): XCD-aware block swizzles on these grids
// either regressed 2.5x (round 9: liveness correlated with orig%8 under
// early-exit) or raised FETCH 144->196 MB at equal time (round 11: chunked
// mapping, wrong XCD-assignment model). Expert GEMMs now use a FLAT LIVE
// grid (no dead blocks, natural dispatch order) — no permutation games.

// ---------------------------------------------------------------------------
// RMSNorm fp32 -> bf16 (for the expert phase)
// ---------------------------------------------------------------------------
__global__ __launch_bounds__(256)
void rmsnorm_k(const float* __restrict__ x, unsigned short* __restrict__ xn) {
    int tok = blockIdx.x, tid = threadIdx.x;
    const float* xr = x + (size_t)tok * D_;
    float v0 = xr[tid];
    float v1 = xr[tid + 256];
    float v2 = (tid < D_ - 512) ? xr[tid + 512] : 0.f;
    float ss = v0*v0 + v1*v1 + v2*v2;
    #pragma unroll
    for (int d = 1; d < 64; d <<= 1) ss += __shfl_xor(ss, d, 64);
    __shared__ float red[4];
    if ((tid & 63) == 0) red[tid >> 6] = ss;
    __syncthreads();
    float tot = red[0] + red[1] + red[2] + red[3];
    float rms = rsqrtf(tot / (float)D_ + 1e-6f);
    unsigned short* orow = xn + (size_t)tok * D_;
    orow[tid]       = f2b(v0 * rms);
    orow[tid + 256] = f2b(v1 * rms);
    if (tid < D_ - 512) orow[tid + 512] = f2b(v2 * rms);
}

// RMSNorm fp32 -> fp32, chunk-local output (fallback path)
__global__ __launch_bounds__(256)
void rms32_k(const float* __restrict__ x, float* __restrict__ xn) {
    int tok = blockIdx.x, tid = threadIdx.x;
    const float* xr = x + (size_t)tok * D_;
    float v0 = xr[tid];
    float v1 = xr[tid + 256];
    float v2 = (tid < D_ - 512) ? xr[tid + 512] : 0.f;
    float ss = v0*v0 + v1*v1 + v2*v2;
    #pragma unroll
    for (int d = 1; d < 64; d <<= 1) ss += __shfl_xor(ss, d, 64);
    __shared__ float red[4];
    if ((tid & 63) == 0) red[tid >> 6] = ss;
    __syncthreads();
    float tot = red[0] + red[1] + red[2] + red[3];
    float rms = rsqrtf(tot / (float)D_ + 1e-6f);
    float* orow = xn + (size_t)tok * D_;
    orow[tid]       = v0 * rms;
    orow[tid + 256] = v1 * rms;
    if (tid < D_ - 512) orow[tid + 512] = v2 * rms;
}

// RMSNorm fp32 -> pre-split f16 pair (Ah, Al*2048), chunk-local. Rounding is
// bit-identical to the old in-loop split of the fp32 xn32c value.
__global__ __launch_bounds__(256)
void rmssplit_k(const float* __restrict__ x,
                _Float16* __restrict__ xh, _Float16* __restrict__ xl) {
    int tok = blockIdx.x, tid = threadIdx.x;
    const float* xr = x + (size_t)tok * D_;
    float v0 = xr[tid];
    float v1 = xr[tid + 256];
    float v2 = (tid < D_ - 512) ? xr[tid + 512] : 0.f;
    float ss = v0*v0 + v1*v1 + v2*v2;
    #pragma unroll
    for (int d = 1; d < 64; d <<= 1) ss += __shfl_xor(ss, d, 64);
    __shared__ float red[4];
    if ((tid & 63) == 0) red[tid >> 6] = ss;
    __syncthreads();
    float tot = red[0] + red[1] + red[2] + red[3];
    float rms = rsqrtf(tot / (float)D_ + 1e-6f);
    _Float16* hr = xh + (size_t)tok * D_;
    _Float16* lr = xl + (size_t)tok * D_;
    {
        float v = v0 * rms; _Float16 h = (_Float16)v;
        hr[tid] = h; lr[tid] = (_Float16)((v - (float)h) * 2048.0f);
    }
    {
        float v = v1 * rms; _Float16 h = (_Float16)v;
        hr[tid + 256] = h; lr[tid + 256] = (_Float16)((v - (float)h) * 2048.0f);
    }
    if (tid < D_ - 512) {
        float v = v2 * rms; _Float16 h = (_Float16)v;
        hr[tid + 512] = h; lr[tid + 512] = (_Float16)((v - (float)h) * 2048.0f);
    }
}

// ---------------------------------------------------------------------------
// Merged weight convert+transpose, w1/w3 family: fp32 [D][FF] -> bf16 [FF][D].
// z: 0..7 = w1 experts, 8 = sw1, 9..16 = w3 experts, 17 = sw3.
// ---------------------------------------------------------------------------
__global__ __launch_bounds__(256)
void convw13_k(const float* __restrict__ w1, const float* __restrict__ w3,
               const float* __restrict__ sw1, const float* __restrict__ sw3,
               unsigned short* __restrict__ wt1, unsigned short* __restrict__ wt3)
{
    const size_t WE = (size_t)D_ * FF_;
    int z = blockIdx.z;
    const float* s; unsigned short* d;
    if (z < 8)       { s = w1 + (size_t)z * WE;       d = wt1 + (size_t)z * WE; }
    else if (z == 8) { s = sw1;                        d = wt1 + 8 * WE; }
    else if (z < 17) { s = w3 + (size_t)(z - 9) * WE;  d = wt3 + (size_t)(z - 9) * WE; }
    else             { s = sw3;                        d = wt3 + 8 * WE; }
    const int K = D_, N = FF_;
    __shared__ unsigned short t[64][72];
    int n0 = blockIdx.x * 64, k0 = blockIdx.y * 64;
    int tx = threadIdx.x & 63, ty = threadIdx.x >> 6;
    #pragma unroll
    for (int i = 0; i < 16; ++i) {
        int k = i * 4 + ty;
        t[k][tx] = f2b(s[(size_t)(k0 + k) * N + n0 + tx]);
    }
    __syncthreads();
    int r = threadIdx.x >> 3, c8 = (threadIdx.x & 7) * 8;
    #pragma unroll
    for (int it = 0; it < 2; ++it, r += 32) {
        u16x8 v;
        #pragma unroll
        for (int j = 0; j < 8; ++j) v[j] = t[c8 + j][r];
        *(u16x8*)&d[(size_t)(n0 + r) * K + k0 + c8] = v;
    }
}

// w2 family: fp32 [FF][D] -> bf16 [D][FF]. z: 0..7 = w2 experts, 8 = sw2.
__global__ __launch_bounds__(256)
void convw2_k(const float* __restrict__ w2, const float* __restrict__ sw2,
              unsigned short* __restrict__ wt2)
{
    const size_t WE = (size_t)D_ * FF_;
    int z = blockIdx.z;
    const float* s = (z < 8) ? w2 + (size_t)z * WE : sw2;
    unsigned short* d = wt2 + (size_t)z * WE;
    const int K = FF_, N = D_;
    __shared__ unsigned short t[64][72];
    int n0 = blockIdx.x * 64, k0 = blockIdx.y * 64;
    int tx = threadIdx.x & 63, ty = threadIdx.x >> 6;
    #pragma unroll
    for (int i = 0; i < 16; ++i) {
        int k = i * 4 + ty;
        t[k][tx] = f2b(s[(size_t)(k0 + k) * N + n0 + tx]);
    }
    __syncthreads();
    int r = threadIdx.x >> 3, c8 = (threadIdx.x & 7) * 8;
    #pragma unroll
    for (int it = 0; it < 2; ++it, r += 32) {
        u16x8 v;
        #pragma unroll
        for (int j = 0; j < 8; ++j) v[j] = t[c8 + j][r];
        *(u16x8*)&d[(size_t)(n0 + r) * K + k0 + c8] = v;
    }
}

// ---------------------------------------------------------------------------
// Split-weight convert+transpose, attention-path weights, ONE launch:
// z=0 -> q_w [D][D], z=1 -> kv_w [D][1152], z=2 -> o_w [D][D].
// fp32 [K][N] -> f16 Wh[N][K] and Wl[N][K] (= (v-h)*2048).
// ---------------------------------------------------------------------------
__global__ __launch_bounds__(256)
void convSall_k(const float* __restrict__ q_w, const float* __restrict__ kv_w,
                const float* __restrict__ o_w,
                _Float16* __restrict__ qwh,  _Float16* __restrict__ qwl,
                _Float16* __restrict__ kvwh, _Float16* __restrict__ kvwl,
                _Float16* __restrict__ owh,  _Float16* __restrict__ owl)
{
    int z = blockIdx.z;
    const float* src; _Float16 *dh, *dl; int N;
    if (z == 0)      { if (blockIdx.x >= D_/64) return; src = q_w;  dh = qwh;  dl = qwl;  N = D_; }
    else if (z == 1) { src = kv_w; dh = kvwh; dl = kvwl; N = 1152; }
    else             { if (blockIdx.x >= D_/64) return; src = o_w;  dh = owh;  dl = owl;  N = D_; }
    const int K = D_;
    __shared__ _Float16 th[64][72], tl[64][72];
    int n0 = blockIdx.x * 64, k0 = blockIdx.y * 64;
    int tx = threadIdx.x & 63, ty = threadIdx.x >> 6;
    #pragma unroll
    for (int i = 0; i < 16; ++i) {
        int k = i * 4 + ty;
        float v = src[(size_t)(k0 + k) * N + n0 + tx];
        _Float16 h = (_Float16)v;
        th[k][tx] = h;
        tl[k][tx] = (_Float16)((v - (float)h) * 2048.0f);
    }
    __syncthreads();
    int r = threadIdx.x >> 3, c8 = (threadIdx.x & 7) * 8;
    #pragma unroll
    for (int it = 0; it < 2; ++it, r += 32) {
        f16x8 vh, vl;
        #pragma unroll
        for (int j = 0; j < 8; ++j) { vh[j] = th[c8 + j][r]; vl[j] = tl[c8 + j][r]; }
        *(f16x8*)&dh[(size_t)(n0 + r) * K + k0 + c8] = vh;
        *(f16x8*)&dl[(size_t)(n0 + r) * K + k0 + c8] = vl;
    }
}

// ---------------------------------------------------------------------------
// High-precision GEMM via scaled fp16 split. XOR-swizzled unpadded LDS.
// AB=1: A pre-split f16 (Ahp/Alp) -> vector staging.
// ---------------------------------------------------------------------------
template<int BN, int EPI, int WB, int AB>
__global__ __launch_bounds__(256)
void gemmS_k(const float* __restrict__ A,
             const _Float16* __restrict__ Ahp, const _Float16* __restrict__ Alp,
             const float* __restrict__ Bm,
             const _Float16* __restrict__ Bhp, const _Float16* __restrict__ Blp,
             float* __restrict__ Cout, const float* __restrict__ resid,
             int M, int N, int K, int ldb)
{
    constexpr int BM = 128, BK = 64;
    constexpr int WM = BM / 2, WN = BN / 2, MI = WM / 16, NJ = WN / 16;
    __shared__ alignas(16) _Float16 Ah[BM][BK], Al[BM][BK];
    __shared__ alignas(16) _Float16 Bh[BN][BK], Bl[BN][BK];
    const int tid  = threadIdx.x;
    const int bn0  = blockIdx.x * BN, bm0 = blockIdx.y * BM;
    const int lane = tid & 63, wave = tid >> 6;
    const int l    = lane & 15, quad = lane >> 4;
    const int wm   = wave >> 1, wn = wave & 1;
    const int rsz  = (l & 7) << 3;          // read swizzle (16B slots)

    f32x4 accH[MI][NJ], accL[MI][NJ];
    #pragma unroll
    for (int mi = 0; mi < MI; ++mi)
        #pragma unroll
        for (int nj = 0; nj < NJ; ++nj) {
            accH[mi][nj] = (f32x4){0.f, 0.f, 0.f, 0.f};
            accL[mi][nj] = (f32x4){0.f, 0.f, 0.f, 0.f};
        }

    const int nK = K / BK;
    for (int kc = 0; kc < nK; ++kc) {
        __syncthreads();
        if constexpr (AB == 1) {
            #pragma unroll
            for (int i = 0; i < (BM * BK) / 2048; ++i) {
                int u = i * 256 + tid;
                int r = u >> 3, c8 = (u & 7) * 8;
                int cs = c8 ^ ((r & 7) << 3);
                *(f16x8*)&Ah[r][cs] =
                    *(const f16x8*)(Ahp + (size_t)(bm0 + r) * K + kc * BK + c8);
                *(f16x8*)&Al[r][cs] =
                    *(const f16x8*)(Alp + (size_t)(bm0 + r) * K + kc * BK + c8);
            }
        } else {
            #pragma unroll
            for (int i = 0; i < (BM * BK) / 2048; ++i) {
                int u = i * 256 + tid;
                int r = u >> 3, c8 = (u & 7) * 8;
                int cs = c8 ^ ((r & 7) << 3);
                const float* ga = A + (size_t)(bm0 + r) * K + kc * BK + c8;
                f16x8 hh, ll;
                #pragma unroll
                for (int j = 0; j < 8; ++j) {
                    float v = ga[j];
                    _Float16 h = (_Float16)v;
                    hh[j] = h;
                    ll[j] = (_Float16)((v - (float)h) * 2048.0f);
                }
                *(f16x8*)&Ah[r][cs] = hh;
                *(f16x8*)&Al[r][cs] = ll;
            }
        }
        if constexpr (WB == 1) {
            #pragma unroll
            for (int i = 0; i < (BN * BK) / 2048; ++i) {
                int u = i * 256 + tid;
                int n = u >> 3, c8 = (u & 7) * 8;
                int cs = c8 ^ ((n & 7) << 3);
                *(f16x8*)&Bh[n][cs] =
                    *(const f16x8*)(Bhp + (size_t)(bn0 + n) * K + kc * BK + c8);
                *(f16x8*)&Bl[n][cs] =
                    *(const f16x8*)(Blp + (size_t)(bn0 + n) * K + kc * BK + c8);
            }
        } else {
            #pragma unroll
            for (int i = 0; i < (BN * BK) / 2048; ++i) {
                int u = i * 256 + tid;
                int n = u % BN, k8 = (u / BN) * 8;
                int cs = k8 ^ ((n & 7) << 3);
                const float* gB = Bm + (size_t)(kc * BK + k8) * ldb + bn0 + n;
                f16x8 hh, ll;
                #pragma unroll
                for (int j = 0; j < 8; ++j) {
                    float v = gB[(size_t)j * ldb];
                    _Float16 h = (_Float16)v;
                    hh[j] = h;
                    ll[j] = (_Float16)((v - (float)h) * 2048.0f);
                }
                *(f16x8*)&Bh[n][cs] = hh;
                *(f16x8*)&Bl[n][cs] = ll;
            }
        }
        __syncthreads();
        #pragma unroll
        for (int ks = 0; ks < BK; ks += 32) {
            f16x8 ah[MI], al[MI], bh[NJ], bl[NJ];
            int col = (ks + quad * 8) ^ rsz;
            #pragma unroll
            for (int mi = 0; mi < MI; ++mi) {
                ah[mi] = *(const f16x8*)&Ah[wm * WM + mi * 16 + l][col];
                al[mi] = *(const f16x8*)&Al[wm * WM + mi * 16 + l][col];
            }
            #pragma unroll
            for (int nj = 0; nj < NJ; ++nj) {
                bh[nj] = *(const f16x8*)&Bh[wn * WN + nj * 16 + l][col];
                bl[nj] = *(const f16x8*)&Bl[wn * WN + nj * 16 + l][col];
            }
            #pragma unroll
            for (int mi = 0; mi < MI; ++mi)
                #pragma unroll
                for (int nj = 0; nj < NJ; ++nj) {
                    accH[mi][nj] = __builtin_amdgcn_mfma_f32_16x16x32_f16(
                        ah[mi], bh[nj], accH[mi][nj], 0, 0, 0);
                    accL[mi][nj] = __builtin_amdgcn_mfma_f32_16x16x32_f16(
                        ah[mi], bl[nj], accL[mi][nj], 0, 0, 0);
                    accL[mi][nj] = __builtin_amdgcn_mfma_f32_16x16x32_f16(
                        al[mi], bh[nj], accL[mi][nj], 0, 0, 0);
                }
        }
    }
    #pragma unroll
    for (int mi = 0; mi < MI; ++mi)
        #pragma unroll
        for (int nj = 0; nj < NJ; ++nj)
            #pragma unroll
            for (int r = 0; r < 4; ++r) {
                int row = bm0 + wm * WM + mi * 16 + quad * 4 + r;
                int col = bn0 + wn * WN + nj * 16 + l;
                float v = accH[mi][nj][r] + accL[mi][nj][r] * (1.0f / 2048.0f);
                size_t idx = (size_t)row * N + col;
                if constexpr (EPI == 0) Cout[idx] = v;
                else                    Cout[idx] = v + resid[idx];
            }
}

// ---------------------------------------------------------------------------
// Fused w1+w3 expert GEMM over a FLAT LIVE grid: blockIdx.y spans the
// concatenated 128-padded expert segments (T1ALL/128 tiles); each block
// derives (expert, local tile) by scanning counts. Zero dead blocks,
// natural dispatch order. XOR-swizzled unpadded LDS (conflict-free).
// __launch_bounds__(256, 2): needs ~256 regs/thread; (256,3) spills (round 6).
// ---------------------------------------------------------------------------
__global__ __launch_bounds__(256, 2)
void gemm13_k(const unsigned short* __restrict__ A,
              const unsigned short* __restrict__ B1,
              const unsigned short* __restrict__ B3,
              unsigned short* __restrict__ T1o,
              const int* __restrict__ eidx,
              const int* __restrict__ counts,
              int N, long long bstr)
{
    constexpr int BM = 128, BK = 64;
    constexpr int MI = 4, NJ = 4;
    __shared__ alignas(16) unsigned short As[BM][BK];
    __shared__ alignas(16) unsigned short Bs1[BM][BK];
    __shared__ alignas(16) unsigned short Bs3[BM][BK];
    __shared__ int rowbuf[BM];
    const int tid  = threadIdx.x;
    const int lane = tid & 63, wave = tid >> 6;
    const int l    = lane & 15, quad = lane >> 4;
    const int wm   = wave >> 1, wn = wave & 1;
    const int rs   = tid >> 3, c8 = (tid & 7) * 8;
    const int wsz  = (rs & 7) << 3;   // write swizzle
    const int rsz  = (l & 7) << 3;    // read swizzle

    // locate expert segment for this global row tile
    int row0 = blockIdx.y * BM;
    int e = 0, base = 0;
    for (; e < 9; ++e) {
        int pc = ((counts[e] + 127) >> 7) << 7;
        if (row0 < base + pc) break;
        base += pc;
    }
    if (e >= 9) return;              // beyond used rows
    int cnt   = counts[e];
    int bm0   = row0 - base;         // local tile start within expert
    int crow0 = base;                // compact output row base
    const int bn0 = blockIdx.x * 128;
    B1 += (long long)e * bstr;
    B3 += (long long)e * bstr;
    if (tid < BM) {
        int rr = bm0 + tid;
        rowbuf[tid] = (rr < cnt) ? eidx[e * TOK + rr] : 0;
    }
    __syncthreads();

    f32x4 acc1[MI][NJ], acc3[MI][NJ];
    #pragma unroll
    for (int mi = 0; mi < MI; ++mi)
        #pragma unroll
        for (int nj = 0; nj < NJ; ++nj) {
            acc1[mi][nj] = (f32x4){0.f, 0.f, 0.f, 0.f};
            acc3[mi][nj] = (f32x4){0.f, 0.f, 0.f, 0.f};
        }

    const int nK = D_ / BK;   // 9
    u32x4 ra[4], rb1[4], rb3[4];
    #pragma unroll
    for (int i = 0; i < 4; ++i) {
        int r = i * 32 + rs;
        int arow = rowbuf[r];
        ra[i]  = *(const u32x4*)(A  + (size_t)arow * D_ + c8);
        rb1[i] = *(const u32x4*)(B1 + (size_t)(bn0 + r) * D_ + c8);
        rb3[i] = *(const u32x4*)(B3 + (size_t)(bn0 + r) * D_ + c8);
    }
    for (int kc = 0; kc < nK; ++kc) {
        __syncthreads();
        #pragma unroll
        for (int i = 0; i < 4; ++i) {
            int r = i * 32 + rs;
            *(u32x4*)&As[r][c8 ^ wsz]  = ra[i];
            *(u32x4*)&Bs1[r][c8 ^ wsz] = rb1[i];
            *(u32x4*)&Bs3[r][c8 ^ wsz] = rb3[i];
        }
        __syncthreads();
        if (kc + 1 < nK) {
            int ko = (kc + 1) * BK;
            #pragma unroll
            for (int i = 0; i < 4; ++i) {
                int r = i * 32 + rs;
                int arow = rowbuf[r];
                ra[i]  = *(const u32x4*)(A  + (size_t)arow * D_ + ko + c8);
                rb1[i] = *(const u32x4*)(B1 + (size_t)(bn0 + r) * D_ + ko + c8);
                rb3[i] = *(const u32x4*)(B3 + (size_t)(bn0 + r) * D_ + ko + c8);
            }
        }
        #pragma unroll
        for (int ks = 0; ks < BK; ks += 32) {
            bf16x8 af[MI], b1f[NJ], b3f[NJ];
            int col = (ks + quad * 8) ^ rsz;
            #pragma unroll
            for (int mi = 0; mi < MI; ++mi)
                af[mi] = __builtin_bit_cast(bf16x8,
                    *(const u32x4*)&As[wm * 64 + mi * 16 + l][col]);
            #pragma unroll
            for (int nj = 0; nj < NJ; ++nj) {
                b1f[nj] = __builtin_bit_cast(bf16x8,
                    *(const u32x4*)&Bs1[wn * 64 + nj * 16 + l][col]);
                b3f[nj] = __builtin_bit_cast(bf16x8,
                    *(const u32x4*)&Bs3[wn * 64 + nj * 16 + l][col]);
            }
            #pragma unroll
            for (int mi = 0; mi < MI; ++mi)
                #pragma unroll
                for (int nj = 0; nj < NJ; ++nj) {
                    acc1[mi][nj] = __builtin_amdgcn_mfma_f32_16x16x32_bf16(
                        af[mi], b1f[nj], acc1[mi][nj], 0, 0, 0);
                    acc3[mi][nj] = __builtin_amdgcn_mfma_f32_16x16x32_bf16(
                        af[mi], b3f[nj], acc3[mi][nj], 0, 0, 0);
                }
        }
    }
    #pragma unroll
    for (int mi = 0; mi < MI; ++mi)
        #pragma unroll
        for (int nj = 0; nj < NJ; ++nj)
            #pragma unroll
            for (int r = 0; r < 4; ++r) {
                int lrow = bm0 + wm * 64 + mi * 16 + quad * 4 + r;
                int col  = bn0 + wn * 64 + nj * 16 + l;
                float hv = b2f(f2b(acc1[mi][nj][r]));
                float g  = 0.5f * hv * (1.0f + erff(hv * 0.70710678118654752f));
                T1o[(size_t)(crow0 + lrow) * N + col] = f2b(g * acc3[mi][nj][r]);
            }
}

// ---------------------------------------------------------------------------
// w2 scatter GEMM over the same FLAT LIVE grid (64-row tiles; expert pads are
// 128-aligned so 64-tiles never straddle experts). BM=64, swizzled unpadded
// LDS (32.3 KB). A rows compact, C scatter via rowbuf with atomicAdd.
// ---------------------------------------------------------------------------
__global__ __launch_bounds__(256)
void gemm2_k(const unsigned short* __restrict__ A,
             const unsigned short* __restrict__ Bm,
             float* __restrict__ Cout,
             const float* __restrict__ wgt,
             const int* __restrict__ eidx,
             const int* __restrict__ counts,
             int N, int K, int ldb, long long bstr)
{
    constexpr int BM = 64, BN = 192, BK = 64;
    constexpr int MI = 2, NJ = 6;                 // waves 2x2: WM=32, WN=96
    constexpr int AIT = (BM * BK) / 2048;         // 2
    constexpr int BIT = (BN * BK) / 2048;         // 6
    __shared__ alignas(16) unsigned short As[BM][BK];
    __shared__ alignas(16) unsigned short Bs[BN][BK];
    __shared__ int rowbuf[BM];
    const int tid  = threadIdx.x;
    const int lane = tid & 63, wave = tid >> 6;
    const int l    = lane & 15, quad = lane >> 4;
    const int wm   = wave >> 1, wn = wave & 1;
    const int rs   = tid >> 3, c8 = (tid & 7) * 8;
    const int wsz  = (rs & 7) << 3;
    const int rsz  = (l & 7) << 3;

    int row0 = blockIdx.y * BM;
    int e = 0, base = 0;
    for (; e < 9; ++e) {
        int pc = ((counts[e] + 127) >> 7) << 7;
        if (row0 < base + pc) break;
        base += pc;
    }
    if (e >= 9) return;
    int cnt   = counts[e];
    int bm0   = row0 - base;
    int crow0 = base;
    int ebase = e * TOK;
    const int bn0 = blockIdx.x * BN;
    const unsigned short* Bt = Bm + (long long)e * bstr;
    if (tid < BM) {
        int rr = bm0 + tid;
        rowbuf[tid] = (rr < cnt) ? eidx[ebase + rr] : 0;
    }

    f32x4 acc[MI][NJ];
    #pragma unroll
    for (int mi = 0; mi < MI; ++mi)
        #pragma unroll
        for (int nj = 0; nj < NJ; ++nj) acc[mi][nj] = (f32x4){0.f, 0.f, 0.f, 0.f};

    const int nK = K / BK;
    u32x4 pa[AIT], pb[BIT];
    #pragma unroll
    for (int i = 0; i < AIT; ++i) {
        int r = i * 32 + rs;
        pa[i] = *(const u32x4*)(A + (size_t)(crow0 + bm0 + r) * K + c8);
    }
    #pragma unroll
    for (int i = 0; i < BIT; ++i) {
        int n = i * 32 + rs;
        pb[i] = *(const u32x4*)(Bt + (size_t)(bn0 + n) * ldb + c8);
    }
    for (int kc = 0; kc < nK; ++kc) {
        __syncthreads();
        #pragma unroll
        for (int i = 0; i < AIT; ++i) {
            int r = i * 32 + rs;
            *(u32x4*)&As[r][c8 ^ wsz] = pa[i];
        }
        #pragma unroll
        for (int i = 0; i < BIT; ++i) {
            int n = i * 32 + rs;
            *(u32x4*)&Bs[n][c8 ^ wsz] = pb[i];
        }
        __syncthreads();
        if (kc + 1 < nK) {
            int ko = (kc + 1) * BK;
            #pragma unroll
            for (int i = 0; i < AIT; ++i) {
                int r = i * 32 + rs;
                pa[i] = *(const u32x4*)(A + (size_t)(crow0 + bm0 + r) * K + ko + c8);
            }
            #pragma unroll
            for (int i = 0; i < BIT; ++i) {
                int n = i * 32 + rs;
                pb[i] = *(const u32x4*)(Bt + (size_t)(bn0 + n) * ldb + ko + c8);
            }
        }
        #pragma unroll
        for (int ks = 0; ks < BK; ks += 32) {
            bf16x8 af[MI], bfr[NJ];
            int col = (ks + quad * 8) ^ rsz;
            #pragma unroll
            for (int mi = 0; mi < MI; ++mi)
                af[mi] = __builtin_bit_cast(bf16x8,
                    *(const u32x4*)&As[wm * 32 + mi * 16 + l][col]);
            #pragma unroll
            for (int nj = 0; nj < NJ; ++nj)
                bfr[nj] = __builtin_bit_cast(bf16x8,
                    *(const u32x4*)&Bs[wn * 96 + nj * 16 + l][col]);
            #pragma unroll
            for (int mi = 0; mi < MI; ++mi)
                #pragma unroll
                for (int nj = 0; nj < NJ; ++nj)
                    acc[mi][nj] = __builtin_amdgcn_mfma_f32_16x16x32_bf16(
                        af[mi], bfr[nj], acc[mi][nj], 0, 0, 0);
        }
    }
    #pragma unroll
    for (int mi = 0; mi < MI; ++mi)
        #pragma unroll
        for (int nj = 0; nj < NJ; ++nj)
            #pragma unroll
            for (int r = 0; r < 4; ++r) {
                int lrow = bm0 + wm * 32 + mi * 16 + quad * 4 + r;
                if (lrow < cnt) {
                    int   tok = rowbuf[lrow - bm0];
                    float sc  = wgt[ebase + lrow];
                    int   col = bn0 + wn * 96 + nj * 16 + l;
                    atomicAdd(&Cout[(size_t)tok * N + col], sc * acc[mi][nj][r]);
                }
            }
}

// ---------------------------------------------------------------------------
// Expert-phase MFMA GEMM (fallback path only).
// ---------------------------------------------------------------------------
template<int BN, int EPI, int ROUTED, int WB>
__global__ __launch_bounds__(256)
void gemm_k(const unsigned short* __restrict__ A,
            const void* __restrict__ Bm,
            void* __restrict__ Cout,
            const void* __restrict__ resid,
            const float* __restrict__ wgt,
            const int* __restrict__ eidx,
            const int* __restrict__ counts,
            const int* __restrict__ offs,
            int M, int N, int K, int ldb, long long bstr)
{
    constexpr int BM = 128, BK = 64, LDT = BK + 8;
    constexpr int WM = BM / 2, WN = BN / 2, MI = WM / 16, NJ = WN / 16;
    constexpr int AIT = (BM * BK) / 2048, BIT = (BN * BK) / 2048;
    __shared__ alignas(16) unsigned short As[BM][LDT];
    __shared__ alignas(16) unsigned short Bs[BN][LDT];
    __shared__ int rowbuf[BM];
    const int tid  = threadIdx.x;
    const int bn0  = blockIdx.x * BN, bm0 = blockIdx.y * BM;
    const int lane = tid & 63, wave = tid >> 6;
    const int l    = lane & 15, quad = lane >> 4;
    const int wm   = wave >> 1, wn = wave & 1;

    int cnt = M, crow0 = 0, ebase = 0;
    long long boff = 0;
    if constexpr (ROUTED) {
        int e = blockIdx.z;
        cnt = counts[e];
        if (bm0 >= cnt) return;
        crow0 = offs[e];
        ebase = e * TOK;
        boff  = (long long)e * bstr;
        if (tid < BM) {
            int rr = bm0 + tid;
            rowbuf[tid] = (rr < cnt) ? eidx[ebase + rr] : 0;
        }
        __syncthreads();
    }

    f32x4 acc[MI][NJ];
    #pragma unroll
    for (int mi = 0; mi < MI; ++mi)
        #pragma unroll
        for (int nj = 0; nj < NJ; ++nj) acc[mi][nj] = (f32x4){0.f, 0.f, 0.f, 0.f};

    const int nK = K / BK;
    for (int kc = 0; kc < nK; ++kc) {
        __syncthreads();
        #pragma unroll
        for (int i = 0; i < AIT; ++i) {
            int u = i * 256 + tid;
            int r = u >> 3, c8 = (u & 7) * 8;
            int arow;
            if constexpr (ROUTED && EPI != 5) arow = rowbuf[r];
            else if constexpr (ROUTED)        arow = crow0 + bm0 + r;
            else                              arow = bm0 + r;
            *(u32x4*)&As[r][c8] =
                *(const u32x4*)(A + (size_t)arow * K + kc * BK + c8);
        }
        const float* Bf = (const float*)Bm + boff;
        #pragma unroll
        for (int i = 0; i < BIT; ++i) {
            int u = i * 256 + tid;
            int n = u % BN, k8 = (u / BN) * 8;
            const float* gB = Bf + (size_t)(kc * BK + k8) * ldb + bn0 + n;
            u16x8 tmp;
            #pragma unroll
            for (int j = 0; j < 8; ++j) tmp[j] = f2b(gB[(size_t)j * ldb]);
            *(u16x8*)&Bs[n][k8] = tmp;
        }
        __syncthreads();
        #pragma unroll
        for (int ks = 0; ks < BK; ks += 32) {
            bf16x8 af[MI], bfr[NJ];
            #pragma unroll
            for (int mi = 0; mi < MI; ++mi)
                af[mi] = __builtin_bit_cast(bf16x8,
                    *(const u32x4*)&As[wm * WM + mi * 16 + l][ks + quad * 8]);
            #pragma unroll
            for (int nj = 0; nj < NJ; ++nj)
                bfr[nj] = __builtin_bit_cast(bf16x8,
                    *(const u32x4*)&Bs[wn * WN + nj * 16 + l][ks + quad * 8]);
            #pragma unroll
            for (int mi = 0; mi < MI; ++mi)
                #pragma unroll
                for (int nj = 0; nj < NJ; ++nj)
                    acc[mi][nj] = __builtin_amdgcn_mfma_f32_16x16x32_bf16(
                        af[mi], bfr[nj], acc[mi][nj], 0, 0, 0);
        }
    }
    #pragma unroll
    for (int mi = 0; mi < MI; ++mi)
        #pragma unroll
        for (int nj = 0; nj < NJ; ++nj)
            #pragma unroll
            for (int r = 0; r < 4; ++r) {
                int lrow = bm0 + wm * WM + mi * 16 + quad * 4 + r;
                int col  = bn0 + wn * WN + nj * 16 + l;
                float v = acc[mi][nj][r];
                if constexpr (EPI == 0) {
                    ((unsigned short*)Cout)[(size_t)(crow0 + lrow) * N + col] = f2b(v);
                } else if constexpr (EPI == 3) {
                    size_t ix = (size_t)(crow0 + lrow) * N + col;
                    float hv = b2f(((const unsigned short*)resid)[ix]);
                    float g = 0.5f * hv * (1.0f + erff(hv * 0.70710678118654752f));
                    ((unsigned short*)Cout)[ix] = f2b(g * v);
                } else if constexpr (EPI == 4) {
                    ((float*)Cout)[(size_t)lrow * N + col] += v;
                } else {
                    if (lrow < cnt) {
                        int   tok = rowbuf[lrow - bm0];
                        float sc  = wgt[ebase + lrow];
                        atomicAdd(&((float*)Cout)[(size_t)tok * N + col], sc * v);
                    }
                }
            }
}

// ---------------------------------------------------------------------------
// Per-position cross-head attention, full fp32. Output written as pre-split
// f16 pair (aoh, aol*2048) with the SAME index expression as the old fp32
// ao — feeds the o-projection gemmS AB=1 path bit-identically.
// ---------------------------------------------------------------------------
__global__ __launch_bounds__(256)
void attn32_k(const float* __restrict__ q,   // [ct][H][64]
              const float* __restrict__ kv,  // [ct][H][128]
              _Float16* __restrict__ aoh,
              _Float16* __restrict__ aol,
              int pos0)
{
    int pl   = blockIdx.x * 4 + (threadIdx.x >> 6);
    int lane = threadIdx.x & 63;
    int pos  = pos0 + pl;
    int b = pos >> 11, s = pos & 2047;

    const float* qp  = q  + (size_t)pl * 576;
    const float* kvp = kv + (size_t)pl * 1152;

    int i = lane >> 1;
    float theta = powf(10000.f, -(float)i * (1.0f / 32.0f));
    float sn, cs;
    sincosf((float)s * theta, &sn, &cs);

    float qr[H_], kr[H_], vr[H_];
    #pragma unroll
    for (int h = 0; h < H_; ++h) {
        float qv = qp[h * 64 + lane];
        float qo = __shfl_xor(qv, 1, 64);
        qr[h] = (lane & 1) ? (qo * sn + qv * cs) : (qv * cs - qo * sn);
        kr[h] = kvp[h * 128 + lane];
        vr[h] = kvp[h * 128 + 64 + lane];
    }

    #pragma unroll
    for (int h = 0; h < H_; ++h) {
        float sc[H_];
        #pragma unroll
        for (int t = 0; t < H_; ++t) {
            float p = qr[h] * kr[t];
            #pragma unroll
            for (int d = 1; d < 64; d <<= 1) p += __shfl_xor(p, d, 64);
            sc[t] = p * 0.125f;
        }
        float mx = sc[0];
        #pragma unroll
        for (int t = 1; t < H_; ++t) mx = fmaxf(mx, sc[t]);
        float ssum = 0.f;
        #pragma unroll
        for (int t = 0; t < H_; ++t) { sc[t] = __expf(sc[t] - mx); ssum += sc[t]; }
        float inv = 1.0f / ssum;
        float ov = 0.f;
        #pragma unroll
        for (int t = 0; t < H_; ++t) ov += sc[t] * vr[t];
        float v = ov * inv;
        size_t idx = ((size_t)(b * H_ + h) * S_ + s) * 64 + lane;
        _Float16 hh = (_Float16)v;
        aoh[idx] = hh;
        aol[idx] = (_Float16)((v - (float)hh) * 2048.0f);
    }
}

// ---------------------------------------------------------------------------
// Gating pass 1: per-token top-2 (no atomics). 4 tokens/block, 1 wave each.
// ---------------------------------------------------------------------------
__global__ __launch_bounds__(256)
void gate1_k(const float* __restrict__ x2,
             const float* __restrict__ gw,
             float* __restrict__ tw,    // [TOK][2]
             int*   __restrict__ tsel)  // [TOK]
{
    int tok  = blockIdx.x * 4 + (threadIdx.x >> 6);
    int lane = threadIdx.x & 63;
    float acc[8];
    #pragma unroll
    for (int e = 0; e < 8; ++e) acc[e] = 0.f;
    float ss = 0.f;
    for (int d = lane; d < D_; d += 64) {
        float xv = x2[(size_t)tok * D_ + d];
        ss += xv * xv;
        const float* wr = gw + (size_t)d * 8;
        #pragma unroll
        for (int e = 0; e < 8; ++e) acc[e] += xv * wr[e];
    }
    #pragma unroll
    for (int d = 1; d < 64; d <<= 1) ss += __shfl_xor(ss, d, 64);
    #pragma unroll
    for (int e = 0; e < 8; ++e)
        #pragma unroll
        for (int d = 1; d < 64; d <<= 1) acc[e] += __shfl_xor(acc[e], d, 64);
    if (lane == 0) {
        float rms = rsqrtf(ss / (float)D_ + 1e-6f);
        #pragma unroll
        for (int e = 0; e < 8; ++e) acc[e] *= rms;
        float mx = acc[0];
        #pragma unroll
        for (int e = 1; e < 8; ++e) mx = fmaxf(mx, acc[e]);
        float g[8], ssum = 0.f;
        #pragma unroll
        for (int e = 0; e < 8; ++e) { g[e] = __expf(acc[e] - mx); ssum += g[e]; }
        #pragma unroll
        for (int e = 0; e < 8; ++e) g[e] /= ssum;
        int i1 = 0;
        #pragma unroll
        for (int e = 1; e < 8; ++e) if (g[e] > g[i1]) i1 = e;
        int i2 = -1;
        #pragma unroll
        for (int e = 0; e < 8; ++e)
            if (e != i1 && (i2 < 0 || g[e] > g[i2])) i2 = e;
        float s2 = g[i1] + g[i2];
        tw[(size_t)tok * 2 + 0] = g[i1] / s2;
        tw[(size_t)tok * 2 + 1] = g[i2] / s2;
        tsel[tok] = i1 | (i2 << 8);
    }
}

// ---------------------------------------------------------------------------
// Gating pass 2: deterministic atomic-free compaction. One block per expert.
// Expert 8 (shared) gets the identity list with weight 1.0.
// ---------------------------------------------------------------------------
__global__ __launch_bounds__(256)
void gate2_k(const int*   __restrict__ tsel,
             const float* __restrict__ tw,
             float* __restrict__ wgt,     // [9][TOK]
             int*   __restrict__ eidx,    // [9][TOK]
             int*   __restrict__ counts)  // [9]
{
    int e    = blockIdx.x;   // 0..8
    int tid  = threadIdx.x;
    int lane = tid & 63, wv = tid >> 6;
    __shared__ int wtot[4];
    int base = 0;
    for (int t0 = 0; t0 < TOK; t0 += 256) {
        int tok = t0 + tid;
        int hit = 0; float w = 0.f;
        if (e == E_) { hit = 1; w = 1.0f; }
        else {
            int s = tsel[tok];
            if ((s & 255) == e)      { hit = 1; w = tw[(size_t)tok * 2 + 0]; }
            else if ((s >> 8) == e)  { hit = 1; w = tw[(size_t)tok * 2 + 1]; }
        }
        unsigned long long m = __ballot(hit);
        int pre = __popcll(m & ((1ull << lane) - 1ull));
        if (lane == 0) wtot[wv] = __popcll(m);
        __syncthreads();
        int off = base;
        for (int q = 0; q < wv; ++q) off += wtot[q];
        if (hit) {
            int p = off + pre;
            eidx[e * TOK + p] = tok;
            wgt [e * TOK + p] = w;
        }
        base += wtot[0] + wtot[1] + wtot[2] + wtot[3];
        __syncthreads();   // protect wtot before next chunk overwrites it
    }
    if (tid == 0) counts[e] = base;
}

// 128-padded exclusive prefix of counts -> per-expert compact row offsets
// (fallback gemm_k path only)
__global__ void offs_k(const int* __restrict__ counts, int* __restrict__ offs) {
    if (threadIdx.x == 0) {
        int run = 0;
        for (int e = 0; e < 9; ++e) {
            offs[e] = run;
            run += ((counts[e] + 127) >> 7) << 7;
        }
    }
}

// ---------------------------------------------------------------------------
extern "C" void kernel_launch(void* const* d_in, const int* in_sizes, int n_in,
                              void* d_out, int out_size, void* d_ws, size_t ws_size,
                              hipStream_t stream)
{
    const float* x      = (const float*)d_in[0];
    const float* q_w    = (const float*)d_in[1];
    const float* kv_w   = (const float*)d_in[2];
    const float* o_w    = (const float*)d_in[3];
    const float* gate_w = (const float*)d_in[4];
    const float* w1     = (const float*)d_in[5];
    const float* w2     = (const float*)d_in[6];
    const float* w3     = (const float*)d_in[7];
    const float* sw1    = (const float*)d_in[8];
    const float* sw2    = (const float*)d_in[9];
    const float* sw3    = (const float*)d_in[10];
    float* out = (float*)d_out;   // fp32: holds x2, then accumulates experts

    const size_t XN = (size_t)TOK * D_ * 2;   //  9,437,184 (bf16 TOK x D)
    char* ws = (char*)d_ws;
    unsigned short* xn16 = (unsigned short*)ws;          // [0, XN)      persists
    _Float16* aoh = (_Float16*)(ws + XN);                // [XN, 2XN)    phase A
    _Float16* aol = (_Float16*)(ws + 2 * XN);            // [2XN, 3XN)   phase A

    // split attention-path weights: qh/ql [D][D], kvh/kvl [1152][D], oh/ol [D][D]
    const size_t QE = (size_t)D_ * D_, KVE = (size_t)1152 * D_;
    const size_t SW = (2 * QE + KVE) * 2 * 2;   // 5,308,416 bytes
    _Float16* qwh  = (_Float16*)(ws + 3 * XN);
    _Float16* qwl  = qwh  + QE;
    _Float16* kvwh = qwl  + QE;
    _Float16* kvwl = kvwh + KVE;
    _Float16* owh  = kvwl + KVE;
    _Float16* owl  = owh  + QE;

    // phase-A chunking: footprint = 3XN + (convA?SW:0) + 8XN/TC
    bool convA = true;
    int TC = -1;
    for (int pass = 0; pass < 2; ++pass) {
        size_t base = 3 * XN + (convA ? SW : 0);
        if      (base + 8*XN    <= ws_size) { TC = 1; break; }
        else if (base + 8*XN/2  <= ws_size) { TC = 2; break; }
        else if (base + 8*XN/4  <= ws_size) { TC = 4; break; }
        else if (base + 8*XN/8  <= ws_size) { TC = 8; break; }
        else if (base + 8*XN/16 <= ws_size) { TC = 16; break; }
        else if (base + 8*XN/32 <= ws_size) { TC = 32; break; }
        else if (base + 8*XN/64 <= ws_size) { TC = 64; break; }
        convA = false;  // retry without split weights
    }
    if (TC < 0) { convA = false; TC = 64; }
    const int CT = TOK / TC;
    char* chunk0 = ws + 3*XN + (convA ? SW : 0);
    _Float16* xnh  = (_Float16*)chunk0;
    _Float16* xnl  = xnh + (size_t)CT * D_;
    float*    xn32c = (float*)chunk0;
    float*    qc   = (float*)(chunk0 + (size_t)CT * D_ * 4);
    float*    kvc  = qc + (size_t)CT * D_;

    // expert-phase layout (reuses the ao/chunk space, dead after step 2):
    int*   counts = (int*)(ws + XN);
    int*   offs   = counts + 16;
    float* wgt    = (float*)(ws + XN + 256);
    int*   eidx   = (int*)  (ws + XN + 256 + (size_t)9 * TOK * 4);
    float* tw     = (float*)(ws + XN + 256 + (size_t)9 * TOK * 8);
    int*   tsel   = (int*)  (ws + XN + 256 + (size_t)9 * TOK * 8 + (size_t)TOK * 8);
    const size_t fixedG = XN + 256 + (size_t)9 * TOK * 8 + (size_t)TOK * 12;

    const size_t WELEM = (size_t)D_ * FF_;          // 884736 elems per matrix
    const size_t WSZ   = 27 * WELEM * 2;            // 9 slots x (w1,w3,w2) bf16

    bool conv; int FC;
    if      (fixedG + WSZ + (size_t)T1ALL * FF_     * 2 <= ws_size) { conv = true;  FC = 1; }
    else if (fixedG + WSZ + (size_t)T1ALL * (FF_/2) * 2 <= ws_size) { conv = true;  FC = 2; }
    else if (fixedG + WSZ + (size_t)T1ALL * (FF_/4) * 2 <= ws_size) { conv = true;  FC = 4; }
    else if (fixedG + (size_t)T1ROWS * FF_     * 2 <= ws_size)      { conv = false; FC = 1; }
    else if (fixedG + (size_t)T1ROWS * (FF_/2) * 2 <= ws_size)      { conv = false; FC = 2; }
    else                                                            { conv = false; FC = 4; }
    const int FFc = FF_ / FC;

    unsigned short* wt1 = (unsigned short*)(ws + fixedG);   // 9 slots
    unsigned short* wt3 = wt1 + 9 * WELEM;                  // 9 slots
    unsigned short* wt2 = wt3 + 9 * WELEM;                  // 9 slots
    unsigned short* t1  = (unsigned short*)(ws + fixedG + (conv ? WSZ : 0));

    // 0) split attention-path weights once (bit-identical values; 1 launch)
    if (convA) {
        convSall_k<<<dim3(1152/64, D_/64, 3), 256, 0, stream>>>(
            q_w, kv_w, o_w, qwh, qwl, kvwh, kvwl, owh, owl);
    }
    // 1) phase A per chunk: xn split (f16 pair), q, kv (split GEMM), attention
    for (int t = 0; t < TC; ++t) {
        const float* xc = x + (size_t)t * CT * D_;
        if (convA) {
            rmssplit_k<<<CT, 256, 0, stream>>>(xc, xnh, xnl);
            gemmS_k<64, 0, 1, 1><<<dim3(D_ / 64, CT / 128), 256, 0, stream>>>(
                nullptr, xnh, xnl, nullptr, qwh, qwl, qc, nullptr, CT, D_, D_, D_);
            gemmS_k<64, 0, 1, 1><<<dim3(1152 / 64, CT / 128), 256, 0, stream>>>(
                nullptr, xnh, xnl, nullptr, kvwh, kvwl, kvc, nullptr, CT, 1152, D_, D_);
        } else {
            rms32_k<<<CT, 256, 0, stream>>>(xc, xn32c);
            gemmS_k<64, 0, 0, 0><<<dim3(D_ / 64, CT / 128), 256, 0, stream>>>(
                xn32c, nullptr, nullptr, q_w, nullptr, nullptr, qc, nullptr, CT, D_, D_, D_);
            gemmS_k<64, 0, 0, 0><<<dim3(1152 / 64, CT / 128), 256, 0, stream>>>(
                xn32c, nullptr, nullptr, kv_w, nullptr, nullptr, kvc, nullptr, CT, 1152, D_, 1152);
        }
        attn32_k<<<CT / 4, 256, 0, stream>>>(qc, kvc, aoh, aol, t * CT);
    }
    // 2) x2 = ao @ o_w + x -> d_out (split GEMM; A = pre-split attn output)
    if (convA)
        gemmS_k<64, 1, 1, 1><<<dim3(D_ / 64, TOK / 128), 256, 0, stream>>>(
            nullptr, aoh, aol, nullptr, owh, owl, out, x, TOK, D_, D_, D_);
    else
        gemmS_k<64, 1, 0, 1><<<dim3(D_ / 64, TOK / 128), 256, 0, stream>>>(
            nullptr, aoh, aol, o_w, nullptr, nullptr, out, x, TOK, D_, D_, D_);
    // 3) xn16 = rmsnorm(x2) (bf16, expert input)
    rmsnorm_k<<<TOK, 256, 0, stream>>>(out, xn16);
    // 4) gating (expert 8 = shared identity list)
    gate1_k<<<TOK / 4, 256, 0, stream>>>(out, gate_w, tw, tsel);
    gate2_k<<<E_ + 1, 256, 0, stream>>>(tsel, tw, wgt, eidx, counts);
    // 4b) weight convert+transpose fp32 -> bf16 [N][K], 9 slots each
    if (conv) {
        convw13_k<<<dim3(FF_/64, D_/64, 18), 256, 0, stream>>>(
            w1, w3, sw1, sw3, wt1, wt3);
        convw2_k<<<dim3(D_/64, FF_/64, 9), 256, 0, stream>>>(w2, sw2, wt2);
    } else {
        offs_k<<<1, 64, 0, stream>>>(counts, offs);
    }
    // 5) all 9 experts: flat live grids (shared = expert 8)
    for (int c = 0; c < FC; ++c) {
        if (conv) {
            gemm13_k<<<dim3(FFc / 128, T1ALL / 128), 256, 0, stream>>>(
                xn16, wt1 + (size_t)c * FFc * D_, wt3 + (size_t)c * FFc * D_,
                t1, eidx, counts, FFc, (long long)WELEM);
            gemm2_k<<<dim3(D_ / 192, T1ALL / 64), 256, 0, stream>>>(
                t1, wt2 + (size_t)c * FFc, out, wgt, eidx, counts,
                D_, FFc, FF_, (long long)WELEM);
        } else {
            const float* w1c = w1 + (size_t)c * FFc;
            const float* w3c = w3 + (size_t)c * FFc;
            const float* w2c = w2 + (size_t)c * FFc * D_;
            gemm_k<128, 0, 1, 0><<<dim3(FFc / 128, TOK / 128, E_), 256, 0, stream>>>(
                xn16, w1c, t1, nullptr, wgt, eidx, counts, offs,
                TOK, FFc, D_, FF_, (long long)D_ * FF_);
            gemm_k<128, 3, 1, 0><<<dim3(FFc / 128, TOK / 128, E_), 256, 0, stream>>>(
                xn16, w3c, t1, t1, wgt, eidx, counts, offs,
                TOK, FFc, D_, FF_, (long long)D_ * FF_);
            gemm_k<64, 5, 1, 0><<<dim3(D_ / 64, TOK / 128, E_), 256, 0, stream>>>(
                t1, w2c, out, nullptr, wgt, eidx, counts, offs,
                TOK, D_, FFc, D_, (long long)FF_ * D_);
            gemm_k<128, 0, 0, 0><<<dim3(FFc / 128, TOK / 128), 256, 0, stream>>>(
                xn16, sw1 + (size_t)c * FFc, t1, nullptr, nullptr, nullptr, nullptr, nullptr,
                TOK, FFc, D_, FF_, 0);
            gemm_k<128, 3, 0, 0><<<dim3(FFc / 128, TOK / 128), 256, 0, stream>>>(
                xn16, sw3 + (size_t)c * FFc, t1, t1, nullptr, nullptr, nullptr, nullptr,
                TOK, FFc, D_, FF_, 0);
            gemm_k<64, 4, 0, 0><<<dim3(D_ / 64, TOK / 128), 256, 0, stream>>>(
                t1, sw2 + (size_t)c * FFc * D_, out, nullptr, nullptr, nullptr, nullptr, nullptr,
                TOK, D_, FFc, D_, 0);
        }
    }
}